// Round 1
// baseline (666.649 us; speedup 1.0000x reference)
//
#include <hip/hip_runtime.h>
#include <math.h>

#define N_NODES 50000
#define N_EDGES 800000
#define E_TOT   (N_EDGES + N_NODES)
#define NEG_SLOPE 0.2f

static __device__ __forceinline__ float lrelu(float v) {
    return v > 0.0f ? v : NEG_SLOPE * v;
}

// -------- GEMM 1: h1[N,128] = x[N,128] @ W1[128,128] --------
// thread = (row, 4-col quad); W rows cached in L1/L2 (64 KB total)
__global__ void gemm1_kernel(const float* __restrict__ x, const float* __restrict__ W,
                             float* __restrict__ h) {
    int id = blockIdx.x * blockDim.x + threadIdx.x;
    int row = id >> 5;
    if (row >= N_NODES) return;
    int cq = (id & 31) * 4;
    const float* xr = x + (size_t)row * 128;
    float ax = 0.f, ay = 0.f, az = 0.f, aw = 0.f;
#pragma unroll 8
    for (int k4 = 0; k4 < 32; ++k4) {
        float4 xv = ((const float4*)xr)[k4];
        const float* wp = W + k4 * 4 * 128 + cq;
        float4 w;
        w = *(const float4*)(wp);       ax += xv.x * w.x; ay += xv.x * w.y; az += xv.x * w.z; aw += xv.x * w.w;
        w = *(const float4*)(wp + 128); ax += xv.y * w.x; ay += xv.y * w.y; az += xv.y * w.z; aw += xv.y * w.w;
        w = *(const float4*)(wp + 256); ax += xv.z * w.x; ay += xv.z * w.y; az += xv.z * w.z; aw += xv.z * w.w;
        w = *(const float4*)(wp + 384); ax += xv.w * w.x; ay += xv.w * w.y; az += xv.w * w.z; aw += xv.w * w.w;
    }
    *((float4*)(h + (size_t)row * 128 + cq)) = make_float4(ax, ay, az, aw);
}

// -------- GEMM 2: h2[N,64] = out1[N,128] @ W2[128,64] --------
__global__ void gemm2_kernel(const float* __restrict__ x, const float* __restrict__ W,
                             float* __restrict__ h) {
    int id = blockIdx.x * blockDim.x + threadIdx.x;
    int row = id >> 4;
    if (row >= N_NODES) return;
    int cq = (id & 15) * 4;
    const float* xr = x + (size_t)row * 128;
    float ax = 0.f, ay = 0.f, az = 0.f, aw = 0.f;
#pragma unroll 8
    for (int k4 = 0; k4 < 32; ++k4) {
        float4 xv = ((const float4*)xr)[k4];
        const float* wp = W + k4 * 4 * 64 + cq;
        float4 w;
        w = *(const float4*)(wp);       ax += xv.x * w.x; ay += xv.x * w.y; az += xv.x * w.z; aw += xv.x * w.w;
        w = *(const float4*)(wp + 64);  ax += xv.y * w.x; ay += xv.y * w.y; az += xv.y * w.z; aw += xv.y * w.w;
        w = *(const float4*)(wp + 128); ax += xv.z * w.x; ay += xv.z * w.y; az += xv.z * w.z; aw += xv.z * w.w;
        w = *(const float4*)(wp + 192); ax += xv.w * w.x; ay += xv.w * w.y; az += xv.w * w.z; aw += xv.w * w.w;
    }
    *((float4*)(h + (size_t)row * 64 + cq)) = make_float4(ax, ay, az, aw);
}

// -------- alpha_src/alpha_dst for layer 1 (2 heads, 64 ch) --------
__global__ void alphas1_kernel(const float* __restrict__ h1, const float* __restrict__ a_src,
                               const float* __restrict__ a_dst,
                               float* __restrict__ as, float* __restrict__ ad) {
    int wid = (blockIdx.x * blockDim.x + threadIdx.x) >> 6;
    if (wid >= N_NODES) return;
    int lane = threadIdx.x & 63;
    float h0 = h1[(size_t)wid * 128 + lane];
    float h1v = h1[(size_t)wid * 128 + 64 + lane];
    float s0 = h0 * a_src[lane], s1 = h1v * a_src[64 + lane];
    float d0 = h0 * a_dst[lane], d1 = h1v * a_dst[64 + lane];
    for (int off = 32; off > 0; off >>= 1) {
        s0 += __shfl_down(s0, off, 64);
        s1 += __shfl_down(s1, off, 64);
        d0 += __shfl_down(d0, off, 64);
        d1 += __shfl_down(d1, off, 64);
    }
    if (lane == 0) {
        as[wid * 2] = s0; as[wid * 2 + 1] = s1;
        ad[wid * 2] = d0; ad[wid * 2 + 1] = d1;
    }
}

// -------- alpha_src/alpha_dst for layer 2 (1 head, 64 ch) --------
__global__ void alphas2_kernel(const float* __restrict__ h2, const float* __restrict__ a_src,
                               const float* __restrict__ a_dst,
                               float* __restrict__ as, float* __restrict__ ad) {
    int wid = (blockIdx.x * blockDim.x + threadIdx.x) >> 6;
    if (wid >= N_NODES) return;
    int lane = threadIdx.x & 63;
    float h0 = h2[(size_t)wid * 64 + lane];
    float s0 = h0 * a_src[lane];
    float d0 = h0 * a_dst[lane];
    for (int off = 32; off > 0; off >>= 1) {
        s0 += __shfl_down(s0, off, 64);
        d0 += __shfl_down(d0, off, 64);
    }
    if (lane == 0) { as[wid] = s0; ad[wid] = d0; }
}

// -------- CSR build: histogram over dst --------
__global__ void hist_kernel(const int* __restrict__ ei, int* __restrict__ deg) {
    int tid = blockIdx.x * blockDim.x + threadIdx.x;
    if (tid >= E_TOT) return;
    int d = (tid < N_EDGES) ? ei[N_EDGES + tid] : (tid - N_EDGES);
    atomicAdd(&deg[d], 1);
}

// -------- exclusive scan (single block, 1024 threads) --------
__global__ void scan_kernel(const int* __restrict__ deg, int* __restrict__ offsets,
                            int* __restrict__ cursor) {
    __shared__ int sums[1024];
    int t = threadIdx.x;
    const int chunk = (N_NODES + 1023) / 1024;
    int lo = t * chunk;
    int hi = lo + chunk; if (hi > N_NODES) hi = N_NODES; if (lo > N_NODES) lo = N_NODES;
    int s = 0;
    for (int i = lo; i < hi; ++i) s += deg[i];
    sums[t] = s;
    __syncthreads();
    for (int off = 1; off < 1024; off <<= 1) {
        int v = (t >= off) ? sums[t - off] : 0;
        __syncthreads();
        sums[t] += v;
        __syncthreads();
    }
    int base = (t == 0) ? 0 : sums[t - 1];
    for (int i = lo; i < hi; ++i) {
        offsets[i] = base; cursor[i] = base;
        base += deg[i];
    }
    if (t == 1023) offsets[N_NODES] = sums[1023];
}

// -------- CSR build: scatter src ids into dst-sorted order --------
__global__ void scatter_kernel(const int* __restrict__ ei, int* __restrict__ cursor,
                               int* __restrict__ csr_src) {
    int tid = blockIdx.x * blockDim.x + threadIdx.x;
    if (tid >= E_TOT) return;
    int s, d;
    if (tid < N_EDGES) { s = ei[tid]; d = ei[N_EDGES + tid]; }
    else { s = d = tid - N_EDGES; }
    int pos = atomicAdd(&cursor[d], 1);
    csr_src[pos] = s;
}

// -------- layer 1 aggregate: wave per node, softmax-weighted sum, +b1, relu --------
__global__ void agg1_kernel(const float* __restrict__ h1, const float* __restrict__ as1,
                            const float* __restrict__ ad1, const float* __restrict__ b1,
                            const int* __restrict__ offsets, const int* __restrict__ csr_src,
                            float* __restrict__ out1) {
    int wid = (blockIdx.x * blockDim.x + threadIdx.x) >> 6;
    if (wid >= N_NODES) return;
    int lane = threadIdx.x & 63;
    float da0 = ad1[wid * 2 + 0], da1 = ad1[wid * 2 + 1];
    int jb = offsets[wid], je = offsets[wid + 1];
    float acc0 = 0.f, acc1 = 0.f, sum0 = 0.f, sum1 = 0.f;
    for (int j = jb; j < je; ++j) {
        int s = csr_src[j];
        float w0 = expf(lrelu(as1[s * 2 + 0] + da0));
        float w1 = expf(lrelu(as1[s * 2 + 1] + da1));
        const float* hp = h1 + (size_t)s * 128;
        acc0 += w0 * hp[lane];
        acc1 += w1 * hp[64 + lane];
        sum0 += w0; sum1 += w1;
    }
    float v0 = acc0 / sum0 + b1[lane];
    float v1 = acc1 / sum1 + b1[64 + lane];
    out1[(size_t)wid * 128 + lane] = v0 > 0.f ? v0 : 0.f;
    out1[(size_t)wid * 128 + 64 + lane] = v1 > 0.f ? v1 : 0.f;
}

// -------- layer 2 aggregate: wave per node, +b2, sigmoid --------
__global__ void agg2_kernel(const float* __restrict__ h2, const float* __restrict__ as2,
                            const float* __restrict__ ad2, const float* __restrict__ b2,
                            const int* __restrict__ offsets, const int* __restrict__ csr_src,
                            float* __restrict__ out) {
    int wid = (blockIdx.x * blockDim.x + threadIdx.x) >> 6;
    if (wid >= N_NODES) return;
    int lane = threadIdx.x & 63;
    float da = ad2[wid];
    int jb = offsets[wid], je = offsets[wid + 1];
    float acc = 0.f, sum = 0.f;
    for (int j = jb; j < je; ++j) {
        int s = csr_src[j];
        float w = expf(lrelu(as2[s] + da));
        acc += w * h2[(size_t)s * 64 + lane];
        sum += w;
    }
    float v = acc / sum + b2[lane];
    out[(size_t)wid * 64 + lane] = 1.f / (1.f + expf(-v));
}

extern "C" void kernel_launch(void* const* d_in, const int* in_sizes, int n_in,
                              void* d_out, int out_size, void* d_ws, size_t ws_size,
                              hipStream_t stream) {
    const float* x     = (const float*)d_in[0];
    const int*   ei    = (const int*)d_in[1];
    const float* W1    = (const float*)d_in[2];
    const float* asrc1 = (const float*)d_in[3];
    const float* adst1 = (const float*)d_in[4];
    const float* b1    = (const float*)d_in[5];
    const float* W2    = (const float*)d_in[6];
    const float* asrc2 = (const float*)d_in[7];
    const float* adst2 = (const float*)d_in[8];
    const float* b2    = (const float*)d_in[9];
    float* out = (float*)d_out;

    float* ws = (float*)d_ws;
    size_t off = 0;
    float* h1   = ws + off; off += (size_t)N_NODES * 128;
    float* out1 = ws + off; off += (size_t)N_NODES * 128;
    float* h2   = ws + off; off += (size_t)N_NODES * 64;
    float* as1  = ws + off; off += (size_t)N_NODES * 2;
    float* ad1  = ws + off; off += (size_t)N_NODES * 2;
    float* as2  = ws + off; off += (size_t)N_NODES;
    float* ad2  = ws + off; off += (size_t)N_NODES;
    int* ibuf    = (int*)(ws + off);
    int* deg     = ibuf;
    int* offsets = deg + N_NODES;
    int* cursor  = offsets + N_NODES + 1;
    int* csr_src = cursor + N_NODES;

    hipMemsetAsync(deg, 0, N_NODES * sizeof(int), stream);

    gemm1_kernel<<<(N_NODES * 32 + 255) / 256, 256, 0, stream>>>(x, W1, h1);
    alphas1_kernel<<<(N_NODES * 64 + 255) / 256, 256, 0, stream>>>(h1, asrc1, adst1, as1, ad1);
    hist_kernel<<<(E_TOT + 255) / 256, 256, 0, stream>>>(ei, deg);
    scan_kernel<<<1, 1024, 0, stream>>>(deg, offsets, cursor);
    scatter_kernel<<<(E_TOT + 255) / 256, 256, 0, stream>>>(ei, cursor, csr_src);
    agg1_kernel<<<(N_NODES * 64 + 255) / 256, 256, 0, stream>>>(h1, as1, ad1, b1, offsets, csr_src, out1);
    gemm2_kernel<<<(N_NODES * 16 + 255) / 256, 256, 0, stream>>>(out1, W2, h2);
    alphas2_kernel<<<(N_NODES * 64 + 255) / 256, 256, 0, stream>>>(h2, asrc2, adst2, as2, ad2);
    agg2_kernel<<<(N_NODES * 64 + 255) / 256, 256, 0, stream>>>(h2, as2, ad2, b2, offsets, csr_src, out);
}

// Round 2
// 554.514 us; speedup vs baseline: 1.2022x; 1.2022x over previous
//
#include <hip/hip_runtime.h>
#include <math.h>

#define N_NODES 50000
#define N_EDGES 800000
#define E_TOT   (N_EDGES + N_NODES)
#define NEG_SLOPE 0.2f

static __device__ __forceinline__ float lrelu(float v) {
    return v > 0.0f ? v : NEG_SLOPE * v;
}

// -------- GEMM 1: h1[N,128] = x[N,128] @ W1[128,128] --------
// Tiled: block = 32 rows x 128 cols, W1 (64KB) + x-tile (16KB) in LDS.
// Thread = 4 rows x 4 cols, k unrolled by 4 -> 64 FMA per 8 ds_read_b128.
__global__ __launch_bounds__(256, 2) void gemm1_kernel(const float* __restrict__ x,
                                                       const float* __restrict__ W,
                                                       float* __restrict__ h) {
    __shared__ float ws[128 * 128];  // 64 KB
    __shared__ float xs[32 * 128];   // 16 KB
    int tid = threadIdx.x;
    int r0 = blockIdx.x * 32;

    // stage W: 16384 floats, 64 per thread (16 float4), coalesced
#pragma unroll
    for (int i = 0; i < 16; ++i) {
        int idx = i * 1024 + tid * 4;
        *(float4*)&ws[idx] = *(const float4*)&W[idx];
    }
    // stage x rows [r0, r0+32): 4096 floats, 16 per thread (4 float4)
    {
        int row = tid >> 3;            // 0..31
        int kb = (tid & 7) * 16;
        int grow = r0 + row;
        if (grow >= N_NODES) grow = N_NODES - 1;  // clamp OOB reads
        const float* xp = x + (size_t)grow * 128 + kb;
        float* xd = &xs[row * 128 + kb];
        *(float4*)(xd + 0)  = *(const float4*)(xp + 0);
        *(float4*)(xd + 4)  = *(const float4*)(xp + 4);
        *(float4*)(xd + 8)  = *(const float4*)(xp + 8);
        *(float4*)(xd + 12) = *(const float4*)(xp + 12);
    }
    __syncthreads();

    int colg = (tid & 31) * 4;        // 32 col-groups x 4 cols
    int rowg = (tid >> 5) * 4;        // 8 row-groups x 4 rows
    float4 acc0 = {0, 0, 0, 0}, acc1 = {0, 0, 0, 0}, acc2 = {0, 0, 0, 0}, acc3 = {0, 0, 0, 0};

#pragma unroll 8
    for (int k4 = 0; k4 < 32; ++k4) {
        int kb = k4 * 4;
        float4 w0 = *(float4*)&ws[(kb + 0) * 128 + colg];
        float4 w1 = *(float4*)&ws[(kb + 1) * 128 + colg];
        float4 w2 = *(float4*)&ws[(kb + 2) * 128 + colg];
        float4 w3 = *(float4*)&ws[(kb + 3) * 128 + colg];
        float4 xv;
#define ROWSTEP(ACC, R)                                                              \
        xv = *(float4*)&xs[(rowg + R) * 128 + kb];                                   \
        ACC.x += xv.x * w0.x + xv.y * w1.x + xv.z * w2.x + xv.w * w3.x;              \
        ACC.y += xv.x * w0.y + xv.y * w1.y + xv.z * w2.y + xv.w * w3.y;              \
        ACC.z += xv.x * w0.z + xv.y * w1.z + xv.z * w2.z + xv.w * w3.z;              \
        ACC.w += xv.x * w0.w + xv.y * w1.w + xv.z * w2.w + xv.w * w3.w;
        ROWSTEP(acc0, 0) ROWSTEP(acc1, 1) ROWSTEP(acc2, 2) ROWSTEP(acc3, 3)
#undef ROWSTEP
    }

    if (r0 + rowg + 0 < N_NODES) *(float4*)&h[(size_t)(r0 + rowg + 0) * 128 + colg] = acc0;
    if (r0 + rowg + 1 < N_NODES) *(float4*)&h[(size_t)(r0 + rowg + 1) * 128 + colg] = acc1;
    if (r0 + rowg + 2 < N_NODES) *(float4*)&h[(size_t)(r0 + rowg + 2) * 128 + colg] = acc2;
    if (r0 + rowg + 3 < N_NODES) *(float4*)&h[(size_t)(r0 + rowg + 3) * 128 + colg] = acc3;
}

// -------- GEMM 2: h2[N,64] = out1[N,128] @ W2[128,64] --------
// Tiled: block = 64 rows x 64 cols, W2 (32KB) + x-tile (32KB) in LDS.
__global__ __launch_bounds__(256, 2) void gemm2_kernel(const float* __restrict__ x,
                                                       const float* __restrict__ W,
                                                       float* __restrict__ h) {
    __shared__ float ws[128 * 64];   // 32 KB
    __shared__ float xs[64 * 128];   // 32 KB
    int tid = threadIdx.x;
    int r0 = blockIdx.x * 64;

    // stage W: 8192 floats, 32 per thread (8 float4)
#pragma unroll
    for (int i = 0; i < 8; ++i) {
        int idx = i * 1024 + tid * 4;
        *(float4*)&ws[idx] = *(const float4*)&W[idx];
    }
    // stage x rows [r0, r0+64): 8192 floats, 32 per thread (8 float4)
    {
        int row = tid >> 2;            // 0..63
        int kb = (tid & 3) * 32;
        int grow = r0 + row;
        if (grow >= N_NODES) grow = N_NODES - 1;
        const float* xp = x + (size_t)grow * 128 + kb;
        float* xd = &xs[row * 128 + kb];
#pragma unroll
        for (int i = 0; i < 8; ++i)
            *(float4*)(xd + i * 4) = *(const float4*)(xp + i * 4);
    }
    __syncthreads();

    int colg = (tid & 15) * 4;        // 16 col-groups x 4 cols
    int rowg = (tid >> 4) * 4;        // 16 row-groups x 4 rows
    float4 acc0 = {0, 0, 0, 0}, acc1 = {0, 0, 0, 0}, acc2 = {0, 0, 0, 0}, acc3 = {0, 0, 0, 0};

#pragma unroll 8
    for (int k4 = 0; k4 < 32; ++k4) {
        int kb = k4 * 4;
        float4 w0 = *(float4*)&ws[(kb + 0) * 64 + colg];
        float4 w1 = *(float4*)&ws[(kb + 1) * 64 + colg];
        float4 w2 = *(float4*)&ws[(kb + 2) * 64 + colg];
        float4 w3 = *(float4*)&ws[(kb + 3) * 64 + colg];
        float4 xv;
#define ROWSTEP(ACC, R)                                                              \
        xv = *(float4*)&xs[(rowg + R) * 128 + kb];                                   \
        ACC.x += xv.x * w0.x + xv.y * w1.x + xv.z * w2.x + xv.w * w3.x;              \
        ACC.y += xv.x * w0.y + xv.y * w1.y + xv.z * w2.y + xv.w * w3.y;              \
        ACC.z += xv.x * w0.z + xv.y * w1.z + xv.z * w2.z + xv.w * w3.z;              \
        ACC.w += xv.x * w0.w + xv.y * w1.w + xv.z * w2.w + xv.w * w3.w;
        ROWSTEP(acc0, 0) ROWSTEP(acc1, 1) ROWSTEP(acc2, 2) ROWSTEP(acc3, 3)
#undef ROWSTEP
    }

    if (r0 + rowg + 0 < N_NODES) *(float4*)&h[(size_t)(r0 + rowg + 0) * 64 + colg] = acc0;
    if (r0 + rowg + 1 < N_NODES) *(float4*)&h[(size_t)(r0 + rowg + 1) * 64 + colg] = acc1;
    if (r0 + rowg + 2 < N_NODES) *(float4*)&h[(size_t)(r0 + rowg + 2) * 64 + colg] = acc2;
    if (r0 + rowg + 3 < N_NODES) *(float4*)&h[(size_t)(r0 + rowg + 3) * 64 + colg] = acc3;
}

// -------- alpha_src/alpha_dst for layer 1 (2 heads, 64 ch) --------
__global__ void alphas1_kernel(const float* __restrict__ h1, const float* __restrict__ a_src,
                               const float* __restrict__ a_dst,
                               float* __restrict__ as, float* __restrict__ ad) {
    int wid = (blockIdx.x * blockDim.x + threadIdx.x) >> 6;
    if (wid >= N_NODES) return;
    int lane = threadIdx.x & 63;
    float h0 = h1[(size_t)wid * 128 + lane];
    float h1v = h1[(size_t)wid * 128 + 64 + lane];
    float s0 = h0 * a_src[lane], s1 = h1v * a_src[64 + lane];
    float d0 = h0 * a_dst[lane], d1 = h1v * a_dst[64 + lane];
    for (int off = 32; off > 0; off >>= 1) {
        s0 += __shfl_down(s0, off, 64);
        s1 += __shfl_down(s1, off, 64);
        d0 += __shfl_down(d0, off, 64);
        d1 += __shfl_down(d1, off, 64);
    }
    if (lane == 0) {
        as[wid * 2] = s0; as[wid * 2 + 1] = s1;
        ad[wid * 2] = d0; ad[wid * 2 + 1] = d1;
    }
}

// -------- alpha_src/alpha_dst for layer 2 (1 head, 64 ch) --------
__global__ void alphas2_kernel(const float* __restrict__ h2, const float* __restrict__ a_src,
                               const float* __restrict__ a_dst,
                               float* __restrict__ as, float* __restrict__ ad) {
    int wid = (blockIdx.x * blockDim.x + threadIdx.x) >> 6;
    if (wid >= N_NODES) return;
    int lane = threadIdx.x & 63;
    float h0 = h2[(size_t)wid * 64 + lane];
    float s0 = h0 * a_src[lane];
    float d0 = h0 * a_dst[lane];
    for (int off = 32; off > 0; off >>= 1) {
        s0 += __shfl_down(s0, off, 64);
        d0 += __shfl_down(d0, off, 64);
    }
    if (lane == 0) { as[wid] = s0; ad[wid] = d0; }
}

// -------- CSR build: histogram over dst --------
__global__ void hist_kernel(const int* __restrict__ ei, int* __restrict__ deg) {
    int tid = blockIdx.x * blockDim.x + threadIdx.x;
    if (tid >= E_TOT) return;
    int d = (tid < N_EDGES) ? ei[N_EDGES + tid] : (tid - N_EDGES);
    atomicAdd(&deg[d], 1);
}

// -------- exclusive scan (single block, 1024 threads) --------
__global__ void scan_kernel(const int* __restrict__ deg, int* __restrict__ offsets,
                            int* __restrict__ cursor) {
    __shared__ int sums[1024];
    int t = threadIdx.x;
    const int chunk = (N_NODES + 1023) / 1024;
    int lo = t * chunk;
    int hi = lo + chunk; if (hi > N_NODES) hi = N_NODES; if (lo > N_NODES) lo = N_NODES;
    int s = 0;
    for (int i = lo; i < hi; ++i) s += deg[i];
    sums[t] = s;
    __syncthreads();
    for (int off = 1; off < 1024; off <<= 1) {
        int v = (t >= off) ? sums[t - off] : 0;
        __syncthreads();
        sums[t] += v;
        __syncthreads();
    }
    int base = (t == 0) ? 0 : sums[t - 1];
    for (int i = lo; i < hi; ++i) {
        offsets[i] = base; cursor[i] = base;
        base += deg[i];
    }
    if (t == 1023) offsets[N_NODES] = sums[1023];
}

// -------- CSR build: scatter src ids into dst-sorted order --------
__global__ void scatter_kernel(const int* __restrict__ ei, int* __restrict__ cursor,
                               int* __restrict__ csr_src) {
    int tid = blockIdx.x * blockDim.x + threadIdx.x;
    if (tid >= E_TOT) return;
    int s, d;
    if (tid < N_EDGES) { s = ei[tid]; d = ei[N_EDGES + tid]; }
    else { s = d = tid - N_EDGES; }
    int pos = atomicAdd(&cursor[d], 1);
    csr_src[pos] = s;
}

// -------- layer 1 aggregate: wave per node, softmax-weighted sum, +b1, relu --------
__global__ void agg1_kernel(const float* __restrict__ h1, const float* __restrict__ as1,
                            const float* __restrict__ ad1, const float* __restrict__ b1,
                            const int* __restrict__ offsets, const int* __restrict__ csr_src,
                            float* __restrict__ out1) {
    int wid = (blockIdx.x * blockDim.x + threadIdx.x) >> 6;
    if (wid >= N_NODES) return;
    int lane = threadIdx.x & 63;
    float da0 = ad1[wid * 2 + 0], da1 = ad1[wid * 2 + 1];
    int jb = offsets[wid], je = offsets[wid + 1];
    float acc0 = 0.f, acc1 = 0.f, sum0 = 0.f, sum1 = 0.f;
    for (int j = jb; j < je; ++j) {
        int s = csr_src[j];
        float w0 = expf(lrelu(as1[s * 2 + 0] + da0));
        float w1 = expf(lrelu(as1[s * 2 + 1] + da1));
        const float* hp = h1 + (size_t)s * 128;
        acc0 += w0 * hp[lane];
        acc1 += w1 * hp[64 + lane];
        sum0 += w0; sum1 += w1;
    }
    float v0 = acc0 / sum0 + b1[lane];
    float v1 = acc1 / sum1 + b1[64 + lane];
    out1[(size_t)wid * 128 + lane] = v0 > 0.f ? v0 : 0.f;
    out1[(size_t)wid * 128 + 64 + lane] = v1 > 0.f ? v1 : 0.f;
}

// -------- layer 2 aggregate: wave per node, +b2, sigmoid --------
__global__ void agg2_kernel(const float* __restrict__ h2, const float* __restrict__ as2,
                            const float* __restrict__ ad2, const float* __restrict__ b2,
                            const int* __restrict__ offsets, const int* __restrict__ csr_src,
                            float* __restrict__ out) {
    int wid = (blockIdx.x * blockDim.x + threadIdx.x) >> 6;
    if (wid >= N_NODES) return;
    int lane = threadIdx.x & 63;
    float da = ad2[wid];
    int jb = offsets[wid], je = offsets[wid + 1];
    float acc = 0.f, sum = 0.f;
    for (int j = jb; j < je; ++j) {
        int s = csr_src[j];
        float w = expf(lrelu(as2[s] + da));
        acc += w * h2[(size_t)s * 64 + lane];
        sum += w;
    }
    float v = acc / sum + b2[lane];
    out[(size_t)wid * 64 + lane] = 1.f / (1.f + expf(-v));
}

extern "C" void kernel_launch(void* const* d_in, const int* in_sizes, int n_in,
                              void* d_out, int out_size, void* d_ws, size_t ws_size,
                              hipStream_t stream) {
    const float* x     = (const float*)d_in[0];
    const int*   ei    = (const int*)d_in[1];
    const float* W1    = (const float*)d_in[2];
    const float* asrc1 = (const float*)d_in[3];
    const float* adst1 = (const float*)d_in[4];
    const float* b1    = (const float*)d_in[5];
    const float* W2    = (const float*)d_in[6];
    const float* asrc2 = (const float*)d_in[7];
    const float* adst2 = (const float*)d_in[8];
    const float* b2    = (const float*)d_in[9];
    float* out = (float*)d_out;

    float* ws = (float*)d_ws;
    size_t off = 0;
    float* h1   = ws + off; off += (size_t)N_NODES * 128;
    float* out1 = ws + off; off += (size_t)N_NODES * 128;
    float* h2   = ws + off; off += (size_t)N_NODES * 64;
    float* as1  = ws + off; off += (size_t)N_NODES * 2;
    float* ad1  = ws + off; off += (size_t)N_NODES * 2;
    float* as2  = ws + off; off += (size_t)N_NODES;
    float* ad2  = ws + off; off += (size_t)N_NODES;
    int* ibuf    = (int*)(ws + off);
    int* deg     = ibuf;
    int* offsets = deg + N_NODES;
    int* cursor  = offsets + N_NODES + 1;
    int* csr_src = cursor + N_NODES;

    hipMemsetAsync(deg, 0, N_NODES * sizeof(int), stream);

    gemm1_kernel<<<(N_NODES + 31) / 32, 256, 0, stream>>>(x, W1, h1);
    alphas1_kernel<<<(N_NODES * 64 + 255) / 256, 256, 0, stream>>>(h1, asrc1, adst1, as1, ad1);
    hist_kernel<<<(E_TOT + 255) / 256, 256, 0, stream>>>(ei, deg);
    scan_kernel<<<1, 1024, 0, stream>>>(deg, offsets, cursor);
    scatter_kernel<<<(E_TOT + 255) / 256, 256, 0, stream>>>(ei, cursor, csr_src);
    agg1_kernel<<<(N_NODES * 64 + 255) / 256, 256, 0, stream>>>(h1, as1, ad1, b1, offsets, csr_src, out1);
    gemm2_kernel<<<(N_NODES + 63) / 64, 256, 0, stream>>>(out1, W2, h2);
    alphas2_kernel<<<(N_NODES * 64 + 255) / 256, 256, 0, stream>>>(h2, asrc2, adst2, as2, ad2);
    agg2_kernel<<<(N_NODES * 64 + 255) / 256, 256, 0, stream>>>(h2, as2, ad2, b2, offsets, csr_src, out);
}

// Round 3
// 455.301 us; speedup vs baseline: 1.4642x; 1.2179x over previous
//
#include <hip/hip_runtime.h>
#include <math.h>

#define N_NODES 50000
#define N_EDGES 800000
#define E_TOT   (N_EDGES + N_NODES)
#define NEG_SLOPE 0.2f
#define NB_SCAN ((N_NODES + 255) / 256)   // 196 scan blocks

static __device__ __forceinline__ float lrelu(float v) {
    return v > 0.0f ? v : NEG_SLOPE * v;
}

// -------- GEMM 1: h1[N,128] = x[N,128] @ W1[128,128] --------
// Tiled: block = 32 rows x 128 cols, W1 (64KB) + x-tile (16KB) in LDS.
// Thread = 4 rows x 4 cols, k unrolled by 4 -> 64 FMA per 8 ds_read_b128.
__global__ __launch_bounds__(256, 2) void gemm1_kernel(const float* __restrict__ x,
                                                       const float* __restrict__ W,
                                                       float* __restrict__ h) {
    __shared__ float ws[128 * 128];  // 64 KB
    __shared__ float xs[32 * 128];   // 16 KB
    int tid = threadIdx.x;
    int r0 = blockIdx.x * 32;

#pragma unroll
    for (int i = 0; i < 16; ++i) {
        int idx = i * 1024 + tid * 4;
        *(float4*)&ws[idx] = *(const float4*)&W[idx];
    }
    {
        int row = tid >> 3;            // 0..31
        int kb = (tid & 7) * 16;
        int grow = r0 + row;
        if (grow >= N_NODES) grow = N_NODES - 1;
        const float* xp = x + (size_t)grow * 128 + kb;
        float* xd = &xs[row * 128 + kb];
        *(float4*)(xd + 0)  = *(const float4*)(xp + 0);
        *(float4*)(xd + 4)  = *(const float4*)(xp + 4);
        *(float4*)(xd + 8)  = *(const float4*)(xp + 8);
        *(float4*)(xd + 12) = *(const float4*)(xp + 12);
    }
    __syncthreads();

    int colg = (tid & 31) * 4;
    int rowg = (tid >> 5) * 4;
    float4 acc0 = {0, 0, 0, 0}, acc1 = {0, 0, 0, 0}, acc2 = {0, 0, 0, 0}, acc3 = {0, 0, 0, 0};

#pragma unroll 8
    for (int k4 = 0; k4 < 32; ++k4) {
        int kb = k4 * 4;
        float4 w0 = *(float4*)&ws[(kb + 0) * 128 + colg];
        float4 w1 = *(float4*)&ws[(kb + 1) * 128 + colg];
        float4 w2 = *(float4*)&ws[(kb + 2) * 128 + colg];
        float4 w3 = *(float4*)&ws[(kb + 3) * 128 + colg];
        float4 xv;
#define ROWSTEP(ACC, R)                                                              \
        xv = *(float4*)&xs[(rowg + R) * 128 + kb];                                   \
        ACC.x += xv.x * w0.x + xv.y * w1.x + xv.z * w2.x + xv.w * w3.x;              \
        ACC.y += xv.x * w0.y + xv.y * w1.y + xv.z * w2.y + xv.w * w3.y;              \
        ACC.z += xv.x * w0.z + xv.y * w1.z + xv.z * w2.z + xv.w * w3.z;              \
        ACC.w += xv.x * w0.w + xv.y * w1.w + xv.z * w2.w + xv.w * w3.w;
        ROWSTEP(acc0, 0) ROWSTEP(acc1, 1) ROWSTEP(acc2, 2) ROWSTEP(acc3, 3)
#undef ROWSTEP
    }

    if (r0 + rowg + 0 < N_NODES) *(float4*)&h[(size_t)(r0 + rowg + 0) * 128 + colg] = acc0;
    if (r0 + rowg + 1 < N_NODES) *(float4*)&h[(size_t)(r0 + rowg + 1) * 128 + colg] = acc1;
    if (r0 + rowg + 2 < N_NODES) *(float4*)&h[(size_t)(r0 + rowg + 2) * 128 + colg] = acc2;
    if (r0 + rowg + 3 < N_NODES) *(float4*)&h[(size_t)(r0 + rowg + 3) * 128 + colg] = acc3;
}

// -------- GEMM 2: h2[N,64] = out1[N,128] @ W2[128,64] --------
__global__ __launch_bounds__(256, 2) void gemm2_kernel(const float* __restrict__ x,
                                                       const float* __restrict__ W,
                                                       float* __restrict__ h) {
    __shared__ float ws[128 * 64];   // 32 KB
    __shared__ float xs[64 * 128];   // 32 KB
    int tid = threadIdx.x;
    int r0 = blockIdx.x * 64;

#pragma unroll
    for (int i = 0; i < 8; ++i) {
        int idx = i * 1024 + tid * 4;
        *(float4*)&ws[idx] = *(const float4*)&W[idx];
    }
    {
        int row = tid >> 2;            // 0..63
        int kb = (tid & 3) * 32;
        int grow = r0 + row;
        if (grow >= N_NODES) grow = N_NODES - 1;
        const float* xp = x + (size_t)grow * 128 + kb;
        float* xd = &xs[row * 128 + kb];
#pragma unroll
        for (int i = 0; i < 8; ++i)
            *(float4*)(xd + i * 4) = *(const float4*)(xp + i * 4);
    }
    __syncthreads();

    int colg = (tid & 15) * 4;
    int rowg = (tid >> 4) * 4;
    float4 acc0 = {0, 0, 0, 0}, acc1 = {0, 0, 0, 0}, acc2 = {0, 0, 0, 0}, acc3 = {0, 0, 0, 0};

#pragma unroll 8
    for (int k4 = 0; k4 < 32; ++k4) {
        int kb = k4 * 4;
        float4 w0 = *(float4*)&ws[(kb + 0) * 64 + colg];
        float4 w1 = *(float4*)&ws[(kb + 1) * 64 + colg];
        float4 w2 = *(float4*)&ws[(kb + 2) * 64 + colg];
        float4 w3 = *(float4*)&ws[(kb + 3) * 64 + colg];
        float4 xv;
#define ROWSTEP(ACC, R)                                                              \
        xv = *(float4*)&xs[(rowg + R) * 128 + kb];                                   \
        ACC.x += xv.x * w0.x + xv.y * w1.x + xv.z * w2.x + xv.w * w3.x;              \
        ACC.y += xv.x * w0.y + xv.y * w1.y + xv.z * w2.y + xv.w * w3.y;              \
        ACC.z += xv.x * w0.z + xv.y * w1.z + xv.z * w2.z + xv.w * w3.z;              \
        ACC.w += xv.x * w0.w + xv.y * w1.w + xv.z * w2.w + xv.w * w3.w;
        ROWSTEP(acc0, 0) ROWSTEP(acc1, 1) ROWSTEP(acc2, 2) ROWSTEP(acc3, 3)
#undef ROWSTEP
    }

    if (r0 + rowg + 0 < N_NODES) *(float4*)&h[(size_t)(r0 + rowg + 0) * 64 + colg] = acc0;
    if (r0 + rowg + 1 < N_NODES) *(float4*)&h[(size_t)(r0 + rowg + 1) * 64 + colg] = acc1;
    if (r0 + rowg + 2 < N_NODES) *(float4*)&h[(size_t)(r0 + rowg + 2) * 64 + colg] = acc2;
    if (r0 + rowg + 3 < N_NODES) *(float4*)&h[(size_t)(r0 + rowg + 3) * 64 + colg] = acc3;
}

// -------- alpha_src/alpha_dst for layer 1 (2 heads, 64 ch) --------
__global__ void alphas1_kernel(const float* __restrict__ h1, const float* __restrict__ a_src,
                               const float* __restrict__ a_dst,
                               float* __restrict__ as, float* __restrict__ ad) {
    int wid = (blockIdx.x * blockDim.x + threadIdx.x) >> 6;
    if (wid >= N_NODES) return;
    int lane = threadIdx.x & 63;
    float h0 = h1[(size_t)wid * 128 + lane];
    float h1v = h1[(size_t)wid * 128 + 64 + lane];
    float s0 = h0 * a_src[lane], s1 = h1v * a_src[64 + lane];
    float d0 = h0 * a_dst[lane], d1 = h1v * a_dst[64 + lane];
    for (int off = 32; off > 0; off >>= 1) {
        s0 += __shfl_down(s0, off, 64);
        s1 += __shfl_down(s1, off, 64);
        d0 += __shfl_down(d0, off, 64);
        d1 += __shfl_down(d1, off, 64);
    }
    if (lane == 0) {
        as[wid * 2] = s0; as[wid * 2 + 1] = s1;
        ad[wid * 2] = d0; ad[wid * 2 + 1] = d1;
    }
}

// -------- alpha_src/alpha_dst for layer 2 (1 head, 64 ch) --------
__global__ void alphas2_kernel(const float* __restrict__ h2, const float* __restrict__ a_src,
                               const float* __restrict__ a_dst,
                               float* __restrict__ as, float* __restrict__ ad) {
    int wid = (blockIdx.x * blockDim.x + threadIdx.x) >> 6;
    if (wid >= N_NODES) return;
    int lane = threadIdx.x & 63;
    float h0 = h2[(size_t)wid * 64 + lane];
    float s0 = h0 * a_src[lane];
    float d0 = h0 * a_dst[lane];
    for (int off = 32; off > 0; off >>= 1) {
        s0 += __shfl_down(s0, off, 64);
        d0 += __shfl_down(d0, off, 64);
    }
    if (lane == 0) { as[wid] = s0; ad[wid] = d0; }
}

// -------- CSR build: histogram over dst --------
__global__ void hist_kernel(const int* __restrict__ ei, int* __restrict__ deg) {
    int tid = blockIdx.x * blockDim.x + threadIdx.x;
    if (tid >= E_TOT) return;
    int d = (tid < N_EDGES) ? ei[N_EDGES + tid] : (tid - N_EDGES);
    atomicAdd(&deg[d], 1);
}

// -------- scan phase A: per-block reduce of deg -> bsum[NB_SCAN] --------
__global__ void scanA_kernel(const int* __restrict__ deg, int* __restrict__ bsum) {
    __shared__ int red[256];
    int t = threadIdx.x;
    int i = blockIdx.x * 256 + t;
    red[t] = (i < N_NODES) ? deg[i] : 0;
    __syncthreads();
#pragma unroll
    for (int off = 128; off > 0; off >>= 1) {
        if (t < off) red[t] += red[t + off];
        __syncthreads();
    }
    if (t == 0) bsum[blockIdx.x] = red[0];
}

// -------- scan phase B: exclusive scan of bsum -> bbase; offsets[N]=E_TOT --------
__global__ void scanB_kernel(const int* __restrict__ bsum, int* __restrict__ bbase,
                             int* __restrict__ offsets) {
    __shared__ int s[256];
    int t = threadIdx.x;
    int v = (t < NB_SCAN) ? bsum[t] : 0;
    s[t] = v;
    __syncthreads();
#pragma unroll
    for (int off = 1; off < 256; off <<= 1) {
        int u = (t >= off) ? s[t - off] : 0;
        __syncthreads();
        s[t] += u;
        __syncthreads();
    }
    if (t < NB_SCAN) bbase[t] = s[t] - v;   // exclusive
    if (t == 0) offsets[N_NODES] = E_TOT;
}

// -------- scan phase C: block-local exclusive scan + bbase -> offsets, cursor --------
__global__ void scanC_kernel(const int* __restrict__ deg, const int* __restrict__ bbase,
                             int* __restrict__ offsets, int* __restrict__ cursor) {
    __shared__ int s[256];
    int t = threadIdx.x;
    int i = blockIdx.x * 256 + t;
    int v = (i < N_NODES) ? deg[i] : 0;
    s[t] = v;
    __syncthreads();
#pragma unroll
    for (int off = 1; off < 256; off <<= 1) {
        int u = (t >= off) ? s[t - off] : 0;
        __syncthreads();
        s[t] += u;
        __syncthreads();
    }
    if (i < N_NODES) {
        int excl = s[t] - v + bbase[blockIdx.x];
        offsets[i] = excl;
        cursor[i] = excl;
    }
}

// -------- CSR build: scatter src ids into dst-sorted order --------
__global__ void scatter_kernel(const int* __restrict__ ei, int* __restrict__ cursor,
                               int* __restrict__ csr_src) {
    int tid = blockIdx.x * blockDim.x + threadIdx.x;
    if (tid >= E_TOT) return;
    int s, d;
    if (tid < N_EDGES) { s = ei[tid]; d = ei[N_EDGES + tid]; }
    else { s = d = tid - N_EDGES; }
    int pos = atomicAdd(&cursor[d], 1);
    csr_src[pos] = s;
}

// -------- layer 1 aggregate: wave per node, softmax-weighted sum, +b1, relu --------
__global__ void agg1_kernel(const float* __restrict__ h1, const float* __restrict__ as1,
                            const float* __restrict__ ad1, const float* __restrict__ b1,
                            const int* __restrict__ offsets, const int* __restrict__ csr_src,
                            float* __restrict__ out1) {
    int wid = (blockIdx.x * blockDim.x + threadIdx.x) >> 6;
    if (wid >= N_NODES) return;
    int lane = threadIdx.x & 63;
    float da0 = ad1[wid * 2 + 0], da1 = ad1[wid * 2 + 1];
    int jb = offsets[wid], je = offsets[wid + 1];
    float acc0 = 0.f, acc1 = 0.f, sum0 = 0.f, sum1 = 0.f;
    for (int j = jb; j < je; ++j) {
        int s = csr_src[j];
        float w0 = expf(lrelu(as1[s * 2 + 0] + da0));
        float w1 = expf(lrelu(as1[s * 2 + 1] + da1));
        const float* hp = h1 + (size_t)s * 128;
        acc0 += w0 * hp[lane];
        acc1 += w1 * hp[64 + lane];
        sum0 += w0; sum1 += w1;
    }
    float v0 = acc0 / sum0 + b1[lane];
    float v1 = acc1 / sum1 + b1[64 + lane];
    out1[(size_t)wid * 128 + lane] = v0 > 0.f ? v0 : 0.f;
    out1[(size_t)wid * 128 + 64 + lane] = v1 > 0.f ? v1 : 0.f;
}

// -------- layer 2 aggregate: wave per node, +b2, sigmoid --------
__global__ void agg2_kernel(const float* __restrict__ h2, const float* __restrict__ as2,
                            const float* __restrict__ ad2, const float* __restrict__ b2,
                            const int* __restrict__ offsets, const int* __restrict__ csr_src,
                            float* __restrict__ out) {
    int wid = (blockIdx.x * blockDim.x + threadIdx.x) >> 6;
    if (wid >= N_NODES) return;
    int lane = threadIdx.x & 63;
    float da = ad2[wid];
    int jb = offsets[wid], je = offsets[wid + 1];
    float acc = 0.f, sum = 0.f;
    for (int j = jb; j < je; ++j) {
        int s = csr_src[j];
        float w = expf(lrelu(as2[s] + da));
        acc += w * h2[(size_t)s * 64 + lane];
        sum += w;
    }
    float v = acc / sum + b2[lane];
    out[(size_t)wid * 64 + lane] = 1.f / (1.f + expf(-v));
}

extern "C" void kernel_launch(void* const* d_in, const int* in_sizes, int n_in,
                              void* d_out, int out_size, void* d_ws, size_t ws_size,
                              hipStream_t stream) {
    const float* x     = (const float*)d_in[0];
    const int*   ei    = (const int*)d_in[1];
    const float* W1    = (const float*)d_in[2];
    const float* asrc1 = (const float*)d_in[3];
    const float* adst1 = (const float*)d_in[4];
    const float* b1    = (const float*)d_in[5];
    const float* W2    = (const float*)d_in[6];
    const float* asrc2 = (const float*)d_in[7];
    const float* adst2 = (const float*)d_in[8];
    const float* b2    = (const float*)d_in[9];
    float* out = (float*)d_out;

    float* ws = (float*)d_ws;
    size_t off = 0;
    float* h1   = ws + off; off += (size_t)N_NODES * 128;
    float* out1 = ws + off; off += (size_t)N_NODES * 128;
    float* h2   = ws + off; off += (size_t)N_NODES * 64;
    float* as1  = ws + off; off += (size_t)N_NODES * 2;
    float* ad1  = ws + off; off += (size_t)N_NODES * 2;
    float* as2  = ws + off; off += (size_t)N_NODES;
    float* ad2  = ws + off; off += (size_t)N_NODES;
    int* ibuf    = (int*)(ws + off);
    int* deg     = ibuf;
    int* offsets = deg + N_NODES;
    int* cursor  = offsets + N_NODES + 1;
    int* csr_src = cursor + N_NODES;
    int* bsum    = csr_src + E_TOT;
    int* bbase   = bsum + NB_SCAN;

    hipMemsetAsync(deg, 0, N_NODES * sizeof(int), stream);

    gemm1_kernel<<<(N_NODES + 31) / 32, 256, 0, stream>>>(x, W1, h1);
    alphas1_kernel<<<(N_NODES * 64 + 255) / 256, 256, 0, stream>>>(h1, asrc1, adst1, as1, ad1);
    hist_kernel<<<(E_TOT + 255) / 256, 256, 0, stream>>>(ei, deg);
    scanA_kernel<<<NB_SCAN, 256, 0, stream>>>(deg, bsum);
    scanB_kernel<<<1, 256, 0, stream>>>(bsum, bbase, offsets);
    scanC_kernel<<<NB_SCAN, 256, 0, stream>>>(deg, bbase, offsets, cursor);
    scatter_kernel<<<(E_TOT + 255) / 256, 256, 0, stream>>>(ei, cursor, csr_src);
    agg1_kernel<<<(N_NODES * 64 + 255) / 256, 256, 0, stream>>>(h1, as1, ad1, b1, offsets, csr_src, out1);
    gemm2_kernel<<<(N_NODES + 63) / 64, 256, 0, stream>>>(out1, W2, h2);
    alphas2_kernel<<<(N_NODES * 64 + 255) / 256, 256, 0, stream>>>(h2, asrc2, adst2, as2, ad2);
    agg2_kernel<<<(N_NODES * 64 + 255) / 256, 256, 0, stream>>>(h2, as2, ad2, b2, offsets, csr_src, out);
}

// Round 4
// 392.132 us; speedup vs baseline: 1.7001x; 1.1611x over previous
//
#include <hip/hip_runtime.h>
#include <math.h>

#define N_NODES 50000
#define N_EDGES 800000
#define E_TOT   (N_EDGES + N_NODES)
#define NEG_SLOPE 0.2f
#define NB_SCAN ((N_NODES + 255) / 256)   // 196 scan blocks

static __device__ __forceinline__ float lrelu(float v) {
    return v > 0.0f ? v : NEG_SLOPE * v;
}

// -------- GEMM 1: h1[N,128] = x[N,128] @ W1[128,128] --------
__global__ __launch_bounds__(256, 2) void gemm1_kernel(const float* __restrict__ x,
                                                       const float* __restrict__ W,
                                                       float* __restrict__ h) {
    __shared__ float ws[128 * 128];  // 64 KB
    __shared__ float xs[32 * 128];   // 16 KB
    int tid = threadIdx.x;
    int r0 = blockIdx.x * 32;

#pragma unroll
    for (int i = 0; i < 16; ++i) {
        int idx = i * 1024 + tid * 4;
        *(float4*)&ws[idx] = *(const float4*)&W[idx];
    }
    {
        int row = tid >> 3;            // 0..31
        int kb = (tid & 7) * 16;
        int grow = r0 + row;
        if (grow >= N_NODES) grow = N_NODES - 1;
        const float* xp = x + (size_t)grow * 128 + kb;
        float* xd = &xs[row * 128 + kb];
        *(float4*)(xd + 0)  = *(const float4*)(xp + 0);
        *(float4*)(xd + 4)  = *(const float4*)(xp + 4);
        *(float4*)(xd + 8)  = *(const float4*)(xp + 8);
        *(float4*)(xd + 12) = *(const float4*)(xp + 12);
    }
    __syncthreads();

    int colg = (tid & 31) * 4;
    int rowg = (tid >> 5) * 4;
    float4 acc0 = {0, 0, 0, 0}, acc1 = {0, 0, 0, 0}, acc2 = {0, 0, 0, 0}, acc3 = {0, 0, 0, 0};

#pragma unroll 8
    for (int k4 = 0; k4 < 32; ++k4) {
        int kb = k4 * 4;
        float4 w0 = *(float4*)&ws[(kb + 0) * 128 + colg];
        float4 w1 = *(float4*)&ws[(kb + 1) * 128 + colg];
        float4 w2 = *(float4*)&ws[(kb + 2) * 128 + colg];
        float4 w3 = *(float4*)&ws[(kb + 3) * 128 + colg];
        float4 xv;
#define ROWSTEP(ACC, R)                                                              \
        xv = *(float4*)&xs[(rowg + R) * 128 + kb];                                   \
        ACC.x += xv.x * w0.x + xv.y * w1.x + xv.z * w2.x + xv.w * w3.x;              \
        ACC.y += xv.x * w0.y + xv.y * w1.y + xv.z * w2.y + xv.w * w3.y;              \
        ACC.z += xv.x * w0.z + xv.y * w1.z + xv.z * w2.z + xv.w * w3.z;              \
        ACC.w += xv.x * w0.w + xv.y * w1.w + xv.z * w2.w + xv.w * w3.w;
        ROWSTEP(acc0, 0) ROWSTEP(acc1, 1) ROWSTEP(acc2, 2) ROWSTEP(acc3, 3)
#undef ROWSTEP
    }

    if (r0 + rowg + 0 < N_NODES) *(float4*)&h[(size_t)(r0 + rowg + 0) * 128 + colg] = acc0;
    if (r0 + rowg + 1 < N_NODES) *(float4*)&h[(size_t)(r0 + rowg + 1) * 128 + colg] = acc1;
    if (r0 + rowg + 2 < N_NODES) *(float4*)&h[(size_t)(r0 + rowg + 2) * 128 + colg] = acc2;
    if (r0 + rowg + 3 < N_NODES) *(float4*)&h[(size_t)(r0 + rowg + 3) * 128 + colg] = acc3;
}

// -------- GEMM 2: h2[N,64] = out1[N,128] @ W2[128,64] --------
__global__ __launch_bounds__(256, 2) void gemm2_kernel(const float* __restrict__ x,
                                                       const float* __restrict__ W,
                                                       float* __restrict__ h) {
    __shared__ float ws[128 * 64];   // 32 KB
    __shared__ float xs[64 * 128];   // 32 KB
    int tid = threadIdx.x;
    int r0 = blockIdx.x * 64;

#pragma unroll
    for (int i = 0; i < 8; ++i) {
        int idx = i * 1024 + tid * 4;
        *(float4*)&ws[idx] = *(const float4*)&W[idx];
    }
    {
        int row = tid >> 2;            // 0..63
        int kb = (tid & 3) * 32;
        int grow = r0 + row;
        if (grow >= N_NODES) grow = N_NODES - 1;
        const float* xp = x + (size_t)grow * 128 + kb;
        float* xd = &xs[row * 128 + kb];
#pragma unroll
        for (int i = 0; i < 8; ++i)
            *(float4*)(xd + i * 4) = *(const float4*)(xp + i * 4);
    }
    __syncthreads();

    int colg = (tid & 15) * 4;
    int rowg = (tid >> 4) * 4;
    float4 acc0 = {0, 0, 0, 0}, acc1 = {0, 0, 0, 0}, acc2 = {0, 0, 0, 0}, acc3 = {0, 0, 0, 0};

#pragma unroll 8
    for (int k4 = 0; k4 < 32; ++k4) {
        int kb = k4 * 4;
        float4 w0 = *(float4*)&ws[(kb + 0) * 64 + colg];
        float4 w1 = *(float4*)&ws[(kb + 1) * 64 + colg];
        float4 w2 = *(float4*)&ws[(kb + 2) * 64 + colg];
        float4 w3 = *(float4*)&ws[(kb + 3) * 64 + colg];
        float4 xv;
#define ROWSTEP(ACC, R)                                                              \
        xv = *(float4*)&xs[(rowg + R) * 128 + kb];                                   \
        ACC.x += xv.x * w0.x + xv.y * w1.x + xv.z * w2.x + xv.w * w3.x;              \
        ACC.y += xv.x * w0.y + xv.y * w1.y + xv.z * w2.y + xv.w * w3.y;              \
        ACC.z += xv.x * w0.z + xv.y * w1.z + xv.z * w2.z + xv.w * w3.z;              \
        ACC.w += xv.x * w0.w + xv.y * w1.w + xv.z * w2.w + xv.w * w3.w;
        ROWSTEP(acc0, 0) ROWSTEP(acc1, 1) ROWSTEP(acc2, 2) ROWSTEP(acc3, 3)
#undef ROWSTEP
    }

    if (r0 + rowg + 0 < N_NODES) *(float4*)&h[(size_t)(r0 + rowg + 0) * 64 + colg] = acc0;
    if (r0 + rowg + 1 < N_NODES) *(float4*)&h[(size_t)(r0 + rowg + 1) * 64 + colg] = acc1;
    if (r0 + rowg + 2 < N_NODES) *(float4*)&h[(size_t)(r0 + rowg + 2) * 64 + colg] = acc2;
    if (r0 + rowg + 3 < N_NODES) *(float4*)&h[(size_t)(r0 + rowg + 3) * 64 + colg] = acc3;
}

// -------- alpha_src/alpha_dst for layer 1 (2 heads, 64 ch) --------
__global__ void alphas1_kernel(const float* __restrict__ h1, const float* __restrict__ a_src,
                               const float* __restrict__ a_dst,
                               float* __restrict__ as, float* __restrict__ ad) {
    int wid = (blockIdx.x * blockDim.x + threadIdx.x) >> 6;
    if (wid >= N_NODES) return;
    int lane = threadIdx.x & 63;
    float h0 = h1[(size_t)wid * 128 + lane];
    float h1v = h1[(size_t)wid * 128 + 64 + lane];
    float s0 = h0 * a_src[lane], s1 = h1v * a_src[64 + lane];
    float d0 = h0 * a_dst[lane], d1 = h1v * a_dst[64 + lane];
    for (int off = 32; off > 0; off >>= 1) {
        s0 += __shfl_down(s0, off, 64);
        s1 += __shfl_down(s1, off, 64);
        d0 += __shfl_down(d0, off, 64);
        d1 += __shfl_down(d1, off, 64);
    }
    if (lane == 0) {
        as[wid * 2] = s0; as[wid * 2 + 1] = s1;
        ad[wid * 2] = d0; ad[wid * 2 + 1] = d1;
    }
}

// -------- alpha_src/alpha_dst for layer 2 (1 head, 64 ch) --------
__global__ void alphas2_kernel(const float* __restrict__ h2, const float* __restrict__ a_src,
                               const float* __restrict__ a_dst,
                               float* __restrict__ as, float* __restrict__ ad) {
    int wid = (blockIdx.x * blockDim.x + threadIdx.x) >> 6;
    if (wid >= N_NODES) return;
    int lane = threadIdx.x & 63;
    float h0 = h2[(size_t)wid * 64 + lane];
    float s0 = h0 * a_src[lane];
    float d0 = h0 * a_dst[lane];
    for (int off = 32; off > 0; off >>= 1) {
        s0 += __shfl_down(s0, off, 64);
        d0 += __shfl_down(d0, off, 64);
    }
    if (lane == 0) { as[wid] = s0; ad[wid] = d0; }
}

// -------- CSR build: histogram over dst --------
__global__ void hist_kernel(const int* __restrict__ ei, int* __restrict__ deg) {
    int tid = blockIdx.x * blockDim.x + threadIdx.x;
    if (tid >= E_TOT) return;
    int d = (tid < N_EDGES) ? ei[N_EDGES + tid] : (tid - N_EDGES);
    atomicAdd(&deg[d], 1);
}

// -------- scan phase A: per-block reduce of deg -> bsum[NB_SCAN] --------
__global__ void scanA_kernel(const int* __restrict__ deg, int* __restrict__ bsum) {
    __shared__ int red[256];
    int t = threadIdx.x;
    int i = blockIdx.x * 256 + t;
    red[t] = (i < N_NODES) ? deg[i] : 0;
    __syncthreads();
#pragma unroll
    for (int off = 128; off > 0; off >>= 1) {
        if (t < off) red[t] += red[t + off];
        __syncthreads();
    }
    if (t == 0) bsum[blockIdx.x] = red[0];
}

// -------- scan phase B: exclusive scan of bsum -> bbase; offsets[N]=E_TOT --------
__global__ void scanB_kernel(const int* __restrict__ bsum, int* __restrict__ bbase,
                             int* __restrict__ offsets) {
    __shared__ int s[256];
    int t = threadIdx.x;
    int v = (t < NB_SCAN) ? bsum[t] : 0;
    s[t] = v;
    __syncthreads();
#pragma unroll
    for (int off = 1; off < 256; off <<= 1) {
        int u = (t >= off) ? s[t - off] : 0;
        __syncthreads();
        s[t] += u;
        __syncthreads();
    }
    if (t < NB_SCAN) bbase[t] = s[t] - v;   // exclusive
    if (t == 0) offsets[N_NODES] = E_TOT;
}

// -------- scan phase C: block-local exclusive scan + bbase -> offsets, cursor --------
__global__ void scanC_kernel(const int* __restrict__ deg, const int* __restrict__ bbase,
                             int* __restrict__ offsets, int* __restrict__ cursor) {
    __shared__ int s[256];
    int t = threadIdx.x;
    int i = blockIdx.x * 256 + t;
    int v = (i < N_NODES) ? deg[i] : 0;
    s[t] = v;
    __syncthreads();
#pragma unroll
    for (int off = 1; off < 256; off <<= 1) {
        int u = (t >= off) ? s[t - off] : 0;
        __syncthreads();
        s[t] += u;
        __syncthreads();
    }
    if (i < N_NODES) {
        int excl = s[t] - v + bbase[blockIdx.x];
        offsets[i] = excl;
        cursor[i] = excl;
    }
}

// -------- CSR build: scatter src ids into dst-sorted order --------
__global__ void scatter_kernel(const int* __restrict__ ei, int* __restrict__ cursor,
                               int* __restrict__ csr_src) {
    int tid = blockIdx.x * blockDim.x + threadIdx.x;
    if (tid >= E_TOT) return;
    int s, d;
    if (tid < N_EDGES) { s = ei[tid]; d = ei[N_EDGES + tid]; }
    else { s = d = tid - N_EDGES; }
    int pos = atomicAdd(&cursor[d], 1);
    csr_src[pos] = s;
}

// -------- layer 1 aggregate: wave per node, lane-batched weights + shfl broadcast.
// Lane l owns channels (2l, 2l+1): lanes 0-31 = head 0, lanes 32-63 = head 1.
__global__ void agg1_kernel(const float* __restrict__ h1, const float* __restrict__ as1,
                            const float* __restrict__ ad1, const float* __restrict__ b1,
                            const int* __restrict__ offsets, const int* __restrict__ csr_src,
                            float* __restrict__ out1) {
    int wid = (blockIdx.x * blockDim.x + threadIdx.x) >> 6;
    if (wid >= N_NODES) return;
    int lane = threadIdx.x & 63;
    float da0 = ad1[wid * 2 + 0], da1 = ad1[wid * 2 + 1];
    int jb = offsets[wid], je = offsets[wid + 1];
    float acc0 = 0.f, acc1 = 0.f;
    float psum0 = 0.f, psum1 = 0.f;

    for (int chunk = jb; chunk < je; chunk += 64) {
        int j = chunk + lane;
        int s = 0; float w0 = 0.f, w1 = 0.f;
        if (j < je) {
            s = csr_src[j];                       // coalesced batch load
            float2 av = *(const float2*)&as1[s * 2];
            w0 = __expf(lrelu(av.x + da0));       // one exp per edge, not per lane
            w1 = __expf(lrelu(av.y + da1));
        }
        psum0 += w0; psum1 += w1;
        int cnt = je - chunk; if (cnt > 64) cnt = 64;
        for (int k = 0; k < cnt; ++k) {
            int   ss  = __shfl(s, k, 64);
            float bw0 = __shfl(w0, k, 64);
            float bw1 = __shfl(w1, k, 64);
            float bw  = (lane < 32) ? bw0 : bw1;
            float2 hv = *(const float2*)&h1[(size_t)ss * 128 + lane * 2];
            acc0 += bw * hv.x;
            acc1 += bw * hv.y;
        }
    }
    // wave-wide softmax denominators (butterfly -> all lanes hold totals)
#pragma unroll
    for (int m = 1; m < 64; m <<= 1) {
        psum0 += __shfl_xor(psum0, m, 64);
        psum1 += __shfl_xor(psum1, m, 64);
    }
    float inv = 1.f / ((lane < 32) ? psum0 : psum1);
    float2 bv = *(const float2*)&b1[lane * 2];
    float v0 = acc0 * inv + bv.x;
    float v1 = acc1 * inv + bv.y;
    v0 = v0 > 0.f ? v0 : 0.f;
    v1 = v1 > 0.f ? v1 : 0.f;
    *(float2*)&out1[(size_t)wid * 128 + lane * 2] = make_float2(v0, v1);
}

// -------- layer 2 aggregate: same structure, 1 head, sigmoid epilogue --------
__global__ void agg2_kernel(const float* __restrict__ h2, const float* __restrict__ as2,
                            const float* __restrict__ ad2, const float* __restrict__ b2,
                            const int* __restrict__ offsets, const int* __restrict__ csr_src,
                            float* __restrict__ out) {
    int wid = (blockIdx.x * blockDim.x + threadIdx.x) >> 6;
    if (wid >= N_NODES) return;
    int lane = threadIdx.x & 63;
    float da = ad2[wid];
    int jb = offsets[wid], je = offsets[wid + 1];
    float acc = 0.f, psum = 0.f;

    for (int chunk = jb; chunk < je; chunk += 64) {
        int j = chunk + lane;
        int s = 0; float w = 0.f;
        if (j < je) {
            s = csr_src[j];
            w = __expf(lrelu(as2[s] + da));
        }
        psum += w;
        int cnt = je - chunk; if (cnt > 64) cnt = 64;
        for (int k = 0; k < cnt; ++k) {
            int   ss = __shfl(s, k, 64);
            float bw = __shfl(w, k, 64);
            acc += bw * h2[(size_t)ss * 64 + lane];
        }
    }
#pragma unroll
    for (int m = 1; m < 64; m <<= 1) psum += __shfl_xor(psum, m, 64);
    float v = acc / psum + b2[lane];
    out[(size_t)wid * 64 + lane] = 1.f / (1.f + __expf(-v));
}

extern "C" void kernel_launch(void* const* d_in, const int* in_sizes, int n_in,
                              void* d_out, int out_size, void* d_ws, size_t ws_size,
                              hipStream_t stream) {
    const float* x     = (const float*)d_in[0];
    const int*   ei    = (const int*)d_in[1];
    const float* W1    = (const float*)d_in[2];
    const float* asrc1 = (const float*)d_in[3];
    const float* adst1 = (const float*)d_in[4];
    const float* b1    = (const float*)d_in[5];
    const float* W2    = (const float*)d_in[6];
    const float* asrc2 = (const float*)d_in[7];
    const float* adst2 = (const float*)d_in[8];
    const float* b2    = (const float*)d_in[9];
    float* out = (float*)d_out;

    float* ws = (float*)d_ws;
    size_t off = 0;
    float* h1   = ws + off; off += (size_t)N_NODES * 128;
    float* out1 = ws + off; off += (size_t)N_NODES * 128;
    float* h2   = ws + off; off += (size_t)N_NODES * 64;
    float* as1  = ws + off; off += (size_t)N_NODES * 2;
    float* ad1  = ws + off; off += (size_t)N_NODES * 2;
    float* as2  = ws + off; off += (size_t)N_NODES;
    float* ad2  = ws + off; off += (size_t)N_NODES;
    int* ibuf    = (int*)(ws + off);
    int* deg     = ibuf;
    int* offsets = deg + N_NODES;
    int* cursor  = offsets + N_NODES + 1;
    int* csr_src = cursor + N_NODES;
    int* bsum    = csr_src + E_TOT;
    int* bbase   = bsum + NB_SCAN;

    hipMemsetAsync(deg, 0, N_NODES * sizeof(int), stream);

    gemm1_kernel<<<(N_NODES + 31) / 32, 256, 0, stream>>>(x, W1, h1);
    alphas1_kernel<<<(N_NODES * 64 + 255) / 256, 256, 0, stream>>>(h1, asrc1, adst1, as1, ad1);
    hist_kernel<<<(E_TOT + 255) / 256, 256, 0, stream>>>(ei, deg);
    scanA_kernel<<<NB_SCAN, 256, 0, stream>>>(deg, bsum);
    scanB_kernel<<<1, 256, 0, stream>>>(bsum, bbase, offsets);
    scanC_kernel<<<NB_SCAN, 256, 0, stream>>>(deg, bbase, offsets, cursor);
    scatter_kernel<<<(E_TOT + 255) / 256, 256, 0, stream>>>(ei, cursor, csr_src);
    agg1_kernel<<<(N_NODES * 64 + 255) / 256, 256, 0, stream>>>(h1, as1, ad1, b1, offsets, csr_src, out1);
    gemm2_kernel<<<(N_NODES + 63) / 64, 256, 0, stream>>>(out1, W2, h2);
    alphas2_kernel<<<(N_NODES * 64 + 255) / 256, 256, 0, stream>>>(h2, asrc2, adst2, as2, ad2);
    agg2_kernel<<<(N_NODES * 64 + 255) / 256, 256, 0, stream>>>(h2, as2, ad2, b2, offsets, csr_src, out);
}

// Round 5
// 341.392 us; speedup vs baseline: 1.9527x; 1.1486x over previous
//
#include <hip/hip_runtime.h>
#include <math.h>

#define N_NODES 50000
#define N_EDGES 800000
#define E_TOT   (N_EDGES + N_NODES)
#define NEG_SLOPE 0.2f
#define NB_SCAN ((N_NODES + 255) / 256)   // 196 scan blocks

static __device__ __forceinline__ float lrelu(float v) {
    return v > 0.0f ? v : NEG_SLOPE * v;
}

// round-to-nearest-even fp32 -> bf16
static __device__ __forceinline__ unsigned short f2bf(float f) {
    unsigned b = __float_as_uint(f);
    return (unsigned short)((b + 0x7fffu + ((b >> 16) & 1u)) >> 16);
}

// -------- GEMM 1 + fused alphas1: h1b[N,128](bf16), as1/ad1[N,2] --------
// block = 32 rows x 128 cols, W1 (64KB) + x-tile (16KB) in LDS.
// Thread = 4 rows x 4 cols. Epilogue: per-row dot with a_src/a_dst via
// width-32 xor-shuffle reduction (32 col-threads per row group).
__global__ __launch_bounds__(256, 2) void gemm1_kernel(const float* __restrict__ x,
                                                       const float* __restrict__ W,
                                                       const float* __restrict__ a_src,
                                                       const float* __restrict__ a_dst,
                                                       unsigned short* __restrict__ h1b,
                                                       float* __restrict__ as_out,
                                                       float* __restrict__ ad_out) {
    __shared__ float ws[128 * 128];  // 64 KB
    __shared__ float xs[32 * 128];   // 16 KB
    int tid = threadIdx.x;
    int r0 = blockIdx.x * 32;

#pragma unroll
    for (int i = 0; i < 16; ++i) {
        int idx = i * 1024 + tid * 4;
        *(float4*)&ws[idx] = *(const float4*)&W[idx];
    }
    {
        int row = tid >> 3;            // 0..31
        int kb = (tid & 7) * 16;
        int grow = r0 + row;
        if (grow >= N_NODES) grow = N_NODES - 1;
        const float* xp = x + (size_t)grow * 128 + kb;
        float* xd = &xs[row * 128 + kb];
        *(float4*)(xd + 0)  = *(const float4*)(xp + 0);
        *(float4*)(xd + 4)  = *(const float4*)(xp + 4);
        *(float4*)(xd + 8)  = *(const float4*)(xp + 8);
        *(float4*)(xd + 12) = *(const float4*)(xp + 12);
    }
    __syncthreads();

    int colg = (tid & 31) * 4;
    int rowg = (tid >> 5) * 4;
    float4 acc[4] = {{0,0,0,0},{0,0,0,0},{0,0,0,0},{0,0,0,0}};

#pragma unroll 8
    for (int k4 = 0; k4 < 32; ++k4) {
        int kb = k4 * 4;
        float4 w0 = *(float4*)&ws[(kb + 0) * 128 + colg];
        float4 w1 = *(float4*)&ws[(kb + 1) * 128 + colg];
        float4 w2 = *(float4*)&ws[(kb + 2) * 128 + colg];
        float4 w3 = *(float4*)&ws[(kb + 3) * 128 + colg];
#pragma unroll
        for (int R = 0; R < 4; ++R) {
            float4 xv = *(float4*)&xs[(rowg + R) * 128 + kb];
            acc[R].x += xv.x * w0.x + xv.y * w1.x + xv.z * w2.x + xv.w * w3.x;
            acc[R].y += xv.x * w0.y + xv.y * w1.y + xv.z * w2.y + xv.w * w3.y;
            acc[R].z += xv.x * w0.z + xv.y * w1.z + xv.z * w2.z + xv.w * w3.z;
            acc[R].w += xv.x * w0.w + xv.y * w1.w + xv.z * w2.w + xv.w * w3.w;
        }
    }

    // ---- bf16 store of h ----
#pragma unroll
    for (int R = 0; R < 4; ++R) {
        int gr = r0 + rowg + R;
        if (gr < N_NODES) {
            ushort4 p;
            p.x = f2bf(acc[R].x); p.y = f2bf(acc[R].y);
            p.z = f2bf(acc[R].z); p.w = f2bf(acc[R].w);
            *(ushort4*)&h1b[(size_t)gr * 128 + colg] = p;
        }
    }

    // ---- fused alphas: per-row dots, reduced over the 32 col-threads ----
    float4 asv = *(const float4*)&a_src[colg];   // a_src flat [128] = (H=2, 64)
    float4 adv = *(const float4*)&a_dst[colg];
    bool low = (colg < 64);                      // head 0 columns
    float vals[16];
#pragma unroll
    for (int R = 0; R < 4; ++R) {
        float ps = acc[R].x * asv.x + acc[R].y * asv.y + acc[R].z * asv.z + acc[R].w * asv.w;
        float pd = acc[R].x * adv.x + acc[R].y * adv.y + acc[R].z * adv.z + acc[R].w * adv.w;
        vals[R * 4 + 0] = low ? ps : 0.f;
        vals[R * 4 + 1] = low ? 0.f : ps;
        vals[R * 4 + 2] = low ? pd : 0.f;
        vals[R * 4 + 3] = low ? 0.f : pd;
    }
#pragma unroll
    for (int m = 1; m < 32; m <<= 1) {
#pragma unroll
        for (int i = 0; i < 16; ++i) vals[i] += __shfl_xor(vals[i], m, 32);
    }
    if ((tid & 31) == 0) {
#pragma unroll
        for (int R = 0; R < 4; ++R) {
            int gr = r0 + rowg + R;
            if (gr < N_NODES) {
                as_out[gr * 2 + 0] = vals[R * 4 + 0];
                as_out[gr * 2 + 1] = vals[R * 4 + 1];
                ad_out[gr * 2 + 0] = vals[R * 4 + 2];
                ad_out[gr * 2 + 1] = vals[R * 4 + 3];
            }
        }
    }
}

// -------- GEMM 2 + fused alphas2: h2b[N,64](bf16), as2/ad2[N] --------
// block = 64 rows x 64 cols, W2 (32KB) + x-tile (32KB) in LDS.
__global__ __launch_bounds__(256, 2) void gemm2_kernel(const float* __restrict__ x,
                                                       const float* __restrict__ W,
                                                       const float* __restrict__ a_src,
                                                       const float* __restrict__ a_dst,
                                                       unsigned short* __restrict__ h2b,
                                                       float* __restrict__ as_out,
                                                       float* __restrict__ ad_out) {
    __shared__ float ws[128 * 64];   // 32 KB
    __shared__ float xs[64 * 128];   // 32 KB
    int tid = threadIdx.x;
    int r0 = blockIdx.x * 64;

#pragma unroll
    for (int i = 0; i < 8; ++i) {
        int idx = i * 1024 + tid * 4;
        *(float4*)&ws[idx] = *(const float4*)&W[idx];
    }
    {
        int row = tid >> 2;            // 0..63
        int kb = (tid & 3) * 32;
        int grow = r0 + row;
        if (grow >= N_NODES) grow = N_NODES - 1;
        const float* xp = x + (size_t)grow * 128 + kb;
        float* xd = &xs[row * 128 + kb];
#pragma unroll
        for (int i = 0; i < 8; ++i)
            *(float4*)(xd + i * 4) = *(const float4*)(xp + i * 4);
    }
    __syncthreads();

    int colg = (tid & 15) * 4;
    int rowg = (tid >> 4) * 4;
    float4 acc[4] = {{0,0,0,0},{0,0,0,0},{0,0,0,0},{0,0,0,0}};

#pragma unroll 8
    for (int k4 = 0; k4 < 32; ++k4) {
        int kb = k4 * 4;
        float4 w0 = *(float4*)&ws[(kb + 0) * 64 + colg];
        float4 w1 = *(float4*)&ws[(kb + 1) * 64 + colg];
        float4 w2 = *(float4*)&ws[(kb + 2) * 64 + colg];
        float4 w3 = *(float4*)&ws[(kb + 3) * 64 + colg];
#pragma unroll
        for (int R = 0; R < 4; ++R) {
            float4 xv = *(float4*)&xs[(rowg + R) * 128 + kb];
            acc[R].x += xv.x * w0.x + xv.y * w1.x + xv.z * w2.x + xv.w * w3.x;
            acc[R].y += xv.x * w0.y + xv.y * w1.y + xv.z * w2.y + xv.w * w3.y;
            acc[R].z += xv.x * w0.z + xv.y * w1.z + xv.z * w2.z + xv.w * w3.z;
            acc[R].w += xv.x * w0.w + xv.y * w1.w + xv.z * w2.w + xv.w * w3.w;
        }
    }

#pragma unroll
    for (int R = 0; R < 4; ++R) {
        int gr = r0 + rowg + R;
        if (gr < N_NODES) {
            ushort4 p;
            p.x = f2bf(acc[R].x); p.y = f2bf(acc[R].y);
            p.z = f2bf(acc[R].z); p.w = f2bf(acc[R].w);
            *(ushort4*)&h2b[(size_t)gr * 64 + colg] = p;
        }
    }

    float4 asv = *(const float4*)&a_src[colg];
    float4 adv = *(const float4*)&a_dst[colg];
    float vals[8];
#pragma unroll
    for (int R = 0; R < 4; ++R) {
        vals[R * 2 + 0] = acc[R].x * asv.x + acc[R].y * asv.y + acc[R].z * asv.z + acc[R].w * asv.w;
        vals[R * 2 + 1] = acc[R].x * adv.x + acc[R].y * adv.y + acc[R].z * adv.z + acc[R].w * adv.w;
    }
#pragma unroll
    for (int m = 1; m < 16; m <<= 1) {
#pragma unroll
        for (int i = 0; i < 8; ++i) vals[i] += __shfl_xor(vals[i], m, 16);
    }
    if ((tid & 15) == 0) {
#pragma unroll
        for (int R = 0; R < 4; ++R) {
            int gr = r0 + rowg + R;
            if (gr < N_NODES) {
                as_out[gr] = vals[R * 2 + 0];
                ad_out[gr] = vals[R * 2 + 1];
            }
        }
    }
}

// -------- CSR build: histogram over dst --------
__global__ void hist_kernel(const int* __restrict__ ei, int* __restrict__ deg) {
    int tid = blockIdx.x * blockDim.x + threadIdx.x;
    if (tid >= E_TOT) return;
    int d = (tid < N_EDGES) ? ei[N_EDGES + tid] : (tid - N_EDGES);
    atomicAdd(&deg[d], 1);
}

// -------- scan phase A: per-block reduce of deg -> bsum[NB_SCAN] --------
__global__ void scanA_kernel(const int* __restrict__ deg, int* __restrict__ bsum) {
    __shared__ int red[256];
    int t = threadIdx.x;
    int i = blockIdx.x * 256 + t;
    red[t] = (i < N_NODES) ? deg[i] : 0;
    __syncthreads();
#pragma unroll
    for (int off = 128; off > 0; off >>= 1) {
        if (t < off) red[t] += red[t + off];
        __syncthreads();
    }
    if (t == 0) bsum[blockIdx.x] = red[0];
}

// -------- scan phase B: exclusive scan of bsum -> bbase; offsets[N]=E_TOT --------
__global__ void scanB_kernel(const int* __restrict__ bsum, int* __restrict__ bbase,
                             int* __restrict__ offsets) {
    __shared__ int s[256];
    int t = threadIdx.x;
    int v = (t < NB_SCAN) ? bsum[t] : 0;
    s[t] = v;
    __syncthreads();
#pragma unroll
    for (int off = 1; off < 256; off <<= 1) {
        int u = (t >= off) ? s[t - off] : 0;
        __syncthreads();
        s[t] += u;
        __syncthreads();
    }
    if (t < NB_SCAN) bbase[t] = s[t] - v;   // exclusive
    if (t == 0) offsets[N_NODES] = E_TOT;
}

// -------- scan phase C: block-local exclusive scan + bbase -> offsets, cursor --------
__global__ void scanC_kernel(const int* __restrict__ deg, const int* __restrict__ bbase,
                             int* __restrict__ offsets, int* __restrict__ cursor) {
    __shared__ int s[256];
    int t = threadIdx.x;
    int i = blockIdx.x * 256 + t;
    int v = (i < N_NODES) ? deg[i] : 0;
    s[t] = v;
    __syncthreads();
#pragma unroll
    for (int off = 1; off < 256; off <<= 1) {
        int u = (t >= off) ? s[t - off] : 0;
        __syncthreads();
        s[t] += u;
        __syncthreads();
    }
    if (i < N_NODES) {
        int excl = s[t] - v + bbase[blockIdx.x];
        offsets[i] = excl;
        cursor[i] = excl;
    }
}

// -------- CSR build: scatter src ids into dst-sorted order --------
__global__ void scatter_kernel(const int* __restrict__ ei, int* __restrict__ cursor,
                               int* __restrict__ csr_src) {
    int tid = blockIdx.x * blockDim.x + threadIdx.x;
    if (tid >= E_TOT) return;
    int s, d;
    if (tid < N_EDGES) { s = ei[tid]; d = ei[N_EDGES + tid]; }
    else { s = d = tid - N_EDGES; }
    int pos = atomicAdd(&cursor[d], 1);
    csr_src[pos] = s;
}

// -------- layer 1 aggregate: wave/node, bf16 gather (lane = 2 channels) --------
// Lane l owns channels (2l, 2l+1): lanes 0-31 = head 0, lanes 32-63 = head 1.
__global__ void agg1_kernel(const unsigned short* __restrict__ h1b,
                            const float* __restrict__ as1,
                            const float* __restrict__ ad1, const float* __restrict__ b1,
                            const int* __restrict__ offsets, const int* __restrict__ csr_src,
                            float* __restrict__ out1) {
    int wid = (blockIdx.x * blockDim.x + threadIdx.x) >> 6;
    if (wid >= N_NODES) return;
    int lane = threadIdx.x & 63;
    float da0 = ad1[wid * 2 + 0], da1 = ad1[wid * 2 + 1];
    int jb = offsets[wid], je = offsets[wid + 1];
    float acc0 = 0.f, acc1 = 0.f;
    float psum0 = 0.f, psum1 = 0.f;

    for (int chunk = jb; chunk < je; chunk += 64) {
        int j = chunk + lane;
        int s = 0; float w0 = 0.f, w1 = 0.f;
        if (j < je) {
            s = csr_src[j];                       // coalesced batch load
            float2 av = *(const float2*)&as1[s * 2];
            w0 = __expf(lrelu(av.x + da0));       // one exp per edge
            w1 = __expf(lrelu(av.y + da1));
        }
        psum0 += w0; psum1 += w1;
        int cnt = je - chunk; if (cnt > 64) cnt = 64;
        for (int k = 0; k < cnt; ++k) {
            int   ss  = __shfl(s, k, 64);
            float bw0 = __shfl(w0, k, 64);
            float bw1 = __shfl(w1, k, 64);
            float bw  = (lane < 32) ? bw0 : bw1;
            unsigned u = ((const unsigned*)(h1b + (size_t)ss * 128))[lane];  // 2 bf16
            float f0 = __uint_as_float(u << 16);
            float f1 = __uint_as_float(u & 0xffff0000u);
            acc0 += bw * f0;
            acc1 += bw * f1;
        }
    }
#pragma unroll
    for (int m = 1; m < 64; m <<= 1) {
        psum0 += __shfl_xor(psum0, m, 64);
        psum1 += __shfl_xor(psum1, m, 64);
    }
    float inv = 1.f / ((lane < 32) ? psum0 : psum1);
    float2 bv = *(const float2*)&b1[lane * 2];
    float v0 = acc0 * inv + bv.x;
    float v1 = acc1 * inv + bv.y;
    v0 = v0 > 0.f ? v0 : 0.f;
    v1 = v1 > 0.f ? v1 : 0.f;
    *(float2*)&out1[(size_t)wid * 128 + lane * 2] = make_float2(v0, v1);
}

// -------- layer 2 aggregate: wave/node, 2 edges per iteration --------
// Half-wave per edge; lane cl=lane&31 owns channels (2cl, 2cl+1).
__global__ void agg2_kernel(const unsigned short* __restrict__ h2b,
                            const float* __restrict__ as2,
                            const float* __restrict__ ad2, const float* __restrict__ b2,
                            const int* __restrict__ offsets, const int* __restrict__ csr_src,
                            float* __restrict__ out) {
    int wid = (blockIdx.x * blockDim.x + threadIdx.x) >> 6;
    if (wid >= N_NODES) return;
    int lane = threadIdx.x & 63;
    int cl = lane & 31;
    int half = lane >> 5;
    float da = ad2[wid];
    int jb = offsets[wid], je = offsets[wid + 1];
    float acc0 = 0.f, acc1 = 0.f, psum = 0.f;

    for (int chunk = jb; chunk < je; chunk += 64) {
        int j = chunk + lane;
        int s = 0; float w = 0.f;
        if (j < je) {
            s = csr_src[j];
            w = __expf(lrelu(as2[s] + da));
        }
        psum += w;
        int cnt = je - chunk; if (cnt > 64) cnt = 64;
        for (int k = 0; k < cnt; k += 2) {
            int kk = k + half;                    // may be == cnt (w==0, s==0: safe)
            int   ss = __shfl(s, kk, 64);
            float bw = __shfl(w, kk, 64);
            unsigned u = ((const unsigned*)(h2b + (size_t)ss * 64))[cl];
            acc0 += bw * __uint_as_float(u << 16);
            acc1 += bw * __uint_as_float(u & 0xffff0000u);
        }
    }
#pragma unroll
    for (int m = 1; m < 64; m <<= 1) psum += __shfl_xor(psum, m, 64);
    // combine even-edge (lanes 0-31) and odd-edge (lanes 32-63) partials
    float o0 = __shfl(acc0, cl + 32, 64);
    float o1 = __shfl(acc1, cl + 32, 64);
    if (lane < 32) {
        float inv = 1.f / psum;
        float2 bv = *(const float2*)&b2[cl * 2];
        float v0 = (acc0 + o0) * inv + bv.x;
        float v1 = (acc1 + o1) * inv + bv.y;
        v0 = 1.f / (1.f + __expf(-v0));
        v1 = 1.f / (1.f + __expf(-v1));
        *(float2*)&out[(size_t)wid * 64 + cl * 2] = make_float2(v0, v1);
    }
}

extern "C" void kernel_launch(void* const* d_in, const int* in_sizes, int n_in,
                              void* d_out, int out_size, void* d_ws, size_t ws_size,
                              hipStream_t stream) {
    const float* x     = (const float*)d_in[0];
    const int*   ei    = (const int*)d_in[1];
    const float* W1    = (const float*)d_in[2];
    const float* asrc1 = (const float*)d_in[3];
    const float* adst1 = (const float*)d_in[4];
    const float* b1    = (const float*)d_in[5];
    const float* W2    = (const float*)d_in[6];
    const float* asrc2 = (const float*)d_in[7];
    const float* adst2 = (const float*)d_in[8];
    const float* b2    = (const float*)d_in[9];
    float* out = (float*)d_out;

    float* ws = (float*)d_ws;
    size_t off = 0;
    float* out1 = ws + off; off += (size_t)N_NODES * 128;
    float* as1  = ws + off; off += (size_t)N_NODES * 2;
    float* ad1  = ws + off; off += (size_t)N_NODES * 2;
    float* as2  = ws + off; off += (size_t)N_NODES;
    float* ad2  = ws + off; off += (size_t)N_NODES;
    unsigned short* h1b = (unsigned short*)(ws + off); off += (size_t)N_NODES * 64;  // 128 bf16 = 64 floats
    unsigned short* h2b = (unsigned short*)(ws + off); off += (size_t)N_NODES * 32;  // 64 bf16 = 32 floats
    int* deg     = (int*)(ws + off);
    int* offsets = deg + N_NODES;
    int* cursor  = offsets + N_NODES + 1;
    int* csr_src = cursor + N_NODES;
    int* bsum    = csr_src + E_TOT;
    int* bbase   = bsum + NB_SCAN;

    hipMemsetAsync(deg, 0, N_NODES * sizeof(int), stream);

    gemm1_kernel<<<(N_NODES + 31) / 32, 256, 0, stream>>>(x, W1, asrc1, adst1, h1b, as1, ad1);
    hist_kernel<<<(E_TOT + 255) / 256, 256, 0, stream>>>(ei, deg);
    scanA_kernel<<<NB_SCAN, 256, 0, stream>>>(deg, bsum);
    scanB_kernel<<<1, 256, 0, stream>>>(bsum, bbase, offsets);
    scanC_kernel<<<NB_SCAN, 256, 0, stream>>>(deg, bbase, offsets, cursor);
    scatter_kernel<<<(E_TOT + 255) / 256, 256, 0, stream>>>(ei, cursor, csr_src);
    agg1_kernel<<<(N_NODES * 64 + 255) / 256, 256, 0, stream>>>(h1b, as1, ad1, b1, offsets, csr_src, out1);
    gemm2_kernel<<<(N_NODES + 63) / 64, 256, 0, stream>>>(out1, W2, asrc2, adst2, h2b, as2, ad2);
    agg2_kernel<<<(N_NODES * 64 + 255) / 256, 256, 0, stream>>>(h2b, as2, ad2, b2, offsets, csr_src, out);
}

// Round 6
// 312.544 us; speedup vs baseline: 2.1330x; 1.0923x over previous
//
#include <hip/hip_runtime.h>
#include <math.h>

#define N_NODES 50000
#define N_EDGES 800000
#define E_TOT   (N_EDGES + N_NODES)
#define NEG_SLOPE 0.2f
#define NB_SCAN ((N_NODES + 255) / 256)   // 196 scan blocks

static __device__ __forceinline__ float lrelu(float v) {
    return v > 0.0f ? v : NEG_SLOPE * v;
}

// round-to-nearest-even fp32 -> bf16
static __device__ __forceinline__ unsigned short f2bf(float f) {
    unsigned b = __float_as_uint(f);
    return (unsigned short)((b + 0x7fffu + ((b >> 16) & 1u)) >> 16);
}

static __device__ __forceinline__ float bflo(unsigned u) { return __uint_as_float(u << 16); }
static __device__ __forceinline__ float bfhi(unsigned u) { return __uint_as_float(u & 0xffff0000u); }

// -------- GEMM 1 + fused alphas1: h1b[N,128](bf16), as1/ad1[N,2] --------
__global__ __launch_bounds__(256, 2) void gemm1_kernel(const float* __restrict__ x,
                                                       const float* __restrict__ W,
                                                       const float* __restrict__ a_src,
                                                       const float* __restrict__ a_dst,
                                                       unsigned short* __restrict__ h1b,
                                                       float* __restrict__ as_out,
                                                       float* __restrict__ ad_out) {
    __shared__ float ws[128 * 128];  // 64 KB
    __shared__ float xs[32 * 128];   // 16 KB
    int tid = threadIdx.x;
    int r0 = blockIdx.x * 32;

#pragma unroll
    for (int i = 0; i < 16; ++i) {
        int idx = i * 1024 + tid * 4;
        *(float4*)&ws[idx] = *(const float4*)&W[idx];
    }
    {
        int row = tid >> 3;            // 0..31
        int kb = (tid & 7) * 16;
        int grow = r0 + row;
        if (grow >= N_NODES) grow = N_NODES - 1;
        const float* xp = x + (size_t)grow * 128 + kb;
        float* xd = &xs[row * 128 + kb];
        *(float4*)(xd + 0)  = *(const float4*)(xp + 0);
        *(float4*)(xd + 4)  = *(const float4*)(xp + 4);
        *(float4*)(xd + 8)  = *(const float4*)(xp + 8);
        *(float4*)(xd + 12) = *(const float4*)(xp + 12);
    }
    __syncthreads();

    int colg = (tid & 31) * 4;
    int rowg = (tid >> 5) * 4;
    float4 acc[4] = {{0,0,0,0},{0,0,0,0},{0,0,0,0},{0,0,0,0}};

#pragma unroll 8
    for (int k4 = 0; k4 < 32; ++k4) {
        int kb = k4 * 4;
        float4 w0 = *(float4*)&ws[(kb + 0) * 128 + colg];
        float4 w1 = *(float4*)&ws[(kb + 1) * 128 + colg];
        float4 w2 = *(float4*)&ws[(kb + 2) * 128 + colg];
        float4 w3 = *(float4*)&ws[(kb + 3) * 128 + colg];
#pragma unroll
        for (int R = 0; R < 4; ++R) {
            float4 xv = *(float4*)&xs[(rowg + R) * 128 + kb];
            acc[R].x += xv.x * w0.x + xv.y * w1.x + xv.z * w2.x + xv.w * w3.x;
            acc[R].y += xv.x * w0.y + xv.y * w1.y + xv.z * w2.y + xv.w * w3.y;
            acc[R].z += xv.x * w0.z + xv.y * w1.z + xv.z * w2.z + xv.w * w3.z;
            acc[R].w += xv.x * w0.w + xv.y * w1.w + xv.z * w2.w + xv.w * w3.w;
        }
    }

#pragma unroll
    for (int R = 0; R < 4; ++R) {
        int gr = r0 + rowg + R;
        if (gr < N_NODES) {
            ushort4 p;
            p.x = f2bf(acc[R].x); p.y = f2bf(acc[R].y);
            p.z = f2bf(acc[R].z); p.w = f2bf(acc[R].w);
            *(ushort4*)&h1b[(size_t)gr * 128 + colg] = p;
        }
    }

    float4 asv = *(const float4*)&a_src[colg];   // a_src flat [128] = (H=2, 64)
    float4 adv = *(const float4*)&a_dst[colg];
    bool low = (colg < 64);                      // head 0 columns
    float vals[16];
#pragma unroll
    for (int R = 0; R < 4; ++R) {
        float ps = acc[R].x * asv.x + acc[R].y * asv.y + acc[R].z * asv.z + acc[R].w * asv.w;
        float pd = acc[R].x * adv.x + acc[R].y * adv.y + acc[R].z * adv.z + acc[R].w * adv.w;
        vals[R * 4 + 0] = low ? ps : 0.f;
        vals[R * 4 + 1] = low ? 0.f : ps;
        vals[R * 4 + 2] = low ? pd : 0.f;
        vals[R * 4 + 3] = low ? 0.f : pd;
    }
#pragma unroll
    for (int m = 1; m < 32; m <<= 1) {
#pragma unroll
        for (int i = 0; i < 16; ++i) vals[i] += __shfl_xor(vals[i], m, 32);
    }
    if ((tid & 31) == 0) {
#pragma unroll
        for (int R = 0; R < 4; ++R) {
            int gr = r0 + rowg + R;
            if (gr < N_NODES) {
                as_out[gr * 2 + 0] = vals[R * 4 + 0];
                as_out[gr * 2 + 1] = vals[R * 4 + 1];
                ad_out[gr * 2 + 0] = vals[R * 4 + 2];
                ad_out[gr * 2 + 1] = vals[R * 4 + 3];
            }
        }
    }
}

// -------- GEMM 2 + fused alphas2: h2b[N,64](bf16), as2/ad2[N] --------
__global__ __launch_bounds__(256, 2) void gemm2_kernel(const float* __restrict__ x,
                                                       const float* __restrict__ W,
                                                       const float* __restrict__ a_src,
                                                       const float* __restrict__ a_dst,
                                                       unsigned short* __restrict__ h2b,
                                                       float* __restrict__ as_out,
                                                       float* __restrict__ ad_out) {
    __shared__ float ws[128 * 64];   // 32 KB
    __shared__ float xs[64 * 128];   // 32 KB
    int tid = threadIdx.x;
    int r0 = blockIdx.x * 64;

#pragma unroll
    for (int i = 0; i < 8; ++i) {
        int idx = i * 1024 + tid * 4;
        *(float4*)&ws[idx] = *(const float4*)&W[idx];
    }
    {
        int row = tid >> 2;            // 0..63
        int kb = (tid & 3) * 32;
        int grow = r0 + row;
        if (grow >= N_NODES) grow = N_NODES - 1;
        const float* xp = x + (size_t)grow * 128 + kb;
        float* xd = &xs[row * 128 + kb];
#pragma unroll
        for (int i = 0; i < 8; ++i)
            *(float4*)(xd + i * 4) = *(const float4*)(xp + i * 4);
    }
    __syncthreads();

    int colg = (tid & 15) * 4;
    int rowg = (tid >> 4) * 4;
    float4 acc[4] = {{0,0,0,0},{0,0,0,0},{0,0,0,0},{0,0,0,0}};

#pragma unroll 8
    for (int k4 = 0; k4 < 32; ++k4) {
        int kb = k4 * 4;
        float4 w0 = *(float4*)&ws[(kb + 0) * 64 + colg];
        float4 w1 = *(float4*)&ws[(kb + 1) * 64 + colg];
        float4 w2 = *(float4*)&ws[(kb + 2) * 64 + colg];
        float4 w3 = *(float4*)&ws[(kb + 3) * 64 + colg];
#pragma unroll
        for (int R = 0; R < 4; ++R) {
            float4 xv = *(float4*)&xs[(rowg + R) * 128 + kb];
            acc[R].x += xv.x * w0.x + xv.y * w1.x + xv.z * w2.x + xv.w * w3.x;
            acc[R].y += xv.x * w0.y + xv.y * w1.y + xv.z * w2.y + xv.w * w3.y;
            acc[R].z += xv.x * w0.z + xv.y * w1.z + xv.z * w2.z + xv.w * w3.z;
            acc[R].w += xv.x * w0.w + xv.y * w1.w + xv.z * w2.w + xv.w * w3.w;
        }
    }

#pragma unroll
    for (int R = 0; R < 4; ++R) {
        int gr = r0 + rowg + R;
        if (gr < N_NODES) {
            ushort4 p;
            p.x = f2bf(acc[R].x); p.y = f2bf(acc[R].y);
            p.z = f2bf(acc[R].z); p.w = f2bf(acc[R].w);
            *(ushort4*)&h2b[(size_t)gr * 64 + colg] = p;
        }
    }

    float4 asv = *(const float4*)&a_src[colg];
    float4 adv = *(const float4*)&a_dst[colg];
    float vals[8];
#pragma unroll
    for (int R = 0; R < 4; ++R) {
        vals[R * 2 + 0] = acc[R].x * asv.x + acc[R].y * asv.y + acc[R].z * asv.z + acc[R].w * asv.w;
        vals[R * 2 + 1] = acc[R].x * adv.x + acc[R].y * adv.y + acc[R].z * adv.z + acc[R].w * adv.w;
    }
#pragma unroll
    for (int m = 1; m < 16; m <<= 1) {
#pragma unroll
        for (int i = 0; i < 8; ++i) vals[i] += __shfl_xor(vals[i], m, 16);
    }
    if ((tid & 15) == 0) {
#pragma unroll
        for (int R = 0; R < 4; ++R) {
            int gr = r0 + rowg + R;
            if (gr < N_NODES) {
                as_out[gr] = vals[R * 2 + 0];
                ad_out[gr] = vals[R * 2 + 1];
            }
        }
    }
}

// -------- CSR build: histogram over dst --------
__global__ void hist_kernel(const int* __restrict__ ei, int* __restrict__ deg) {
    int tid = blockIdx.x * blockDim.x + threadIdx.x;
    if (tid >= E_TOT) return;
    int d = (tid < N_EDGES) ? ei[N_EDGES + tid] : (tid - N_EDGES);
    atomicAdd(&deg[d], 1);
}

// -------- scan phase A --------
__global__ void scanA_kernel(const int* __restrict__ deg, int* __restrict__ bsum) {
    __shared__ int red[256];
    int t = threadIdx.x;
    int i = blockIdx.x * 256 + t;
    red[t] = (i < N_NODES) ? deg[i] : 0;
    __syncthreads();
#pragma unroll
    for (int off = 128; off > 0; off >>= 1) {
        if (t < off) red[t] += red[t + off];
        __syncthreads();
    }
    if (t == 0) bsum[blockIdx.x] = red[0];
}

// -------- scan phase B --------
__global__ void scanB_kernel(const int* __restrict__ bsum, int* __restrict__ bbase,
                             int* __restrict__ offsets) {
    __shared__ int s[256];
    int t = threadIdx.x;
    int v = (t < NB_SCAN) ? bsum[t] : 0;
    s[t] = v;
    __syncthreads();
#pragma unroll
    for (int off = 1; off < 256; off <<= 1) {
        int u = (t >= off) ? s[t - off] : 0;
        __syncthreads();
        s[t] += u;
        __syncthreads();
    }
    if (t < NB_SCAN) bbase[t] = s[t] - v;   // exclusive
    if (t == 0) offsets[N_NODES] = E_TOT;
}

// -------- scan phase C --------
__global__ void scanC_kernel(const int* __restrict__ deg, const int* __restrict__ bbase,
                             int* __restrict__ offsets, int* __restrict__ cursor) {
    __shared__ int s[256];
    int t = threadIdx.x;
    int i = blockIdx.x * 256 + t;
    int v = (i < N_NODES) ? deg[i] : 0;
    s[t] = v;
    __syncthreads();
#pragma unroll
    for (int off = 1; off < 256; off <<= 1) {
        int u = (t >= off) ? s[t - off] : 0;
        __syncthreads();
        s[t] += u;
        __syncthreads();
    }
    if (i < N_NODES) {
        int excl = s[t] - v + bbase[blockIdx.x];
        offsets[i] = excl;
        cursor[i] = excl;
    }
}

// -------- CSR build: scatter --------
__global__ void scatter_kernel(const int* __restrict__ ei, int* __restrict__ cursor,
                               int* __restrict__ csr_src) {
    int tid = blockIdx.x * blockDim.x + threadIdx.x;
    if (tid >= E_TOT) return;
    int s, d;
    if (tid < N_EDGES) { s = ei[tid]; d = ei[N_EDGES + tid]; }
    else { s = d = tid - N_EDGES; }
    int pos = atomicAdd(&cursor[d], 1);
    csr_src[pos] = s;
}

// -------- layer 1 aggregate: wave/node, bf16 gather, 4 edges in flight --------
// Lane l owns channels (2l, 2l+1): lanes 0-31 = head 0, lanes 32-63 = head 1.
// Tail safety: lanes with j>=je hold s=0,w=0, so broadcasting k+i in [cnt,64)
// contributes 0 (junk load of row 0 is L1-hot).
__global__ void agg1_kernel(const unsigned short* __restrict__ h1b,
                            const float* __restrict__ as1,
                            const float* __restrict__ ad1, const float* __restrict__ b1,
                            const int* __restrict__ offsets, const int* __restrict__ csr_src,
                            float* __restrict__ out1) {
    int wid = (blockIdx.x * blockDim.x + threadIdx.x) >> 6;
    if (wid >= N_NODES) return;
    int lane = threadIdx.x & 63;
    float da0 = ad1[wid * 2 + 0], da1 = ad1[wid * 2 + 1];
    int jb = offsets[wid], je = offsets[wid + 1];
    float acc0 = 0.f, acc1 = 0.f;
    float psum0 = 0.f, psum1 = 0.f;

    for (int chunk = jb; chunk < je; chunk += 64) {
        int j = chunk + lane;
        int s = 0; float w0 = 0.f, w1 = 0.f;
        if (j < je) {
            s = csr_src[j];                       // coalesced batch load
            float2 av = *(const float2*)&as1[s * 2];
            w0 = __expf(lrelu(av.x + da0));
            w1 = __expf(lrelu(av.y + da1));
        }
        psum0 += w0; psum1 += w1;
        int cnt = je - chunk; if (cnt > 64) cnt = 64;
        for (int k = 0; k < cnt; k += 4) {
            int ss0 = __shfl(s, k + 0, 64);
            int ss1 = __shfl(s, k + 1, 64);
            int ss2 = __shfl(s, k + 2, 64);
            int ss3 = __shfl(s, k + 3, 64);
            unsigned u0 = ((const unsigned*)(h1b + (size_t)ss0 * 128))[lane];
            unsigned u1 = ((const unsigned*)(h1b + (size_t)ss1 * 128))[lane];
            unsigned u2 = ((const unsigned*)(h1b + (size_t)ss2 * 128))[lane];
            unsigned u3 = ((const unsigned*)(h1b + (size_t)ss3 * 128))[lane];
            float p0 = __shfl(w0, k + 0, 64), q0 = __shfl(w1, k + 0, 64);
            float p1 = __shfl(w0, k + 1, 64), q1 = __shfl(w1, k + 1, 64);
            float p2 = __shfl(w0, k + 2, 64), q2 = __shfl(w1, k + 2, 64);
            float p3 = __shfl(w0, k + 3, 64), q3 = __shfl(w1, k + 3, 64);
            float bw0 = (lane < 32) ? p0 : q0;
            float bw1 = (lane < 32) ? p1 : q1;
            float bw2 = (lane < 32) ? p2 : q2;
            float bw3 = (lane < 32) ? p3 : q3;
            acc0 += bw0 * bflo(u0); acc1 += bw0 * bfhi(u0);
            acc0 += bw1 * bflo(u1); acc1 += bw1 * bfhi(u1);
            acc0 += bw2 * bflo(u2); acc1 += bw2 * bfhi(u2);
            acc0 += bw3 * bflo(u3); acc1 += bw3 * bfhi(u3);
        }
    }
#pragma unroll
    for (int m = 1; m < 64; m <<= 1) {
        psum0 += __shfl_xor(psum0, m, 64);
        psum1 += __shfl_xor(psum1, m, 64);
    }
    float inv = 1.f / ((lane < 32) ? psum0 : psum1);
    float2 bv = *(const float2*)&b1[lane * 2];
    float v0 = acc0 * inv + bv.x;
    float v1 = acc1 * inv + bv.y;
    v0 = v0 > 0.f ? v0 : 0.f;
    v1 = v1 > 0.f ? v1 : 0.f;
    *(float2*)&out1[(size_t)wid * 128 + lane * 2] = make_float2(v0, v1);
}

// -------- layer 2 aggregate: half-wave/edge, 8 edges per iteration --------
// Lane cl=lane&31 owns channels (2cl, 2cl+1); half 0 takes even k, half 1 odd.
__global__ void agg2_kernel(const unsigned short* __restrict__ h2b,
                            const float* __restrict__ as2,
                            const float* __restrict__ ad2, const float* __restrict__ b2,
                            const int* __restrict__ offsets, const int* __restrict__ csr_src,
                            float* __restrict__ out) {
    int wid = (blockIdx.x * blockDim.x + threadIdx.x) >> 6;
    if (wid >= N_NODES) return;
    int lane = threadIdx.x & 63;
    int cl = lane & 31;
    int half = lane >> 5;
    float da = ad2[wid];
    int jb = offsets[wid], je = offsets[wid + 1];
    float acc0 = 0.f, acc1 = 0.f, psum = 0.f;

    for (int chunk = jb; chunk < je; chunk += 64) {
        int j = chunk + lane;
        int s = 0; float w = 0.f;
        if (j < je) {
            s = csr_src[j];
            w = __expf(lrelu(as2[s] + da));
        }
        psum += w;
        int cnt = je - chunk; if (cnt > 64) cnt = 64;
        for (int k = 0; k < cnt; k += 8) {
            int k0 = k + half, k1 = k + 2 + half, k2 = k + 4 + half, k3 = k + 6 + half;
            int ss0 = __shfl(s, k0, 64);
            int ss1 = __shfl(s, k1, 64);
            int ss2 = __shfl(s, k2, 64);
            int ss3 = __shfl(s, k3, 64);
            unsigned u0 = ((const unsigned*)(h2b + (size_t)ss0 * 64))[cl];
            unsigned u1 = ((const unsigned*)(h2b + (size_t)ss1 * 64))[cl];
            unsigned u2 = ((const unsigned*)(h2b + (size_t)ss2 * 64))[cl];
            unsigned u3 = ((const unsigned*)(h2b + (size_t)ss3 * 64))[cl];
            float bw0 = __shfl(w, k0, 64);
            float bw1 = __shfl(w, k1, 64);
            float bw2 = __shfl(w, k2, 64);
            float bw3 = __shfl(w, k3, 64);
            acc0 += bw0 * bflo(u0); acc1 += bw0 * bfhi(u0);
            acc0 += bw1 * bflo(u1); acc1 += bw1 * bfhi(u1);
            acc0 += bw2 * bflo(u2); acc1 += bw2 * bfhi(u2);
            acc0 += bw3 * bflo(u3); acc1 += bw3 * bfhi(u3);
        }
    }
#pragma unroll
    for (int m = 1; m < 64; m <<= 1) psum += __shfl_xor(psum, m, 64);
    // combine even-edge (lanes 0-31) and odd-edge (lanes 32-63) partials
    float o0 = __shfl(acc0, cl + 32, 64);
    float o1 = __shfl(acc1, cl + 32, 64);
    if (lane < 32) {
        float inv = 1.f / psum;
        float2 bv = *(const float2*)&b2[cl * 2];
        float v0 = (acc0 + o0) * inv + bv.x;
        float v1 = (acc1 + o1) * inv + bv.y;
        v0 = 1.f / (1.f + __expf(-v0));
        v1 = 1.f / (1.f + __expf(-v1));
        *(float2*)&out[(size_t)wid * 64 + cl * 2] = make_float2(v0, v1);
    }
}

extern "C" void kernel_launch(void* const* d_in, const int* in_sizes, int n_in,
                              void* d_out, int out_size, void* d_ws, size_t ws_size,
                              hipStream_t stream) {
    const float* x     = (const float*)d_in[0];
    const int*   ei    = (const int*)d_in[1];
    const float* W1    = (const float*)d_in[2];
    const float* asrc1 = (const float*)d_in[3];
    const float* adst1 = (const float*)d_in[4];
    const float* b1    = (const float*)d_in[5];
    const float* W2    = (const float*)d_in[6];
    const float* asrc2 = (const float*)d_in[7];
    const float* adst2 = (const float*)d_in[8];
    const float* b2    = (const float*)d_in[9];
    float* out = (float*)d_out;

    float* ws = (float*)d_ws;
    size_t off = 0;
    float* out1 = ws + off; off += (size_t)N_NODES * 128;
    float* as1  = ws + off; off += (size_t)N_NODES * 2;
    float* ad1  = ws + off; off += (size_t)N_NODES * 2;
    float* as2  = ws + off; off += (size_t)N_NODES;
    float* ad2  = ws + off; off += (size_t)N_NODES;
    unsigned short* h1b = (unsigned short*)(ws + off); off += (size_t)N_NODES * 64;  // 128 bf16
    unsigned short* h2b = (unsigned short*)(ws + off); off += (size_t)N_NODES * 32;  // 64 bf16
    int* deg     = (int*)(ws + off);
    int* offsets = deg + N_NODES;
    int* cursor  = offsets + N_NODES + 1;
    int* csr_src = cursor + N_NODES;
    int* bsum    = csr_src + E_TOT;
    int* bbase   = bsum + NB_SCAN;

    hipMemsetAsync(deg, 0, N_NODES * sizeof(int), stream);

    gemm1_kernel<<<(N_NODES + 31) / 32, 256, 0, stream>>>(x, W1, asrc1, adst1, h1b, as1, ad1);
    hist_kernel<<<(E_TOT + 255) / 256, 256, 0, stream>>>(ei, deg);
    scanA_kernel<<<NB_SCAN, 256, 0, stream>>>(deg, bsum);
    scanB_kernel<<<1, 256, 0, stream>>>(bsum, bbase, offsets);
    scanC_kernel<<<NB_SCAN, 256, 0, stream>>>(deg, bbase, offsets, cursor);
    scatter_kernel<<<(E_TOT + 255) / 256, 256, 0, stream>>>(ei, cursor, csr_src);
    agg1_kernel<<<(N_NODES * 64 + 255) / 256, 256, 0, stream>>>(h1b, as1, ad1, b1, offsets, csr_src, out1);
    gemm2_kernel<<<(N_NODES + 63) / 64, 256, 0, stream>>>(out1, W2, asrc2, adst2, h2b, as2, ad2);
    agg2_kernel<<<(N_NODES * 64 + 255) / 256, 256, 0, stream>>>(h2b, as2, ad2, b2, offsets, csr_src, out);
}

// Round 7
// 261.733 us; speedup vs baseline: 2.5471x; 1.1941x over previous
//
#include <hip/hip_runtime.h>
#include <math.h>

#define N_NODES 50000
#define N_EDGES 800000
#define E_TOT   (N_EDGES + N_NODES)
#define NEG_SLOPE 0.2f
#define NB_BKT  ((N_NODES + 255) / 256)   // 196 dst-buckets of 256 nodes
#define P1_CHUNK 4096
#define NB_P1   ((E_TOT + P1_CHUNK - 1) / P1_CHUNK)   // 208 pass-1 blocks

static __device__ __forceinline__ float lrelu(float v) {
    return v > 0.0f ? v : NEG_SLOPE * v;
}

// round-to-nearest-even fp32 -> bf16
static __device__ __forceinline__ unsigned short f2bf(float f) {
    unsigned b = __float_as_uint(f);
    return (unsigned short)((b + 0x7fffu + ((b >> 16) & 1u)) >> 16);
}

static __device__ __forceinline__ float bflo(unsigned u) { return __uint_as_float(u << 16); }
static __device__ __forceinline__ float bfhi(unsigned u) { return __uint_as_float(u & 0xffff0000u); }

// -------- GEMM 1 + fused alphas1: h1b[N,128](bf16), as1/ad1[N,2] --------
__global__ __launch_bounds__(256, 2) void gemm1_kernel(const float* __restrict__ x,
                                                       const float* __restrict__ W,
                                                       const float* __restrict__ a_src,
                                                       const float* __restrict__ a_dst,
                                                       unsigned short* __restrict__ h1b,
                                                       float* __restrict__ as_out,
                                                       float* __restrict__ ad_out) {
    __shared__ float ws[128 * 128];  // 64 KB
    __shared__ float xs[32 * 128];   // 16 KB
    int tid = threadIdx.x;
    int r0 = blockIdx.x * 32;

#pragma unroll
    for (int i = 0; i < 16; ++i) {
        int idx = i * 1024 + tid * 4;
        *(float4*)&ws[idx] = *(const float4*)&W[idx];
    }
    {
        int row = tid >> 3;            // 0..31
        int kb = (tid & 7) * 16;
        int grow = r0 + row;
        if (grow >= N_NODES) grow = N_NODES - 1;
        const float* xp = x + (size_t)grow * 128 + kb;
        float* xd = &xs[row * 128 + kb];
        *(float4*)(xd + 0)  = *(const float4*)(xp + 0);
        *(float4*)(xd + 4)  = *(const float4*)(xp + 4);
        *(float4*)(xd + 8)  = *(const float4*)(xp + 8);
        *(float4*)(xd + 12) = *(const float4*)(xp + 12);
    }
    __syncthreads();

    int colg = (tid & 31) * 4;
    int rowg = (tid >> 5) * 4;
    float4 acc[4] = {{0,0,0,0},{0,0,0,0},{0,0,0,0},{0,0,0,0}};

#pragma unroll 8
    for (int k4 = 0; k4 < 32; ++k4) {
        int kb = k4 * 4;
        float4 w0 = *(float4*)&ws[(kb + 0) * 128 + colg];
        float4 w1 = *(float4*)&ws[(kb + 1) * 128 + colg];
        float4 w2 = *(float4*)&ws[(kb + 2) * 128 + colg];
        float4 w3 = *(float4*)&ws[(kb + 3) * 128 + colg];
#pragma unroll
        for (int R = 0; R < 4; ++R) {
            float4 xv = *(float4*)&xs[(rowg + R) * 128 + kb];
            acc[R].x += xv.x * w0.x + xv.y * w1.x + xv.z * w2.x + xv.w * w3.x;
            acc[R].y += xv.x * w0.y + xv.y * w1.y + xv.z * w2.y + xv.w * w3.y;
            acc[R].z += xv.x * w0.z + xv.y * w1.z + xv.z * w2.z + xv.w * w3.z;
            acc[R].w += xv.x * w0.w + xv.y * w1.w + xv.z * w2.w + xv.w * w3.w;
        }
    }

#pragma unroll
    for (int R = 0; R < 4; ++R) {
        int gr = r0 + rowg + R;
        if (gr < N_NODES) {
            ushort4 p;
            p.x = f2bf(acc[R].x); p.y = f2bf(acc[R].y);
            p.z = f2bf(acc[R].z); p.w = f2bf(acc[R].w);
            *(ushort4*)&h1b[(size_t)gr * 128 + colg] = p;
        }
    }

    float4 asv = *(const float4*)&a_src[colg];   // a_src flat [128] = (H=2, 64)
    float4 adv = *(const float4*)&a_dst[colg];
    bool low = (colg < 64);                      // head 0 columns
    float vals[16];
#pragma unroll
    for (int R = 0; R < 4; ++R) {
        float ps = acc[R].x * asv.x + acc[R].y * asv.y + acc[R].z * asv.z + acc[R].w * asv.w;
        float pd = acc[R].x * adv.x + acc[R].y * adv.y + acc[R].z * adv.z + acc[R].w * adv.w;
        vals[R * 4 + 0] = low ? ps : 0.f;
        vals[R * 4 + 1] = low ? 0.f : ps;
        vals[R * 4 + 2] = low ? pd : 0.f;
        vals[R * 4 + 3] = low ? 0.f : pd;
    }
#pragma unroll
    for (int m = 1; m < 32; m <<= 1) {
#pragma unroll
        for (int i = 0; i < 16; ++i) vals[i] += __shfl_xor(vals[i], m, 32);
    }
    if ((tid & 31) == 0) {
#pragma unroll
        for (int R = 0; R < 4; ++R) {
            int gr = r0 + rowg + R;
            if (gr < N_NODES) {
                as_out[gr * 2 + 0] = vals[R * 4 + 0];
                as_out[gr * 2 + 1] = vals[R * 4 + 1];
                ad_out[gr * 2 + 0] = vals[R * 4 + 2];
                ad_out[gr * 2 + 1] = vals[R * 4 + 3];
            }
        }
    }
}

// -------- GEMM 2 + fused alphas2: h2b[N,64](bf16), as2/ad2[N] --------
__global__ __launch_bounds__(256, 2) void gemm2_kernel(const float* __restrict__ x,
                                                       const float* __restrict__ W,
                                                       const float* __restrict__ a_src,
                                                       const float* __restrict__ a_dst,
                                                       unsigned short* __restrict__ h2b,
                                                       float* __restrict__ as_out,
                                                       float* __restrict__ ad_out) {
    __shared__ float ws[128 * 64];   // 32 KB
    __shared__ float xs[64 * 128];   // 32 KB
    int tid = threadIdx.x;
    int r0 = blockIdx.x * 64;

#pragma unroll
    for (int i = 0; i < 8; ++i) {
        int idx = i * 1024 + tid * 4;
        *(float4*)&ws[idx] = *(const float4*)&W[idx];
    }
    {
        int row = tid >> 2;            // 0..63
        int kb = (tid & 3) * 32;
        int grow = r0 + row;
        if (grow >= N_NODES) grow = N_NODES - 1;
        const float* xp = x + (size_t)grow * 128 + kb;
        float* xd = &xs[row * 128 + kb];
#pragma unroll
        for (int i = 0; i < 8; ++i)
            *(float4*)(xd + i * 4) = *(const float4*)(xp + i * 4);
    }
    __syncthreads();

    int colg = (tid & 15) * 4;
    int rowg = (tid >> 4) * 4;
    float4 acc[4] = {{0,0,0,0},{0,0,0,0},{0,0,0,0},{0,0,0,0}};

#pragma unroll 8
    for (int k4 = 0; k4 < 32; ++k4) {
        int kb = k4 * 4;
        float4 w0 = *(float4*)&ws[(kb + 0) * 64 + colg];
        float4 w1 = *(float4*)&ws[(kb + 1) * 64 + colg];
        float4 w2 = *(float4*)&ws[(kb + 2) * 64 + colg];
        float4 w3 = *(float4*)&ws[(kb + 3) * 64 + colg];
#pragma unroll
        for (int R = 0; R < 4; ++R) {
            float4 xv = *(float4*)&xs[(rowg + R) * 128 + kb];
            acc[R].x += xv.x * w0.x + xv.y * w1.x + xv.z * w2.x + xv.w * w3.x;
            acc[R].y += xv.x * w0.y + xv.y * w1.y + xv.z * w2.y + xv.w * w3.y;
            acc[R].z += xv.x * w0.z + xv.y * w1.z + xv.z * w2.z + xv.w * w3.z;
            acc[R].w += xv.x * w0.w + xv.y * w1.w + xv.z * w2.w + xv.w * w3.w;
        }
    }

#pragma unroll
    for (int R = 0; R < 4; ++R) {
        int gr = r0 + rowg + R;
        if (gr < N_NODES) {
            ushort4 p;
            p.x = f2bf(acc[R].x); p.y = f2bf(acc[R].y);
            p.z = f2bf(acc[R].z); p.w = f2bf(acc[R].w);
            *(ushort4*)&h2b[(size_t)gr * 64 + colg] = p;
        }
    }

    float4 asv = *(const float4*)&a_src[colg];
    float4 adv = *(const float4*)&a_dst[colg];
    float vals[8];
#pragma unroll
    for (int R = 0; R < 4; ++R) {
        vals[R * 2 + 0] = acc[R].x * asv.x + acc[R].y * asv.y + acc[R].z * asv.z + acc[R].w * asv.w;
        vals[R * 2 + 1] = acc[R].x * adv.x + acc[R].y * adv.y + acc[R].z * adv.z + acc[R].w * adv.w;
    }
#pragma unroll
    for (int m = 1; m < 16; m <<= 1) {
#pragma unroll
        for (int i = 0; i < 8; ++i) vals[i] += __shfl_xor(vals[i], m, 16);
    }
    if ((tid & 15) == 0) {
#pragma unroll
        for (int R = 0; R < 4; ++R) {
            int gr = r0 + rowg + R;
            if (gr < N_NODES) {
                as_out[gr] = vals[R * 2 + 0];
                ad_out[gr] = vals[R * 2 + 1];
            }
        }
    }
}

// -------- CSR build pass 0: coarse per-bucket histogram (LDS-aggregated) --------
__global__ void coarse_hist_kernel(const int* __restrict__ ei, int* __restrict__ bcnt) {
    __shared__ int bins[NB_BKT];
    int tid = threadIdx.x;
    for (int i = tid; i < NB_BKT; i += 256) bins[i] = 0;
    __syncthreads();
    int base = blockIdx.x * P1_CHUNK;
    for (int i = tid; i < P1_CHUNK; i += 256) {
        int e = base + i;
        if (e >= E_TOT) break;
        int d = (e < N_EDGES) ? ei[N_EDGES + e] : (e - N_EDGES);
        atomicAdd(&bins[d >> 8], 1);          // LDS atomic
    }
    __syncthreads();
    for (int i = tid; i < NB_BKT; i += 256)
        if (bins[i]) atomicAdd(&bcnt[i], bins[i]);
}

// -------- CSR build: scan 196 bucket counts -> bstart[197], bucketcur --------
__global__ void bucket_scan_kernel(const int* __restrict__ bcnt, int* __restrict__ bstart,
                                   int* __restrict__ bucketcur, int* __restrict__ offsets) {
    __shared__ int s[256];
    int t = threadIdx.x;
    int v = (t < NB_BKT) ? bcnt[t] : 0;
    s[t] = v;
    __syncthreads();
#pragma unroll
    for (int off = 1; off < 256; off <<= 1) {
        int u = (t >= off) ? s[t - off] : 0;
        __syncthreads();
        s[t] += u;
        __syncthreads();
    }
    if (t < NB_BKT) {
        int excl = s[t] - v;
        bstart[t] = excl;
        bucketcur[t] = excl;
    }
    if (t == 0) {
        bstart[NB_BKT] = E_TOT;
        offsets[N_NODES] = E_TOT;
    }
}

// -------- CSR build pass 1: bucket-binned scatter of (src,dst) pairs --------
// Per block: LDS histogram, ONE global atomic per touched bucket, then
// contiguous writes per bucket run (write amplification ~1).
__global__ void scatterP1_kernel(const int* __restrict__ ei, int* __restrict__ bucketcur,
                                 uint2* __restrict__ pairs) {
    __shared__ int cnt[NB_BKT];
    __shared__ int base[NB_BKT];
    int tid = threadIdx.x;
    for (int i = tid; i < NB_BKT; i += 256) cnt[i] = 0;
    __syncthreads();
    int cbase = blockIdx.x * P1_CHUNK;
    for (int i = tid; i < P1_CHUNK; i += 256) {
        int e = cbase + i;
        if (e >= E_TOT) break;
        int d = (e < N_EDGES) ? ei[N_EDGES + e] : (e - N_EDGES);
        atomicAdd(&cnt[d >> 8], 1);
    }
    __syncthreads();
    for (int i = tid; i < NB_BKT; i += 256) {
        int c = cnt[i];
        base[i] = c ? atomicAdd(&bucketcur[i], c) : 0;
        cnt[i] = 0;
    }
    __syncthreads();
    for (int i = tid; i < P1_CHUNK; i += 256) {
        int e = cbase + i;
        if (e >= E_TOT) break;
        int s, d;
        if (e < N_EDGES) { s = ei[e]; d = ei[N_EDGES + e]; }
        else { s = d = e - N_EDGES; }
        int bk = d >> 8;
        int p = base[bk] + atomicAdd(&cnt[bk], 1);
        pairs[p] = make_uint2((unsigned)s, (unsigned)d);
    }
}

// -------- CSR build pass 2: per-bucket node scan + place; writes offsets + csr_src --------
// One block per bucket (<=256 nodes). All cursors in LDS; csr_src lines are
// written exclusively by this block -> full-line writes.
__global__ void scatterP2_kernel(const uint2* __restrict__ pairs, const int* __restrict__ bstart,
                                 int* __restrict__ offsets, int* __restrict__ csr_src) {
    __shared__ int cnt[256];
    __shared__ int scn[256];
    int t = threadIdx.x;
    int b = blockIdx.x;
    int node0 = b << 8;
    int start = bstart[b], end = bstart[b + 1];
    cnt[t] = 0;
    __syncthreads();
    for (int j = start + t; j < end; j += 256)
        atomicAdd(&cnt[pairs[j].y - node0], 1);
    __syncthreads();
    int v = cnt[t];
    scn[t] = v;
    __syncthreads();
#pragma unroll
    for (int off = 1; off < 256; off <<= 1) {
        int u = (t >= off) ? scn[t - off] : 0;
        __syncthreads();
        scn[t] += u;
        __syncthreads();
    }
    int excl = start + scn[t] - v;
    if (node0 + t < N_NODES) offsets[node0 + t] = excl;
    cnt[t] = excl;                       // repurpose as cursor
    __syncthreads();
    for (int j = start + t; j < end; j += 256) {
        uint2 pr = pairs[j];
        int p = atomicAdd(&cnt[pr.y - node0], 1);
        csr_src[p] = (int)pr.x;
    }
}

// -------- layer 1 aggregate: wave/node, bf16 gather, 4 edges in flight --------
__global__ void agg1_kernel(const unsigned short* __restrict__ h1b,
                            const float* __restrict__ as1,
                            const float* __restrict__ ad1, const float* __restrict__ b1,
                            const int* __restrict__ offsets, const int* __restrict__ csr_src,
                            float* __restrict__ out1) {
    int wid = (blockIdx.x * blockDim.x + threadIdx.x) >> 6;
    if (wid >= N_NODES) return;
    int lane = threadIdx.x & 63;
    float da0 = ad1[wid * 2 + 0], da1 = ad1[wid * 2 + 1];
    int jb = offsets[wid], je = offsets[wid + 1];
    float acc0 = 0.f, acc1 = 0.f;
    float psum0 = 0.f, psum1 = 0.f;

    for (int chunk = jb; chunk < je; chunk += 64) {
        int j = chunk + lane;
        int s = 0; float w0 = 0.f, w1 = 0.f;
        if (j < je) {
            s = csr_src[j];                       // coalesced batch load
            float2 av = *(const float2*)&as1[s * 2];
            w0 = __expf(lrelu(av.x + da0));
            w1 = __expf(lrelu(av.y + da1));
        }
        psum0 += w0; psum1 += w1;
        int cnt = je - chunk; if (cnt > 64) cnt = 64;
        for (int k = 0; k < cnt; k += 4) {
            int ss0 = __shfl(s, k + 0, 64);
            int ss1 = __shfl(s, k + 1, 64);
            int ss2 = __shfl(s, k + 2, 64);
            int ss3 = __shfl(s, k + 3, 64);
            unsigned u0 = ((const unsigned*)(h1b + (size_t)ss0 * 128))[lane];
            unsigned u1 = ((const unsigned*)(h1b + (size_t)ss1 * 128))[lane];
            unsigned u2 = ((const unsigned*)(h1b + (size_t)ss2 * 128))[lane];
            unsigned u3 = ((const unsigned*)(h1b + (size_t)ss3 * 128))[lane];
            float p0 = __shfl(w0, k + 0, 64), q0 = __shfl(w1, k + 0, 64);
            float p1 = __shfl(w0, k + 1, 64), q1 = __shfl(w1, k + 1, 64);
            float p2 = __shfl(w0, k + 2, 64), q2 = __shfl(w1, k + 2, 64);
            float p3 = __shfl(w0, k + 3, 64), q3 = __shfl(w1, k + 3, 64);
            float bw0 = (lane < 32) ? p0 : q0;
            float bw1 = (lane < 32) ? p1 : q1;
            float bw2 = (lane < 32) ? p2 : q2;
            float bw3 = (lane < 32) ? p3 : q3;
            acc0 += bw0 * bflo(u0); acc1 += bw0 * bfhi(u0);
            acc0 += bw1 * bflo(u1); acc1 += bw1 * bfhi(u1);
            acc0 += bw2 * bflo(u2); acc1 += bw2 * bfhi(u2);
            acc0 += bw3 * bflo(u3); acc1 += bw3 * bfhi(u3);
        }
    }
#pragma unroll
    for (int m = 1; m < 64; m <<= 1) {
        psum0 += __shfl_xor(psum0, m, 64);
        psum1 += __shfl_xor(psum1, m, 64);
    }
    float inv = 1.f / ((lane < 32) ? psum0 : psum1);
    float2 bv = *(const float2*)&b1[lane * 2];
    float v0 = acc0 * inv + bv.x;
    float v1 = acc1 * inv + bv.y;
    v0 = v0 > 0.f ? v0 : 0.f;
    v1 = v1 > 0.f ? v1 : 0.f;
    *(float2*)&out1[(size_t)wid * 128 + lane * 2] = make_float2(v0, v1);
}

// -------- layer 2 aggregate: half-wave/edge, 8 edges per iteration --------
__global__ void agg2_kernel(const unsigned short* __restrict__ h2b,
                            const float* __restrict__ as2,
                            const float* __restrict__ ad2, const float* __restrict__ b2,
                            const int* __restrict__ offsets, const int* __restrict__ csr_src,
                            float* __restrict__ out) {
    int wid = (blockIdx.x * blockDim.x + threadIdx.x) >> 6;
    if (wid >= N_NODES) return;
    int lane = threadIdx.x & 63;
    int cl = lane & 31;
    int half = lane >> 5;
    float da = ad2[wid];
    int jb = offsets[wid], je = offsets[wid + 1];
    float acc0 = 0.f, acc1 = 0.f, psum = 0.f;

    for (int chunk = jb; chunk < je; chunk += 64) {
        int j = chunk + lane;
        int s = 0; float w = 0.f;
        if (j < je) {
            s = csr_src[j];
            w = __expf(lrelu(as2[s] + da));
        }
        psum += w;
        int cnt = je - chunk; if (cnt > 64) cnt = 64;
        for (int k = 0; k < cnt; k += 8) {
            int k0 = k + half, k1 = k + 2 + half, k2 = k + 4 + half, k3 = k + 6 + half;
            int ss0 = __shfl(s, k0, 64);
            int ss1 = __shfl(s, k1, 64);
            int ss2 = __shfl(s, k2, 64);
            int ss3 = __shfl(s, k3, 64);
            unsigned u0 = ((const unsigned*)(h2b + (size_t)ss0 * 64))[cl];
            unsigned u1 = ((const unsigned*)(h2b + (size_t)ss1 * 64))[cl];
            unsigned u2 = ((const unsigned*)(h2b + (size_t)ss2 * 64))[cl];
            unsigned u3 = ((const unsigned*)(h2b + (size_t)ss3 * 64))[cl];
            float bw0 = __shfl(w, k0, 64);
            float bw1 = __shfl(w, k1, 64);
            float bw2 = __shfl(w, k2, 64);
            float bw3 = __shfl(w, k3, 64);
            acc0 += bw0 * bflo(u0); acc1 += bw0 * bfhi(u0);
            acc0 += bw1 * bflo(u1); acc1 += bw1 * bfhi(u1);
            acc0 += bw2 * bflo(u2); acc1 += bw2 * bfhi(u2);
            acc0 += bw3 * bflo(u3); acc1 += bw3 * bfhi(u3);
        }
    }
#pragma unroll
    for (int m = 1; m < 64; m <<= 1) psum += __shfl_xor(psum, m, 64);
    // combine even-edge (lanes 0-31) and odd-edge (lanes 32-63) partials
    float o0 = __shfl(acc0, cl + 32, 64);
    float o1 = __shfl(acc1, cl + 32, 64);
    if (lane < 32) {
        float inv = 1.f / psum;
        float2 bv = *(const float2*)&b2[cl * 2];
        float v0 = (acc0 + o0) * inv + bv.x;
        float v1 = (acc1 + o1) * inv + bv.y;
        v0 = 1.f / (1.f + __expf(-v0));
        v1 = 1.f / (1.f + __expf(-v1));
        *(float2*)&out[(size_t)wid * 64 + cl * 2] = make_float2(v0, v1);
    }
}

extern "C" void kernel_launch(void* const* d_in, const int* in_sizes, int n_in,
                              void* d_out, int out_size, void* d_ws, size_t ws_size,
                              hipStream_t stream) {
    const float* x     = (const float*)d_in[0];
    const int*   ei    = (const int*)d_in[1];
    const float* W1    = (const float*)d_in[2];
    const float* asrc1 = (const float*)d_in[3];
    const float* adst1 = (const float*)d_in[4];
    const float* b1    = (const float*)d_in[5];
    const float* W2    = (const float*)d_in[6];
    const float* asrc2 = (const float*)d_in[7];
    const float* adst2 = (const float*)d_in[8];
    const float* b2    = (const float*)d_in[9];
    float* out = (float*)d_out;

    float* ws = (float*)d_ws;
    size_t off = 0;
    float* out1 = ws + off; off += (size_t)N_NODES * 128;
    float* as1  = ws + off; off += (size_t)N_NODES * 2;
    float* ad1  = ws + off; off += (size_t)N_NODES * 2;
    float* as2  = ws + off; off += (size_t)N_NODES;
    float* ad2  = ws + off; off += (size_t)N_NODES;
    unsigned short* h1b = (unsigned short*)(ws + off); off += (size_t)N_NODES * 64;  // 128 bf16
    unsigned short* h2b = (unsigned short*)(ws + off); off += (size_t)N_NODES * 32;  // 64 bf16
    int* offsets   = (int*)(ws + off);
    int* csr_src   = offsets + N_NODES + 1;
    int* bcnt      = csr_src + E_TOT;
    int* bstart    = bcnt + NB_BKT;
    int* bucketcur = bstart + NB_BKT + 1;
    uint2* pairs   = (uint2*)((((size_t)(bucketcur + NB_BKT)) + 7) & ~(size_t)7);

    hipMemsetAsync(bcnt, 0, NB_BKT * sizeof(int), stream);

    gemm1_kernel<<<(N_NODES + 31) / 32, 256, 0, stream>>>(x, W1, asrc1, adst1, h1b, as1, ad1);
    coarse_hist_kernel<<<NB_P1, 256, 0, stream>>>(ei, bcnt);
    bucket_scan_kernel<<<1, 256, 0, stream>>>(bcnt, bstart, bucketcur, offsets);
    scatterP1_kernel<<<NB_P1, 256, 0, stream>>>(ei, bucketcur, pairs);
    scatterP2_kernel<<<NB_BKT, 256, 0, stream>>>(pairs, bstart, offsets, csr_src);
    agg1_kernel<<<(N_NODES * 64 + 255) / 256, 256, 0, stream>>>(h1b, as1, ad1, b1, offsets, csr_src, out1);
    gemm2_kernel<<<(N_NODES + 63) / 64, 256, 0, stream>>>(out1, W2, asrc2, adst2, h2b, as2, ad2);
    agg2_kernel<<<(N_NODES * 64 + 255) / 256, 256, 0, stream>>>(h2b, as2, ad2, b2, offsets, csr_src, out);
}

// Round 8
// 238.332 us; speedup vs baseline: 2.7971x; 1.0982x over previous
//
#include <hip/hip_runtime.h>
#include <math.h>

#define N_NODES 50000
#define N_EDGES 800000
#define E_TOT   (N_EDGES + N_NODES)
#define NEG_SLOPE 0.2f
#define NB_BKT  ((N_NODES + 255) / 256)   // 196 dst-buckets of 256 nodes
#define P1_CHUNK 4096
#define NB_P1   ((E_TOT + P1_CHUNK - 1) / P1_CHUNK)   // 208 pass-1 blocks
#define NB_G1   ((N_NODES + 127) / 128)   // 391 gemm1 blocks

typedef short bf16x8 __attribute__((ext_vector_type(8)));
typedef float f32x4 __attribute__((ext_vector_type(4)));

static __device__ __forceinline__ float lrelu(float v) {
    return v > 0.0f ? v : NEG_SLOPE * v;
}

// round-to-nearest-even fp32 -> bf16
static __device__ __forceinline__ unsigned short f2bf(float f) {
    unsigned b = __float_as_uint(f);
    return (unsigned short)((b + 0x7fffu + ((b >> 16) & 1u)) >> 16);
}

static __device__ __forceinline__ float bflo(unsigned u) { return __uint_as_float(u << 16); }
static __device__ __forceinline__ float bfhi(unsigned u) { return __uint_as_float(u & 0xffff0000u); }

// LDS index (in ushort units) for element (row, k) of a 128x128 bf16 tile.
// 16B-chunk XOR swizzle: b128 frag reads and staging writes are conflict-free.
static __device__ __forceinline__ int swz(int row, int k) {
    return row * 128 + ((((k >> 3) ^ (row & 15)) << 3) | (k & 7));
}

// -------- GEMM 1 (bf16 MFMA) + fused alphas1: h1b[N,128], as1/ad1[N,2] --------
// Block = 128 rows x 128 cols, 4 waves x (2 m-tiles x 8 n-tiles), K=128 in 4 chunks.
__global__ __launch_bounds__(256, 2) void gemm1_kernel(const float* __restrict__ x,
                                                       const float* __restrict__ W,
                                                       const float* __restrict__ a_src,
                                                       const float* __restrict__ a_dst,
                                                       unsigned short* __restrict__ h1b,
                                                       float* __restrict__ as_out,
                                                       float* __restrict__ ad_out) {
    __shared__ unsigned short xs[128 * 128];  // 32 KB, bf16 swizzled
    __shared__ unsigned short wt[128 * 128];  // 32 KB, W^T bf16 swizzled
    int tid = threadIdx.x;
    int r0 = blockIdx.x * 128;

    // ---- stage W^T: wt[n][k] = W[k][n] (reads coalesced over n) ----
    {
        int n = tid & 127;
        int c0 = (tid >> 7) * 8;
        for (int c = c0; c < c0 + 8; ++c) {
            int kb = c * 8;
            ushort4 lo, hi;
            lo.x = f2bf(W[(kb + 0) * 128 + n]);
            lo.y = f2bf(W[(kb + 1) * 128 + n]);
            lo.z = f2bf(W[(kb + 2) * 128 + n]);
            lo.w = f2bf(W[(kb + 3) * 128 + n]);
            hi.x = f2bf(W[(kb + 4) * 128 + n]);
            hi.y = f2bf(W[(kb + 5) * 128 + n]);
            hi.z = f2bf(W[(kb + 6) * 128 + n]);
            hi.w = f2bf(W[(kb + 7) * 128 + n]);
            int a = swz(n, kb);
            *(ushort4*)&wt[a] = lo;
            *(ushort4*)&wt[a + 4] = hi;
        }
    }
    // ---- stage x rows [r0, r0+128) as bf16 (clamped linear float4 reads) ----
    {
        const int maxe = N_NODES * 128 - 4;
#pragma unroll
        for (int i = 0; i < 16384; i += 1024) {
            int e = i + tid * 4;
            int ge = r0 * 128 + e;
            if (ge > maxe) ge = maxe;
            float4 v = *(const float4*)&x[ge];
            ushort4 p;
            p.x = f2bf(v.x); p.y = f2bf(v.y); p.z = f2bf(v.z); p.w = f2bf(v.w);
            *(ushort4*)&xs[swz(e >> 7, e & 127)] = p;
        }
    }
    __syncthreads();

    int wv = tid >> 6, lane = tid & 63, lm = lane & 15, quad = lane >> 4;
    f32x4 acc[2][8];
#pragma unroll
    for (int m = 0; m < 2; ++m)
#pragma unroll
        for (int n = 0; n < 8; ++n) acc[m][n] = (f32x4){0.f, 0.f, 0.f, 0.f};

#pragma unroll
    for (int kc = 0; kc < 4; ++kc) {
        int kb = kc * 32 + quad * 8;
        bf16x8 a0 = *(bf16x8*)&xs[swz(wv * 32 + lm, kb)];
        bf16x8 a1 = *(bf16x8*)&xs[swz(wv * 32 + 16 + lm, kb)];
#pragma unroll
        for (int nt = 0; nt < 8; ++nt) {
            bf16x8 b = *(bf16x8*)&wt[swz(nt * 16 + lm, kb)];
            acc[0][nt] = __builtin_amdgcn_mfma_f32_16x16x32_bf16(a0, b, acc[0][nt], 0, 0, 0);
            acc[1][nt] = __builtin_amdgcn_mfma_f32_16x16x32_bf16(a1, b, acc[1][nt], 0, 0, 0);
        }
    }

    // ---- fused alphas: per-row dots with a_src/a_dst (head0=cols 0-63) ----
    float asv[8], adv[8];
#pragma unroll
    for (int nt = 0; nt < 8; ++nt) {
        asv[nt] = a_src[nt * 16 + lm];
        adv[nt] = a_dst[nt * 16 + lm];
    }
#pragma unroll
    for (int mt = 0; mt < 2; ++mt) {
#pragma unroll
        for (int r = 0; r < 4; ++r) {
            float s0 = 0.f, s1 = 0.f, d0 = 0.f, d1 = 0.f;
#pragma unroll
            for (int nt = 0; nt < 4; ++nt) {
                s0 += acc[mt][nt][r] * asv[nt];
                d0 += acc[mt][nt][r] * adv[nt];
            }
#pragma unroll
            for (int nt = 4; nt < 8; ++nt) {
                s1 += acc[mt][nt][r] * asv[nt];
                d1 += acc[mt][nt][r] * adv[nt];
            }
#pragma unroll
            for (int m = 1; m < 16; m <<= 1) {
                s0 += __shfl_xor(s0, m, 64);
                s1 += __shfl_xor(s1, m, 64);
                d0 += __shfl_xor(d0, m, 64);
                d1 += __shfl_xor(d1, m, 64);
            }
            if (lm == 0) {
                int gr = r0 + wv * 32 + mt * 16 + quad * 4 + r;
                if (gr < N_NODES) {
                    as_out[gr * 2 + 0] = s0;
                    as_out[gr * 2 + 1] = s1;
                    ad_out[gr * 2 + 0] = d0;
                    ad_out[gr * 2 + 1] = d1;
                }
            }
        }
    }

    // ---- h1b store: repack acc through LDS (reuse xs), then coalesced 16B stores ----
    __syncthreads();
#pragma unroll
    for (int mt = 0; mt < 2; ++mt) {
#pragma unroll
        for (int nt = 0; nt < 8; ++nt) {
#pragma unroll
            for (int r = 0; r < 4; ++r) {
                int lrow = wv * 32 + mt * 16 + quad * 4 + r;
                xs[swz(lrow, nt * 16 + lm)] = f2bf(acc[mt][nt][r]);
            }
        }
    }
    __syncthreads();
    {
        int lrow = tid >> 1;
        int cb = (tid & 1) * 64;
        int gr = r0 + lrow;
        if (gr < N_NODES) {
            unsigned short* dst = h1b + (size_t)gr * 128 + cb;
#pragma unroll
            for (int c = 0; c < 8; ++c)
                *(uint4*)(dst + c * 8) = *(uint4*)&xs[swz(lrow, cb + c * 8)];
        }
    }
}

// -------- GEMM 2 + fused alphas2: h2b[N,64](bf16), as2/ad2[N] --------
__global__ __launch_bounds__(256, 2) void gemm2_kernel(const float* __restrict__ x,
                                                       const float* __restrict__ W,
                                                       const float* __restrict__ a_src,
                                                       const float* __restrict__ a_dst,
                                                       unsigned short* __restrict__ h2b,
                                                       float* __restrict__ as_out,
                                                       float* __restrict__ ad_out) {
    __shared__ float ws[128 * 64];   // 32 KB
    __shared__ float xs[64 * 128];   // 32 KB
    int tid = threadIdx.x;
    int r0 = blockIdx.x * 64;

#pragma unroll
    for (int i = 0; i < 8; ++i) {
        int idx = i * 1024 + tid * 4;
        *(float4*)&ws[idx] = *(const float4*)&W[idx];
    }
    {
        int row = tid >> 2;            // 0..63
        int kb = (tid & 3) * 32;
        int grow = r0 + row;
        if (grow >= N_NODES) grow = N_NODES - 1;
        const float* xp = x + (size_t)grow * 128 + kb;
        float* xd = &xs[row * 128 + kb];
#pragma unroll
        for (int i = 0; i < 8; ++i)
            *(float4*)(xd + i * 4) = *(const float4*)(xp + i * 4);
    }
    __syncthreads();

    int colg = (tid & 15) * 4;
    int rowg = (tid >> 4) * 4;
    float4 acc[4] = {{0,0,0,0},{0,0,0,0},{0,0,0,0},{0,0,0,0}};

#pragma unroll 8
    for (int k4 = 0; k4 < 32; ++k4) {
        int kb = k4 * 4;
        float4 w0 = *(float4*)&ws[(kb + 0) * 64 + colg];
        float4 w1 = *(float4*)&ws[(kb + 1) * 64 + colg];
        float4 w2 = *(float4*)&ws[(kb + 2) * 64 + colg];
        float4 w3 = *(float4*)&ws[(kb + 3) * 64 + colg];
#pragma unroll
        for (int R = 0; R < 4; ++R) {
            float4 xv = *(float4*)&xs[(rowg + R) * 128 + kb];
            acc[R].x += xv.x * w0.x + xv.y * w1.x + xv.z * w2.x + xv.w * w3.x;
            acc[R].y += xv.x * w0.y + xv.y * w1.y + xv.z * w2.y + xv.w * w3.y;
            acc[R].z += xv.x * w0.z + xv.y * w1.z + xv.z * w2.z + xv.w * w3.z;
            acc[R].w += xv.x * w0.w + xv.y * w1.w + xv.z * w2.w + xv.w * w3.w;
        }
    }

#pragma unroll
    for (int R = 0; R < 4; ++R) {
        int gr = r0 + rowg + R;
        if (gr < N_NODES) {
            ushort4 p;
            p.x = f2bf(acc[R].x); p.y = f2bf(acc[R].y);
            p.z = f2bf(acc[R].z); p.w = f2bf(acc[R].w);
            *(ushort4*)&h2b[(size_t)gr * 64 + colg] = p;
        }
    }

    float4 asv = *(const float4*)&a_src[colg];
    float4 adv = *(const float4*)&a_dst[colg];
    float vals[8];
#pragma unroll
    for (int R = 0; R < 4; ++R) {
        vals[R * 2 + 0] = acc[R].x * asv.x + acc[R].y * asv.y + acc[R].z * asv.z + acc[R].w * asv.w;
        vals[R * 2 + 1] = acc[R].x * adv.x + acc[R].y * adv.y + acc[R].z * adv.z + acc[R].w * adv.w;
    }
#pragma unroll
    for (int m = 1; m < 16; m <<= 1) {
#pragma unroll
        for (int i = 0; i < 8; ++i) vals[i] += __shfl_xor(vals[i], m, 16);
    }
    if ((tid & 15) == 0) {
#pragma unroll
        for (int R = 0; R < 4; ++R) {
            int gr = r0 + rowg + R;
            if (gr < N_NODES) {
                as_out[gr] = vals[R * 2 + 0];
                ad_out[gr] = vals[R * 2 + 1];
            }
        }
    }
}

// -------- CSR build pass 0: coarse per-bucket histogram (LDS-aggregated) --------
__global__ void coarse_hist_kernel(const int* __restrict__ ei, int* __restrict__ bcnt) {
    __shared__ int bins[NB_BKT];
    int tid = threadIdx.x;
    for (int i = tid; i < NB_BKT; i += 256) bins[i] = 0;
    __syncthreads();
    int base = blockIdx.x * P1_CHUNK;
    for (int i = tid; i < P1_CHUNK; i += 256) {
        int e = base + i;
        if (e >= E_TOT) break;
        int d = (e < N_EDGES) ? ei[N_EDGES + e] : (e - N_EDGES);
        atomicAdd(&bins[d >> 8], 1);          // LDS atomic
    }
    __syncthreads();
    for (int i = tid; i < NB_BKT; i += 256)
        if (bins[i]) atomicAdd(&bcnt[i], bins[i]);
}

// -------- CSR build: scan 196 bucket counts -> bstart[197], bucketcur --------
__global__ void bucket_scan_kernel(const int* __restrict__ bcnt, int* __restrict__ bstart,
                                   int* __restrict__ bucketcur, int* __restrict__ offsets) {
    __shared__ int s[256];
    int t = threadIdx.x;
    int v = (t < NB_BKT) ? bcnt[t] : 0;
    s[t] = v;
    __syncthreads();
#pragma unroll
    for (int off = 1; off < 256; off <<= 1) {
        int u = (t >= off) ? s[t - off] : 0;
        __syncthreads();
        s[t] += u;
        __syncthreads();
    }
    if (t < NB_BKT) {
        int excl = s[t] - v;
        bstart[t] = excl;
        bucketcur[t] = excl;
    }
    if (t == 0) {
        bstart[NB_BKT] = E_TOT;
        offsets[N_NODES] = E_TOT;
    }
}

// -------- CSR build pass 1: bucket-binned scatter of (src,dst) pairs --------
__global__ void scatterP1_kernel(const int* __restrict__ ei, int* __restrict__ bucketcur,
                                 uint2* __restrict__ pairs) {
    __shared__ int cnt[NB_BKT];
    __shared__ int base[NB_BKT];
    int tid = threadIdx.x;
    for (int i = tid; i < NB_BKT; i += 256) cnt[i] = 0;
    __syncthreads();
    int cbase = blockIdx.x * P1_CHUNK;
    for (int i = tid; i < P1_CHUNK; i += 256) {
        int e = cbase + i;
        if (e >= E_TOT) break;
        int d = (e < N_EDGES) ? ei[N_EDGES + e] : (e - N_EDGES);
        atomicAdd(&cnt[d >> 8], 1);
    }
    __syncthreads();
    for (int i = tid; i < NB_BKT; i += 256) {
        int c = cnt[i];
        base[i] = c ? atomicAdd(&bucketcur[i], c) : 0;
        cnt[i] = 0;
    }
    __syncthreads();
    for (int i = tid; i < P1_CHUNK; i += 256) {
        int e = cbase + i;
        if (e >= E_TOT) break;
        int s, d;
        if (e < N_EDGES) { s = ei[e]; d = ei[N_EDGES + e]; }
        else { s = d = e - N_EDGES; }
        int bk = d >> 8;
        int p = base[bk] + atomicAdd(&cnt[bk], 1);
        pairs[p] = make_uint2((unsigned)s, (unsigned)d);
    }
}

// -------- CSR build pass 2: per-bucket node scan + place --------
__global__ void scatterP2_kernel(const uint2* __restrict__ pairs, const int* __restrict__ bstart,
                                 int* __restrict__ offsets, int* __restrict__ csr_src) {
    __shared__ int cnt[256];
    __shared__ int scn[256];
    int t = threadIdx.x;
    int b = blockIdx.x;
    int node0 = b << 8;
    int start = bstart[b], end = bstart[b + 1];
    cnt[t] = 0;
    __syncthreads();
    for (int j = start + t; j < end; j += 256)
        atomicAdd(&cnt[pairs[j].y - node0], 1);
    __syncthreads();
    int v = cnt[t];
    scn[t] = v;
    __syncthreads();
#pragma unroll
    for (int off = 1; off < 256; off <<= 1) {
        int u = (t >= off) ? scn[t - off] : 0;
        __syncthreads();
        scn[t] += u;
        __syncthreads();
    }
    int excl = start + scn[t] - v;
    if (node0 + t < N_NODES) offsets[node0 + t] = excl;
    cnt[t] = excl;                       // repurpose as cursor
    __syncthreads();
    for (int j = start + t; j < end; j += 256) {
        uint2 pr = pairs[j];
        int p = atomicAdd(&cnt[pr.y - node0], 1);
        csr_src[p] = (int)pr.x;
    }
}

// -------- layer 1 aggregate: wave/node, bf16 gather, 4 edges in flight --------
__global__ void agg1_kernel(const unsigned short* __restrict__ h1b,
                            const float* __restrict__ as1,
                            const float* __restrict__ ad1, const float* __restrict__ b1,
                            const int* __restrict__ offsets, const int* __restrict__ csr_src,
                            float* __restrict__ out1) {
    int wid = (blockIdx.x * blockDim.x + threadIdx.x) >> 6;
    if (wid >= N_NODES) return;
    int lane = threadIdx.x & 63;
    float da0 = ad1[wid * 2 + 0], da1 = ad1[wid * 2 + 1];
    int jb = offsets[wid], je = offsets[wid + 1];
    float acc0 = 0.f, acc1 = 0.f;
    float psum0 = 0.f, psum1 = 0.f;

    for (int chunk = jb; chunk < je; chunk += 64) {
        int j = chunk + lane;
        int s = 0; float w0 = 0.f, w1 = 0.f;
        if (j < je) {
            s = csr_src[j];
            float2 av = *(const float2*)&as1[s * 2];
            w0 = __expf(lrelu(av.x + da0));
            w1 = __expf(lrelu(av.y + da1));
        }
        psum0 += w0; psum1 += w1;
        int cnt = je - chunk; if (cnt > 64) cnt = 64;
        for (int k = 0; k < cnt; k += 4) {
            int ss0 = __shfl(s, k + 0, 64);
            int ss1 = __shfl(s, k + 1, 64);
            int ss2 = __shfl(s, k + 2, 64);
            int ss3 = __shfl(s, k + 3, 64);
            unsigned u0 = ((const unsigned*)(h1b + (size_t)ss0 * 128))[lane];
            unsigned u1 = ((const unsigned*)(h1b + (size_t)ss1 * 128))[lane];
            unsigned u2 = ((const unsigned*)(h1b + (size_t)ss2 * 128))[lane];
            unsigned u3 = ((const unsigned*)(h1b + (size_t)ss3 * 128))[lane];
            float p0 = __shfl(w0, k + 0, 64), q0 = __shfl(w1, k + 0, 64);
            float p1 = __shfl(w0, k + 1, 64), q1 = __shfl(w1, k + 1, 64);
            float p2 = __shfl(w0, k + 2, 64), q2 = __shfl(w1, k + 2, 64);
            float p3 = __shfl(w0, k + 3, 64), q3 = __shfl(w1, k + 3, 64);
            float bw0 = (lane < 32) ? p0 : q0;
            float bw1 = (lane < 32) ? p1 : q1;
            float bw2 = (lane < 32) ? p2 : q2;
            float bw3 = (lane < 32) ? p3 : q3;
            acc0 += bw0 * bflo(u0); acc1 += bw0 * bfhi(u0);
            acc0 += bw1 * bflo(u1); acc1 += bw1 * bfhi(u1);
            acc0 += bw2 * bflo(u2); acc1 += bw2 * bfhi(u2);
            acc0 += bw3 * bflo(u3); acc1 += bw3 * bfhi(u3);
        }
    }
#pragma unroll
    for (int m = 1; m < 64; m <<= 1) {
        psum0 += __shfl_xor(psum0, m, 64);
        psum1 += __shfl_xor(psum1, m, 64);
    }
    float inv = 1.f / ((lane < 32) ? psum0 : psum1);
    float2 bv = *(const float2*)&b1[lane * 2];
    float v0 = acc0 * inv + bv.x;
    float v1 = acc1 * inv + bv.y;
    v0 = v0 > 0.f ? v0 : 0.f;
    v1 = v1 > 0.f ? v1 : 0.f;
    *(float2*)&out1[(size_t)wid * 128 + lane * 2] = make_float2(v0, v1);
}

// -------- layer 2 aggregate: half-wave/edge, 8 edges per iteration --------
__global__ void agg2_kernel(const unsigned short* __restrict__ h2b,
                            const float* __restrict__ as2,
                            const float* __restrict__ ad2, const float* __restrict__ b2,
                            const int* __restrict__ offsets, const int* __restrict__ csr_src,
                            float* __restrict__ out) {
    int wid = (blockIdx.x * blockDim.x + threadIdx.x) >> 6;
    if (wid >= N_NODES) return;
    int lane = threadIdx.x & 63;
    int cl = lane & 31;
    int half = lane >> 5;
    float da = ad2[wid];
    int jb = offsets[wid], je = offsets[wid + 1];
    float acc0 = 0.f, acc1 = 0.f, psum = 0.f;

    for (int chunk = jb; chunk < je; chunk += 64) {
        int j = chunk + lane;
        int s = 0; float w = 0.f;
        if (j < je) {
            s = csr_src[j];
            w = __expf(lrelu(as2[s] + da));
        }
        psum += w;
        int cnt = je - chunk; if (cnt > 64) cnt = 64;
        for (int k = 0; k < cnt; k += 8) {
            int k0 = k + half, k1 = k + 2 + half, k2 = k + 4 + half, k3 = k + 6 + half;
            int ss0 = __shfl(s, k0, 64);
            int ss1 = __shfl(s, k1, 64);
            int ss2 = __shfl(s, k2, 64);
            int ss3 = __shfl(s, k3, 64);
            unsigned u0 = ((const unsigned*)(h2b + (size_t)ss0 * 64))[cl];
            unsigned u1 = ((const unsigned*)(h2b + (size_t)ss1 * 64))[cl];
            unsigned u2 = ((const unsigned*)(h2b + (size_t)ss2 * 64))[cl];
            unsigned u3 = ((const unsigned*)(h2b + (size_t)ss3 * 64))[cl];
            float bw0 = __shfl(w, k0, 64);
            float bw1 = __shfl(w, k1, 64);
            float bw2 = __shfl(w, k2, 64);
            float bw3 = __shfl(w, k3, 64);
            acc0 += bw0 * bflo(u0); acc1 += bw0 * bfhi(u0);
            acc0 += bw1 * bflo(u1); acc1 += bw1 * bfhi(u1);
            acc0 += bw2 * bflo(u2); acc1 += bw2 * bfhi(u2);
            acc0 += bw3 * bflo(u3); acc1 += bw3 * bfhi(u3);
        }
    }
#pragma unroll
    for (int m = 1; m < 64; m <<= 1) psum += __shfl_xor(psum, m, 64);
    float o0 = __shfl(acc0, cl + 32, 64);
    float o1 = __shfl(acc1, cl + 32, 64);
    if (lane < 32) {
        float inv = 1.f / psum;
        float2 bv = *(const float2*)&b2[cl * 2];
        float v0 = (acc0 + o0) * inv + bv.x;
        float v1 = (acc1 + o1) * inv + bv.y;
        v0 = 1.f / (1.f + __expf(-v0));
        v1 = 1.f / (1.f + __expf(-v1));
        *(float2*)&out[(size_t)wid * 64 + cl * 2] = make_float2(v0, v1);
    }
}

extern "C" void kernel_launch(void* const* d_in, const int* in_sizes, int n_in,
                              void* d_out, int out_size, void* d_ws, size_t ws_size,
                              hipStream_t stream) {
    const float* x     = (const float*)d_in[0];
    const int*   ei    = (const int*)d_in[1];
    const float* W1    = (const float*)d_in[2];
    const float* asrc1 = (const float*)d_in[3];
    const float* adst1 = (const float*)d_in[4];
    const float* b1    = (const float*)d_in[5];
    const float* W2    = (const float*)d_in[6];
    const float* asrc2 = (const float*)d_in[7];
    const float* adst2 = (const float*)d_in[8];
    const float* b2    = (const float*)d_in[9];
    float* out = (float*)d_out;

    float* ws = (float*)d_ws;
    size_t off = 0;
    float* out1 = ws + off; off += (size_t)N_NODES * 128;
    float* as1  = ws + off; off += (size_t)N_NODES * 2;
    float* ad1  = ws + off; off += (size_t)N_NODES * 2;
    float* as2  = ws + off; off += (size_t)N_NODES;
    float* ad2  = ws + off; off += (size_t)N_NODES;
    unsigned short* h1b = (unsigned short*)(ws + off); off += (size_t)N_NODES * 64;  // 128 bf16
    unsigned short* h2b = (unsigned short*)(ws + off); off += (size_t)N_NODES * 32;  // 64 bf16
    int* offsets   = (int*)(ws + off);
    int* csr_src   = offsets + N_NODES + 1;
    int* bcnt      = csr_src + E_TOT;
    int* bstart    = bcnt + NB_BKT;
    int* bucketcur = bstart + NB_BKT + 1;
    uint2* pairs   = (uint2*)((((size_t)(bucketcur + NB_BKT)) + 7) & ~(size_t)7);

    hipMemsetAsync(bcnt, 0, NB_BKT * sizeof(int), stream);

    gemm1_kernel<<<NB_G1, 256, 0, stream>>>(x, W1, asrc1, adst1, h1b, as1, ad1);
    coarse_hist_kernel<<<NB_P1, 256, 0, stream>>>(ei, bcnt);
    bucket_scan_kernel<<<1, 256, 0, stream>>>(bcnt, bstart, bucketcur, offsets);
    scatterP1_kernel<<<NB_P1, 256, 0, stream>>>(ei, bucketcur, pairs);
    scatterP2_kernel<<<NB_BKT, 256, 0, stream>>>(pairs, bstart, offsets, csr_src);
    agg1_kernel<<<(N_NODES * 64 + 255) / 256, 256, 0, stream>>>(h1b, as1, ad1, b1, offsets, csr_src, out1);
    gemm2_kernel<<<(N_NODES + 63) / 64, 256, 0, stream>>>(out1, W2, asrc2, adst2, h2b, as2, ad2);
    agg2_kernel<<<(N_NODES * 64 + 255) / 256, 256, 0, stream>>>(h2b, as2, ad2, b2, offsets, csr_src, out);
}

// Round 9
// 212.035 us; speedup vs baseline: 3.1441x; 1.1240x over previous
//
#include <hip/hip_runtime.h>
#include <math.h>

#define N_NODES 50000
#define N_EDGES 800000
#define E_TOT   (N_EDGES + N_NODES)
#define NEG_SLOPE 0.2f
#define NB_BKT  ((N_NODES + 255) / 256)   // 196 dst-buckets of 256 nodes
#define P1_CHUNK 4096
#define NB_P1   ((E_TOT + P1_CHUNK - 1) / P1_CHUNK)   // 208 pass-1 blocks
#define NB_G1   ((N_NODES + 127) / 128)   // 391 gemm blocks

typedef short bf16x8 __attribute__((ext_vector_type(8)));
typedef float f32x4 __attribute__((ext_vector_type(4)));

static __device__ __forceinline__ float lrelu(float v) {
    return v > 0.0f ? v : NEG_SLOPE * v;
}

// round-to-nearest-even fp32 -> bf16
static __device__ __forceinline__ unsigned short f2bf(float f) {
    unsigned b = __float_as_uint(f);
    return (unsigned short)((b + 0x7fffu + ((b >> 16) & 1u)) >> 16);
}

static __device__ __forceinline__ float bflo(unsigned u) { return __uint_as_float(u << 16); }
static __device__ __forceinline__ float bfhi(unsigned u) { return __uint_as_float(u & 0xffff0000u); }

// LDS index (ushort units) for element (row, k) of a row*128 bf16 tile.
// 16B-chunk XOR swizzle: b128 frag reads and staging writes conflict-free.
static __device__ __forceinline__ int swz(int row, int k) {
    return row * 128 + ((((k >> 3) ^ (row & 15)) << 3) | (k & 7));
}
// 64-wide variant for the gemm2 h2b repack
static __device__ __forceinline__ int swz64(int row, int c) {
    return row * 64 + ((((c >> 3) ^ (row & 7)) << 3) | (c & 7));
}

// -------- GEMM 1 (bf16 MFMA) + fused alphas1: h1b[N,128], as1/ad1[N,2] --------
__global__ __launch_bounds__(256, 2) void gemm1_kernel(const float* __restrict__ x,
                                                       const float* __restrict__ W,
                                                       const float* __restrict__ a_src,
                                                       const float* __restrict__ a_dst,
                                                       unsigned short* __restrict__ h1b,
                                                       float* __restrict__ as_out,
                                                       float* __restrict__ ad_out) {
    __shared__ unsigned short xs[128 * 128];  // 32 KB
    __shared__ unsigned short wt[128 * 128];  // 32 KB, W^T
    int tid = threadIdx.x;
    int r0 = blockIdx.x * 128;

    {   // stage W^T
        int n = tid & 127;
        int c0 = (tid >> 7) * 8;
        for (int c = c0; c < c0 + 8; ++c) {
            int kb = c * 8;
            ushort4 lo, hi;
            lo.x = f2bf(W[(kb + 0) * 128 + n]);
            lo.y = f2bf(W[(kb + 1) * 128 + n]);
            lo.z = f2bf(W[(kb + 2) * 128 + n]);
            lo.w = f2bf(W[(kb + 3) * 128 + n]);
            hi.x = f2bf(W[(kb + 4) * 128 + n]);
            hi.y = f2bf(W[(kb + 5) * 128 + n]);
            hi.z = f2bf(W[(kb + 6) * 128 + n]);
            hi.w = f2bf(W[(kb + 7) * 128 + n]);
            int a = swz(n, kb);
            *(ushort4*)&wt[a] = lo;
            *(ushort4*)&wt[a + 4] = hi;
        }
    }
    {   // stage x rows as bf16
        const int maxe = N_NODES * 128 - 4;
#pragma unroll
        for (int i = 0; i < 16384; i += 1024) {
            int e = i + tid * 4;
            int ge = r0 * 128 + e;
            if (ge > maxe) ge = maxe;
            float4 v = *(const float4*)&x[ge];
            ushort4 p;
            p.x = f2bf(v.x); p.y = f2bf(v.y); p.z = f2bf(v.z); p.w = f2bf(v.w);
            *(ushort4*)&xs[swz(e >> 7, e & 127)] = p;
        }
    }
    __syncthreads();

    int wv = tid >> 6, lane = tid & 63, lm = lane & 15, quad = lane >> 4;
    f32x4 acc[2][8];
#pragma unroll
    for (int m = 0; m < 2; ++m)
#pragma unroll
        for (int n = 0; n < 8; ++n) acc[m][n] = (f32x4){0.f, 0.f, 0.f, 0.f};

#pragma unroll
    for (int kc = 0; kc < 4; ++kc) {
        int kb = kc * 32 + quad * 8;
        bf16x8 a0 = *(bf16x8*)&xs[swz(wv * 32 + lm, kb)];
        bf16x8 a1 = *(bf16x8*)&xs[swz(wv * 32 + 16 + lm, kb)];
#pragma unroll
        for (int nt = 0; nt < 8; ++nt) {
            bf16x8 b = *(bf16x8*)&wt[swz(nt * 16 + lm, kb)];
            acc[0][nt] = __builtin_amdgcn_mfma_f32_16x16x32_bf16(a0, b, acc[0][nt], 0, 0, 0);
            acc[1][nt] = __builtin_amdgcn_mfma_f32_16x16x32_bf16(a1, b, acc[1][nt], 0, 0, 0);
        }
    }

    float asv[8], adv[8];
#pragma unroll
    for (int nt = 0; nt < 8; ++nt) {
        asv[nt] = a_src[nt * 16 + lm];
        adv[nt] = a_dst[nt * 16 + lm];
    }
#pragma unroll
    for (int mt = 0; mt < 2; ++mt) {
#pragma unroll
        for (int r = 0; r < 4; ++r) {
            float s0 = 0.f, s1 = 0.f, d0 = 0.f, d1 = 0.f;
#pragma unroll
            for (int nt = 0; nt < 4; ++nt) {
                s0 += acc[mt][nt][r] * asv[nt];
                d0 += acc[mt][nt][r] * adv[nt];
            }
#pragma unroll
            for (int nt = 4; nt < 8; ++nt) {
                s1 += acc[mt][nt][r] * asv[nt];
                d1 += acc[mt][nt][r] * adv[nt];
            }
#pragma unroll
            for (int m = 1; m < 16; m <<= 1) {
                s0 += __shfl_xor(s0, m, 64);
                s1 += __shfl_xor(s1, m, 64);
                d0 += __shfl_xor(d0, m, 64);
                d1 += __shfl_xor(d1, m, 64);
            }
            if (lm == 0) {
                int gr = r0 + wv * 32 + mt * 16 + quad * 4 + r;
                if (gr < N_NODES) {
                    as_out[gr * 2 + 0] = s0;
                    as_out[gr * 2 + 1] = s1;
                    ad_out[gr * 2 + 0] = d0;
                    ad_out[gr * 2 + 1] = d1;
                }
            }
        }
    }

    __syncthreads();
#pragma unroll
    for (int mt = 0; mt < 2; ++mt) {
#pragma unroll
        for (int nt = 0; nt < 8; ++nt) {
#pragma unroll
            for (int r = 0; r < 4; ++r) {
                int lrow = wv * 32 + mt * 16 + quad * 4 + r;
                xs[swz(lrow, nt * 16 + lm)] = f2bf(acc[mt][nt][r]);
            }
        }
    }
    __syncthreads();
    {
        int lrow = tid >> 1;
        int cb = (tid & 1) * 64;
        int gr = r0 + lrow;
        if (gr < N_NODES) {
            unsigned short* dst = h1b + (size_t)gr * 128 + cb;
#pragma unroll
            for (int c = 0; c < 8; ++c)
                *(uint4*)(dst + c * 8) = *(uint4*)&xs[swz(lrow, cb + c * 8)];
        }
    }
}

// -------- GEMM 2 (bf16 MFMA) + fused alphas2: h2b[N,64], as2/ad2[N] --------
// Block = 128 rows x 64 cols; input out1b is already bf16.
__global__ __launch_bounds__(256, 2) void gemm2_kernel(const unsigned short* __restrict__ xb,
                                                       const float* __restrict__ W,
                                                       const float* __restrict__ a_src,
                                                       const float* __restrict__ a_dst,
                                                       unsigned short* __restrict__ h2b,
                                                       float* __restrict__ as_out,
                                                       float* __restrict__ ad_out) {
    __shared__ unsigned short xs[128 * 128];  // 32 KB
    __shared__ unsigned short wt[64 * 128];   // 16 KB, W^T
    int tid = threadIdx.x;
    int r0 = blockIdx.x * 128;

    {   // stage W^T: wt[n][k] = W[k][n], n in [0,64)
        int n = tid & 63;
        int c0 = (tid >> 6) * 4;
        for (int c = c0; c < c0 + 4; ++c) {
            int kb = c * 8;
            ushort4 lo, hi;
            lo.x = f2bf(W[(kb + 0) * 64 + n]);
            lo.y = f2bf(W[(kb + 1) * 64 + n]);
            lo.z = f2bf(W[(kb + 2) * 64 + n]);
            lo.w = f2bf(W[(kb + 3) * 64 + n]);
            hi.x = f2bf(W[(kb + 4) * 64 + n]);
            hi.y = f2bf(W[(kb + 5) * 64 + n]);
            hi.z = f2bf(W[(kb + 6) * 64 + n]);
            hi.w = f2bf(W[(kb + 7) * 64 + n]);
            int a = swz(n, kb);
            *(ushort4*)&wt[a] = lo;
            *(ushort4*)&wt[a + 4] = hi;
        }
    }
    {   // stage x rows (already bf16): uint4 = 8 ushorts
        const int maxe = N_NODES * 128 - 8;
#pragma unroll
        for (int i = 0; i < 16384; i += 2048) {
            int e = i + tid * 8;
            int ge = r0 * 128 + e;
            if (ge > maxe) ge = maxe;
            uint4 v = *(const uint4*)&xb[ge];
            *(uint4*)&xs[swz(e >> 7, e & 127)] = v;
        }
    }
    __syncthreads();

    int wv = tid >> 6, lane = tid & 63, lm = lane & 15, quad = lane >> 4;
    f32x4 acc[2][4];
#pragma unroll
    for (int m = 0; m < 2; ++m)
#pragma unroll
        for (int n = 0; n < 4; ++n) acc[m][n] = (f32x4){0.f, 0.f, 0.f, 0.f};

#pragma unroll
    for (int kc = 0; kc < 4; ++kc) {
        int kb = kc * 32 + quad * 8;
        bf16x8 a0 = *(bf16x8*)&xs[swz(wv * 32 + lm, kb)];
        bf16x8 a1 = *(bf16x8*)&xs[swz(wv * 32 + 16 + lm, kb)];
#pragma unroll
        for (int nt = 0; nt < 4; ++nt) {
            bf16x8 b = *(bf16x8*)&wt[swz(nt * 16 + lm, kb)];
            acc[0][nt] = __builtin_amdgcn_mfma_f32_16x16x32_bf16(a0, b, acc[0][nt], 0, 0, 0);
            acc[1][nt] = __builtin_amdgcn_mfma_f32_16x16x32_bf16(a1, b, acc[1][nt], 0, 0, 0);
        }
    }

    float asv[4], adv[4];
#pragma unroll
    for (int nt = 0; nt < 4; ++nt) {
        asv[nt] = a_src[nt * 16 + lm];
        adv[nt] = a_dst[nt * 16 + lm];
    }
#pragma unroll
    for (int mt = 0; mt < 2; ++mt) {
#pragma unroll
        for (int r = 0; r < 4; ++r) {
            float s0 = 0.f, d0 = 0.f;
#pragma unroll
            for (int nt = 0; nt < 4; ++nt) {
                s0 += acc[mt][nt][r] * asv[nt];
                d0 += acc[mt][nt][r] * adv[nt];
            }
#pragma unroll
            for (int m = 1; m < 16; m <<= 1) {
                s0 += __shfl_xor(s0, m, 64);
                d0 += __shfl_xor(d0, m, 64);
            }
            if (lm == 0) {
                int gr = r0 + wv * 32 + mt * 16 + quad * 4 + r;
                if (gr < N_NODES) {
                    as_out[gr] = s0;
                    ad_out[gr] = d0;
                }
            }
        }
    }

    // h2b repack through LDS (reuse wt: 8192 ushorts = 128 rows x 64 ch)
    __syncthreads();
#pragma unroll
    for (int mt = 0; mt < 2; ++mt) {
#pragma unroll
        for (int nt = 0; nt < 4; ++nt) {
#pragma unroll
            for (int r = 0; r < 4; ++r) {
                int lrow = wv * 32 + mt * 16 + quad * 4 + r;
                wt[swz64(lrow, nt * 16 + lm)] = f2bf(acc[mt][nt][r]);
            }
        }
    }
    __syncthreads();
    {
        int lrow = tid >> 1;
        int cb = (tid & 1) * 32;
        int gr = r0 + lrow;
        if (gr < N_NODES) {
            unsigned short* dst = h2b + (size_t)gr * 64 + cb;
#pragma unroll
            for (int c = 0; c < 4; ++c)
                *(uint4*)(dst + c * 8) = *(uint4*)&wt[swz64(lrow, cb + c * 8)];
        }
    }
}

// -------- CSR build pass 0: coarse per-bucket histogram --------
__global__ void coarse_hist_kernel(const int* __restrict__ ei, int* __restrict__ bcnt) {
    __shared__ int bins[NB_BKT];
    int tid = threadIdx.x;
    for (int i = tid; i < NB_BKT; i += 256) bins[i] = 0;
    __syncthreads();
    int base = blockIdx.x * P1_CHUNK;
    for (int i = tid; i < P1_CHUNK; i += 256) {
        int e = base + i;
        if (e >= E_TOT) break;
        int d = (e < N_EDGES) ? ei[N_EDGES + e] : (e - N_EDGES);
        atomicAdd(&bins[d >> 8], 1);
    }
    __syncthreads();
    for (int i = tid; i < NB_BKT; i += 256)
        if (bins[i]) atomicAdd(&bcnt[i], bins[i]);
}

// -------- CSR build: bucket scan --------
__global__ void bucket_scan_kernel(const int* __restrict__ bcnt, int* __restrict__ bstart,
                                   int* __restrict__ bucketcur, int* __restrict__ offsets) {
    __shared__ int s[256];
    int t = threadIdx.x;
    int v = (t < NB_BKT) ? bcnt[t] : 0;
    s[t] = v;
    __syncthreads();
#pragma unroll
    for (int off = 1; off < 256; off <<= 1) {
        int u = (t >= off) ? s[t - off] : 0;
        __syncthreads();
        s[t] += u;
        __syncthreads();
    }
    if (t < NB_BKT) {
        int excl = s[t] - v;
        bstart[t] = excl;
        bucketcur[t] = excl;
    }
    if (t == 0) {
        bstart[NB_BKT] = E_TOT;
        offsets[N_NODES] = E_TOT;
    }
}

// -------- CSR build pass 1: bucket-binned scatter of (src,dst) pairs --------
__global__ void scatterP1_kernel(const int* __restrict__ ei, int* __restrict__ bucketcur,
                                 uint2* __restrict__ pairs) {
    __shared__ int cnt[NB_BKT];
    __shared__ int base[NB_BKT];
    int tid = threadIdx.x;
    for (int i = tid; i < NB_BKT; i += 256) cnt[i] = 0;
    __syncthreads();
    int cbase = blockIdx.x * P1_CHUNK;
    for (int i = tid; i < P1_CHUNK; i += 256) {
        int e = cbase + i;
        if (e >= E_TOT) break;
        int d = (e < N_EDGES) ? ei[N_EDGES + e] : (e - N_EDGES);
        atomicAdd(&cnt[d >> 8], 1);
    }
    __syncthreads();
    for (int i = tid; i < NB_BKT; i += 256) {
        int c = cnt[i];
        base[i] = c ? atomicAdd(&bucketcur[i], c) : 0;
        cnt[i] = 0;
    }
    __syncthreads();
    for (int i = tid; i < P1_CHUNK; i += 256) {
        int e = cbase + i;
        if (e >= E_TOT) break;
        int s, d;
        if (e < N_EDGES) { s = ei[e]; d = ei[N_EDGES + e]; }
        else { s = d = e - N_EDGES; }
        int bk = d >> 8;
        int p = base[bk] + atomicAdd(&cnt[bk], 1);
        pairs[p] = make_uint2((unsigned)s, (unsigned)d);
    }
}

// -------- CSR build pass 2: per-bucket node scan + place --------
__global__ void scatterP2_kernel(const uint2* __restrict__ pairs, const int* __restrict__ bstart,
                                 int* __restrict__ offsets, int* __restrict__ csr_src) {
    __shared__ int cnt[256];
    __shared__ int scn[256];
    int t = threadIdx.x;
    int b = blockIdx.x;
    int node0 = b << 8;
    int start = bstart[b], end = bstart[b + 1];
    cnt[t] = 0;
    __syncthreads();
    for (int j = start + t; j < end; j += 256)
        atomicAdd(&cnt[pairs[j].y - node0], 1);
    __syncthreads();
    int v = cnt[t];
    scn[t] = v;
    __syncthreads();
#pragma unroll
    for (int off = 1; off < 256; off <<= 1) {
        int u = (t >= off) ? scn[t - off] : 0;
        __syncthreads();
        scn[t] += u;
        __syncthreads();
    }
    int excl = start + scn[t] - v;
    if (node0 + t < N_NODES) offsets[node0 + t] = excl;
    cnt[t] = excl;
    __syncthreads();
    for (int j = start + t; j < end; j += 256) {
        uint2 pr = pairs[j];
        int p = atomicAdd(&cnt[pr.y - node0], 1);
        csr_src[p] = (int)pr.x;
    }
}

// -------- layer 1 aggregate: half-wave/edge, uint2 gather, 8 edges/iter --------
// Lane cl=lane&31 owns channels [4cl, 4cl+4); head0 = cl<16. Writes bf16 out1b.
__global__ void agg1_kernel(const unsigned short* __restrict__ h1b,
                            const float* __restrict__ as1,
                            const float* __restrict__ ad1, const float* __restrict__ b1,
                            const int* __restrict__ offsets, const int* __restrict__ csr_src,
                            unsigned short* __restrict__ out1b) {
    int wid = (blockIdx.x * blockDim.x + threadIdx.x) >> 6;
    if (wid >= N_NODES) return;
    int lane = threadIdx.x & 63;
    int cl = lane & 31;
    int half = lane >> 5;
    bool head1 = (cl >= 16);
    float da0 = ad1[wid * 2 + 0], da1 = ad1[wid * 2 + 1];
    int jb = offsets[wid], je = offsets[wid + 1];
    float a0 = 0.f, a1 = 0.f, a2 = 0.f, a3 = 0.f;
    float psum0 = 0.f, psum1 = 0.f;

    for (int chunk = jb; chunk < je; chunk += 64) {
        int j = chunk + lane;
        int s = 0; float w0 = 0.f, w1 = 0.f;
        if (j < je) {
            s = csr_src[j];
            float2 av = *(const float2*)&as1[s * 2];
            w0 = __expf(lrelu(av.x + da0));
            w1 = __expf(lrelu(av.y + da1));
        }
        psum0 += w0; psum1 += w1;
        int cnt = je - chunk; if (cnt > 64) cnt = 64;
        for (int k = 0; k < cnt; k += 8) {
            int k0 = k + half, k1 = k + 2 + half, k2 = k + 4 + half, k3 = k + 6 + half;
            int ss0 = __shfl(s, k0, 64);
            int ss1 = __shfl(s, k1, 64);
            int ss2 = __shfl(s, k2, 64);
            int ss3 = __shfl(s, k3, 64);
            uint2 u0 = ((const uint2*)(h1b + (size_t)ss0 * 128))[cl];
            uint2 u1 = ((const uint2*)(h1b + (size_t)ss1 * 128))[cl];
            uint2 u2 = ((const uint2*)(h1b + (size_t)ss2 * 128))[cl];
            uint2 u3 = ((const uint2*)(h1b + (size_t)ss3 * 128))[cl];
            float p0 = __shfl(w0, k0, 64), q0 = __shfl(w1, k0, 64);
            float p1 = __shfl(w0, k1, 64), q1 = __shfl(w1, k1, 64);
            float p2 = __shfl(w0, k2, 64), q2 = __shfl(w1, k2, 64);
            float p3 = __shfl(w0, k3, 64), q3 = __shfl(w1, k3, 64);
            float bw0 = head1 ? q0 : p0;
            float bw1 = head1 ? q1 : p1;
            float bw2 = head1 ? q2 : p2;
            float bw3 = head1 ? q3 : p3;
            a0 += bw0 * bflo(u0.x); a1 += bw0 * bfhi(u0.x); a2 += bw0 * bflo(u0.y); a3 += bw0 * bfhi(u0.y);
            a0 += bw1 * bflo(u1.x); a1 += bw1 * bfhi(u1.x); a2 += bw1 * bflo(u1.y); a3 += bw1 * bfhi(u1.y);
            a0 += bw2 * bflo(u2.x); a1 += bw2 * bfhi(u2.x); a2 += bw2 * bflo(u2.y); a3 += bw2 * bfhi(u2.y);
            a0 += bw3 * bflo(u3.x); a1 += bw3 * bfhi(u3.x); a2 += bw3 * bflo(u3.y); a3 += bw3 * bfhi(u3.y);
        }
    }
#pragma unroll
    for (int m = 1; m < 64; m <<= 1) {
        psum0 += __shfl_xor(psum0, m, 64);
        psum1 += __shfl_xor(psum1, m, 64);
    }
    // combine half 0 (even edges) and half 1 (odd edges)
    float o0 = __shfl(a0, cl + 32, 64);
    float o1 = __shfl(a1, cl + 32, 64);
    float o2 = __shfl(a2, cl + 32, 64);
    float o3 = __shfl(a3, cl + 32, 64);
    if (lane < 32) {
        float inv = 1.f / (head1 ? psum1 : psum0);
        float4 bv = *(const float4*)&b1[cl * 4];
        float v0 = (a0 + o0) * inv + bv.x;
        float v1 = (a1 + o1) * inv + bv.y;
        float v2 = (a2 + o2) * inv + bv.z;
        float v3 = (a3 + o3) * inv + bv.w;
        v0 = v0 > 0.f ? v0 : 0.f;
        v1 = v1 > 0.f ? v1 : 0.f;
        v2 = v2 > 0.f ? v2 : 0.f;
        v3 = v3 > 0.f ? v3 : 0.f;
        ushort4 p;
        p.x = f2bf(v0); p.y = f2bf(v1); p.z = f2bf(v2); p.w = f2bf(v3);
        *(ushort4*)&out1b[(size_t)wid * 128 + cl * 4] = p;
    }
}

// -------- layer 2 aggregate: half-wave/edge, 8 edges per iteration --------
__global__ void agg2_kernel(const unsigned short* __restrict__ h2b,
                            const float* __restrict__ as2,
                            const float* __restrict__ ad2, const float* __restrict__ b2,
                            const int* __restrict__ offsets, const int* __restrict__ csr_src,
                            float* __restrict__ out) {
    int wid = (blockIdx.x * blockDim.x + threadIdx.x) >> 6;
    if (wid >= N_NODES) return;
    int lane = threadIdx.x & 63;
    int cl = lane & 31;
    int half = lane >> 5;
    float da = ad2[wid];
    int jb = offsets[wid], je = offsets[wid + 1];
    float acc0 = 0.f, acc1 = 0.f, psum = 0.f;

    for (int chunk = jb; chunk < je; chunk += 64) {
        int j = chunk + lane;
        int s = 0; float w = 0.f;
        if (j < je) {
            s = csr_src[j];
            w = __expf(lrelu(as2[s] + da));
        }
        psum += w;
        int cnt = je - chunk; if (cnt > 64) cnt = 64;
        for (int k = 0; k < cnt; k += 8) {
            int k0 = k + half, k1 = k + 2 + half, k2 = k + 4 + half, k3 = k + 6 + half;
            int ss0 = __shfl(s, k0, 64);
            int ss1 = __shfl(s, k1, 64);
            int ss2 = __shfl(s, k2, 64);
            int ss3 = __shfl(s, k3, 64);
            unsigned u0 = ((const unsigned*)(h2b + (size_t)ss0 * 64))[cl];
            unsigned u1 = ((const unsigned*)(h2b + (size_t)ss1 * 64))[cl];
            unsigned u2 = ((const unsigned*)(h2b + (size_t)ss2 * 64))[cl];
            unsigned u3 = ((const unsigned*)(h2b + (size_t)ss3 * 64))[cl];
            float bw0 = __shfl(w, k0, 64);
            float bw1 = __shfl(w, k1, 64);
            float bw2 = __shfl(w, k2, 64);
            float bw3 = __shfl(w, k3, 64);
            acc0 += bw0 * bflo(u0); acc1 += bw0 * bfhi(u0);
            acc0 += bw1 * bflo(u1); acc1 += bw1 * bfhi(u1);
            acc0 += bw2 * bflo(u2); acc1 += bw2 * bfhi(u2);
            acc0 += bw3 * bflo(u3); acc1 += bw3 * bfhi(u3);
        }
    }
#pragma unroll
    for (int m = 1; m < 64; m <<= 1) psum += __shfl_xor(psum, m, 64);
    float o0 = __shfl(acc0, cl + 32, 64);
    float o1 = __shfl(acc1, cl + 32, 64);
    if (lane < 32) {
        float inv = 1.f / psum;
        float2 bv = *(const float2*)&b2[cl * 2];
        float v0 = (acc0 + o0) * inv + bv.x;
        float v1 = (acc1 + o1) * inv + bv.y;
        v0 = 1.f / (1.f + __expf(-v0));
        v1 = 1.f / (1.f + __expf(-v1));
        *(float2*)&out[(size_t)wid * 64 + cl * 2] = make_float2(v0, v1);
    }
}

extern "C" void kernel_launch(void* const* d_in, const int* in_sizes, int n_in,
                              void* d_out, int out_size, void* d_ws, size_t ws_size,
                              hipStream_t stream) {
    const float* x     = (const float*)d_in[0];
    const int*   ei    = (const int*)d_in[1];
    const float* W1    = (const float*)d_in[2];
    const float* asrc1 = (const float*)d_in[3];
    const float* adst1 = (const float*)d_in[4];
    const float* b1    = (const float*)d_in[5];
    const float* W2    = (const float*)d_in[6];
    const float* asrc2 = (const float*)d_in[7];
    const float* adst2 = (const float*)d_in[8];
    const float* b2    = (const float*)d_in[9];
    float* out = (float*)d_out;

    float* ws = (float*)d_ws;
    size_t off = 0;
    float* as1  = ws + off; off += (size_t)N_NODES * 2;
    float* ad1  = ws + off; off += (size_t)N_NODES * 2;
    float* as2  = ws + off; off += (size_t)N_NODES;
    float* ad2  = ws + off; off += (size_t)N_NODES;
    unsigned short* h1b   = (unsigned short*)(ws + off); off += (size_t)N_NODES * 64;  // 128 bf16
    unsigned short* out1b = (unsigned short*)(ws + off); off += (size_t)N_NODES * 64;  // 128 bf16
    unsigned short* h2b   = (unsigned short*)(ws + off); off += (size_t)N_NODES * 32;  // 64 bf16
    int* offsets   = (int*)(ws + off);
    int* csr_src   = offsets + N_NODES + 1;
    int* bcnt      = csr_src + E_TOT;
    int* bstart    = bcnt + NB_BKT;
    int* bucketcur = bstart + NB_BKT + 1;
    uint2* pairs   = (uint2*)((((size_t)(bucketcur + NB_BKT)) + 7) & ~(size_t)7);

    hipMemsetAsync(bcnt, 0, NB_BKT * sizeof(int), stream);

    gemm1_kernel<<<NB_G1, 256, 0, stream>>>(x, W1, asrc1, adst1, h1b, as1, ad1);
    coarse_hist_kernel<<<NB_P1, 256, 0, stream>>>(ei, bcnt);
    bucket_scan_kernel<<<1, 256, 0, stream>>>(bcnt, bstart, bucketcur, offsets);
    scatterP1_kernel<<<NB_P1, 256, 0, stream>>>(ei, bucketcur, pairs);
    scatterP2_kernel<<<NB_BKT, 256, 0, stream>>>(pairs, bstart, offsets, csr_src);
    agg1_kernel<<<(N_NODES * 64 + 255) / 256, 256, 0, stream>>>(h1b, as1, ad1, b1, offsets, csr_src, out1b);
    gemm2_kernel<<<NB_G1, 256, 0, stream>>>(out1b, W2, asrc2, adst2, h2b, as2, ad2);
    agg2_kernel<<<(N_NODES * 64 + 255) / 256, 256, 0, stream>>>(h2b, as2, ad2, b2, offsets, csr_src, out);
}

// Round 10
// 194.007 us; speedup vs baseline: 3.4362x; 1.0929x over previous
//
#include <hip/hip_runtime.h>
#include <math.h>

#define N_NODES 50000
#define N_EDGES 800000
#define E_TOT   (N_EDGES + N_NODES)
#define NEG_SLOPE 0.2f
#define NB_BKT  ((N_NODES + 255) / 256)   // 196 dst-buckets of 256 nodes
#define BKT_CAP 5632                      // mean 4352 + 20 sigma (uniform dst)
#define P1_CHUNK 4096
#define NB_P1   ((E_TOT + P1_CHUNK - 1) / P1_CHUNK)   // 208 scatter blocks
#define NB_G1   ((N_NODES + 127) / 128)   // 391 gemm blocks

typedef short bf16x8 __attribute__((ext_vector_type(8)));
typedef float f32x4 __attribute__((ext_vector_type(4)));

static __device__ __forceinline__ float lrelu(float v) {
    return v > 0.0f ? v : NEG_SLOPE * v;
}

// round-to-nearest-even fp32 -> bf16
static __device__ __forceinline__ unsigned short f2bf(float f) {
    unsigned b = __float_as_uint(f);
    return (unsigned short)((b + 0x7fffu + ((b >> 16) & 1u)) >> 16);
}

static __device__ __forceinline__ float bflo(unsigned u) { return __uint_as_float(u << 16); }
static __device__ __forceinline__ float bfhi(unsigned u) { return __uint_as_float(u & 0xffff0000u); }

// LDS index (ushort units) for element (row, k) of a row*128 bf16 tile.
// 16B-chunk XOR swizzle: b128 frag reads and staging writes conflict-free.
static __device__ __forceinline__ int swz(int row, int k) {
    return row * 128 + ((((k >> 3) ^ (row & 15)) << 3) | (k & 7));
}
// 64-wide variant for the gemm2 h2b repack
static __device__ __forceinline__ int swz64(int row, int c) {
    return row * 64 + ((((c >> 3) ^ (row & 7)) << 3) | (c & 7));
}

// -------- fused A: blocks [0,NB_G1) = GEMM1 (bf16 MFMA) + alphas1;
//                   blocks [NB_G1, NB_G1+NB_P1) = bucket-binned edge scatter.
__global__ __launch_bounds__(256, 2) void fusedA_kernel(const float* __restrict__ x,
                                                        const float* __restrict__ W,
                                                        const float* __restrict__ a_src,
                                                        const float* __restrict__ a_dst,
                                                        unsigned short* __restrict__ h1b,
                                                        float* __restrict__ as_out,
                                                        float* __restrict__ ad_out,
                                                        const int* __restrict__ ei,
                                                        int* __restrict__ bktcnt,
                                                        uint2* __restrict__ pairs) {
    __shared__ __align__(16) unsigned char smem[65536];
    int tid = threadIdx.x;

    if (blockIdx.x >= NB_G1) {
        // ---------------- scatter P1 path ----------------
        int* cnt  = (int*)smem;
        int* base = (int*)(smem + 1024);
        for (int i = tid; i < NB_BKT; i += 256) cnt[i] = 0;
        __syncthreads();
        int cbase = (blockIdx.x - NB_G1) * P1_CHUNK;
        for (int i = tid; i < P1_CHUNK; i += 256) {
            int e = cbase + i;
            if (e >= E_TOT) break;
            int d = (e < N_EDGES) ? ei[N_EDGES + e] : (e - N_EDGES);
            atomicAdd(&cnt[d >> 8], 1);
        }
        __syncthreads();
        for (int i = tid; i < NB_BKT; i += 256) {
            int c = cnt[i];
            base[i] = c ? (BKT_CAP * i + atomicAdd(&bktcnt[i], c)) : 0;
            cnt[i] = 0;
        }
        __syncthreads();
        for (int i = tid; i < P1_CHUNK; i += 256) {
            int e = cbase + i;
            if (e >= E_TOT) break;
            int s, d;
            if (e < N_EDGES) { s = ei[e]; d = ei[N_EDGES + e]; }
            else { s = d = e - N_EDGES; }
            int bk = d >> 8;
            int p = base[bk] + atomicAdd(&cnt[bk], 1);
            pairs[p] = make_uint2((unsigned)s, (unsigned)d);
        }
        return;
    }

    // ---------------- GEMM1 path ----------------
    unsigned short* xs = (unsigned short*)smem;            // 32 KB
    unsigned short* wt = (unsigned short*)(smem + 32768);  // 32 KB, W^T
    int r0 = blockIdx.x * 128;

    {   // stage W^T
        int n = tid & 127;
        int c0 = (tid >> 7) * 8;
        for (int c = c0; c < c0 + 8; ++c) {
            int kb = c * 8;
            ushort4 lo, hi;
            lo.x = f2bf(W[(kb + 0) * 128 + n]);
            lo.y = f2bf(W[(kb + 1) * 128 + n]);
            lo.z = f2bf(W[(kb + 2) * 128 + n]);
            lo.w = f2bf(W[(kb + 3) * 128 + n]);
            hi.x = f2bf(W[(kb + 4) * 128 + n]);
            hi.y = f2bf(W[(kb + 5) * 128 + n]);
            hi.z = f2bf(W[(kb + 6) * 128 + n]);
            hi.w = f2bf(W[(kb + 7) * 128 + n]);
            int a = swz(n, kb);
            *(ushort4*)&wt[a] = lo;
            *(ushort4*)&wt[a + 4] = hi;
        }
    }
    {   // stage x rows as bf16
        const int maxe = N_NODES * 128 - 4;
#pragma unroll
        for (int i = 0; i < 16384; i += 1024) {
            int e = i + tid * 4;
            int ge = r0 * 128 + e;
            if (ge > maxe) ge = maxe;
            float4 v = *(const float4*)&x[ge];
            ushort4 p;
            p.x = f2bf(v.x); p.y = f2bf(v.y); p.z = f2bf(v.z); p.w = f2bf(v.w);
            *(ushort4*)&xs[swz(e >> 7, e & 127)] = p;
        }
    }
    __syncthreads();

    int wv = tid >> 6, lane = tid & 63, lm = lane & 15, quad = lane >> 4;
    f32x4 acc[2][8];
#pragma unroll
    for (int m = 0; m < 2; ++m)
#pragma unroll
        for (int n = 0; n < 8; ++n) acc[m][n] = (f32x4){0.f, 0.f, 0.f, 0.f};

#pragma unroll
    for (int kc = 0; kc < 4; ++kc) {
        int kb = kc * 32 + quad * 8;
        bf16x8 a0 = *(bf16x8*)&xs[swz(wv * 32 + lm, kb)];
        bf16x8 a1 = *(bf16x8*)&xs[swz(wv * 32 + 16 + lm, kb)];
#pragma unroll
        for (int nt = 0; nt < 8; ++nt) {
            bf16x8 b = *(bf16x8*)&wt[swz(nt * 16 + lm, kb)];
            acc[0][nt] = __builtin_amdgcn_mfma_f32_16x16x32_bf16(a0, b, acc[0][nt], 0, 0, 0);
            acc[1][nt] = __builtin_amdgcn_mfma_f32_16x16x32_bf16(a1, b, acc[1][nt], 0, 0, 0);
        }
    }

    float asv[8], adv[8];
#pragma unroll
    for (int nt = 0; nt < 8; ++nt) {
        asv[nt] = a_src[nt * 16 + lm];
        adv[nt] = a_dst[nt * 16 + lm];
    }
#pragma unroll
    for (int mt = 0; mt < 2; ++mt) {
#pragma unroll
        for (int r = 0; r < 4; ++r) {
            float s0 = 0.f, s1 = 0.f, d0 = 0.f, d1 = 0.f;
#pragma unroll
            for (int nt = 0; nt < 4; ++nt) {
                s0 += acc[mt][nt][r] * asv[nt];
                d0 += acc[mt][nt][r] * adv[nt];
            }
#pragma unroll
            for (int nt = 4; nt < 8; ++nt) {
                s1 += acc[mt][nt][r] * asv[nt];
                d1 += acc[mt][nt][r] * adv[nt];
            }
#pragma unroll
            for (int m = 1; m < 16; m <<= 1) {
                s0 += __shfl_xor(s0, m, 64);
                s1 += __shfl_xor(s1, m, 64);
                d0 += __shfl_xor(d0, m, 64);
                d1 += __shfl_xor(d1, m, 64);
            }
            if (lm == 0) {
                int gr = r0 + wv * 32 + mt * 16 + quad * 4 + r;
                if (gr < N_NODES) {
                    as_out[gr * 2 + 0] = s0;
                    as_out[gr * 2 + 1] = s1;
                    ad_out[gr * 2 + 0] = d0;
                    ad_out[gr * 2 + 1] = d1;
                }
            }
        }
    }

    __syncthreads();
#pragma unroll
    for (int mt = 0; mt < 2; ++mt) {
#pragma unroll
        for (int nt = 0; nt < 8; ++nt) {
#pragma unroll
            for (int r = 0; r < 4; ++r) {
                int lrow = wv * 32 + mt * 16 + quad * 4 + r;
                xs[swz(lrow, nt * 16 + lm)] = f2bf(acc[mt][nt][r]);
            }
        }
    }
    __syncthreads();
    {
        int lrow = tid >> 1;
        int cb = (tid & 1) * 64;
        int gr = r0 + lrow;
        if (gr < N_NODES) {
            unsigned short* dst = h1b + (size_t)gr * 128 + cb;
#pragma unroll
            for (int c = 0; c < 8; ++c)
                *(uint4*)(dst + c * 8) = *(uint4*)&xs[swz(lrow, cb + c * 8)];
        }
    }
}

// -------- CSR build pass 2: per-bucket node scan + place (padded csr) --------
__global__ void scatterP2_kernel(const uint2* __restrict__ pairs, const int* __restrict__ bktcnt,
                                 int* __restrict__ offsets, int* __restrict__ deg,
                                 int* __restrict__ csr_src) {
    __shared__ int cnt[256];
    __shared__ int scn[256];
    int t = threadIdx.x;
    int b = blockIdx.x;
    int node0 = b << 8;
    int pbase = b * BKT_CAP;
    int cntE = bktcnt[b];
    cnt[t] = 0;
    __syncthreads();
    for (int j = t; j < cntE; j += 256)
        atomicAdd(&cnt[pairs[pbase + j].y - node0], 1);
    __syncthreads();
    int v = cnt[t];
    scn[t] = v;
    __syncthreads();
#pragma unroll
    for (int off = 1; off < 256; off <<= 1) {
        int u = (t >= off) ? scn[t - off] : 0;
        __syncthreads();
        scn[t] += u;
        __syncthreads();
    }
    int start = pbase + scn[t] - v;
    if (node0 + t < N_NODES) {
        offsets[node0 + t] = start;
        deg[node0 + t] = v;
    }
    cnt[t] = start;
    __syncthreads();
    for (int j = t; j < cntE; j += 256) {
        uint2 pr = pairs[pbase + j];
        int p = atomicAdd(&cnt[pr.y - node0], 1);
        csr_src[p] = (int)pr.x;
    }
}

// -------- GEMM 2 (bf16 MFMA) + fused alphas2: h2b[N,64], as2/ad2[N] --------
__global__ __launch_bounds__(256, 2) void gemm2_kernel(const unsigned short* __restrict__ xb,
                                                       const float* __restrict__ W,
                                                       const float* __restrict__ a_src,
                                                       const float* __restrict__ a_dst,
                                                       unsigned short* __restrict__ h2b,
                                                       float* __restrict__ as_out,
                                                       float* __restrict__ ad_out) {
    __shared__ unsigned short xs[128 * 128];  // 32 KB
    __shared__ unsigned short wt[64 * 128];   // 16 KB, W^T
    int tid = threadIdx.x;
    int r0 = blockIdx.x * 128;

    {   // stage W^T: wt[n][k] = W[k][n], n in [0,64)
        int n = tid & 63;
        int c0 = (tid >> 6) * 4;
        for (int c = c0; c < c0 + 4; ++c) {
            int kb = c * 8;
            ushort4 lo, hi;
            lo.x = f2bf(W[(kb + 0) * 64 + n]);
            lo.y = f2bf(W[(kb + 1) * 64 + n]);
            lo.z = f2bf(W[(kb + 2) * 64 + n]);
            lo.w = f2bf(W[(kb + 3) * 64 + n]);
            hi.x = f2bf(W[(kb + 4) * 64 + n]);
            hi.y = f2bf(W[(kb + 5) * 64 + n]);
            hi.z = f2bf(W[(kb + 6) * 64 + n]);
            hi.w = f2bf(W[(kb + 7) * 64 + n]);
            int a = swz(n, kb);
            *(ushort4*)&wt[a] = lo;
            *(ushort4*)&wt[a + 4] = hi;
        }
    }
    {   // stage x rows (already bf16)
        const int maxe = N_NODES * 128 - 8;
#pragma unroll
        for (int i = 0; i < 16384; i += 2048) {
            int e = i + tid * 8;
            int ge = r0 * 128 + e;
            if (ge > maxe) ge = maxe;
            uint4 v = *(const uint4*)&xb[ge];
            *(uint4*)&xs[swz(e >> 7, e & 127)] = v;
        }
    }
    __syncthreads();

    int wv = tid >> 6, lane = tid & 63, lm = lane & 15, quad = lane >> 4;
    f32x4 acc[2][4];
#pragma unroll
    for (int m = 0; m < 2; ++m)
#pragma unroll
        for (int n = 0; n < 4; ++n) acc[m][n] = (f32x4){0.f, 0.f, 0.f, 0.f};

#pragma unroll
    for (int kc = 0; kc < 4; ++kc) {
        int kb = kc * 32 + quad * 8;
        bf16x8 a0 = *(bf16x8*)&xs[swz(wv * 32 + lm, kb)];
        bf16x8 a1 = *(bf16x8*)&xs[swz(wv * 32 + 16 + lm, kb)];
#pragma unroll
        for (int nt = 0; nt < 4; ++nt) {
            bf16x8 b = *(bf16x8*)&wt[swz(nt * 16 + lm, kb)];
            acc[0][nt] = __builtin_amdgcn_mfma_f32_16x16x32_bf16(a0, b, acc[0][nt], 0, 0, 0);
            acc[1][nt] = __builtin_amdgcn_mfma_f32_16x16x32_bf16(a1, b, acc[1][nt], 0, 0, 0);
        }
    }

    float asv[4], adv[4];
#pragma unroll
    for (int nt = 0; nt < 4; ++nt) {
        asv[nt] = a_src[nt * 16 + lm];
        adv[nt] = a_dst[nt * 16 + lm];
    }
#pragma unroll
    for (int mt = 0; mt < 2; ++mt) {
#pragma unroll
        for (int r = 0; r < 4; ++r) {
            float s0 = 0.f, d0 = 0.f;
#pragma unroll
            for (int nt = 0; nt < 4; ++nt) {
                s0 += acc[mt][nt][r] * asv[nt];
                d0 += acc[mt][nt][r] * adv[nt];
            }
#pragma unroll
            for (int m = 1; m < 16; m <<= 1) {
                s0 += __shfl_xor(s0, m, 64);
                d0 += __shfl_xor(d0, m, 64);
            }
            if (lm == 0) {
                int gr = r0 + wv * 32 + mt * 16 + quad * 4 + r;
                if (gr < N_NODES) {
                    as_out[gr] = s0;
                    ad_out[gr] = d0;
                }
            }
        }
    }

    __syncthreads();
#pragma unroll
    for (int mt = 0; mt < 2; ++mt) {
#pragma unroll
        for (int nt = 0; nt < 4; ++nt) {
#pragma unroll
            for (int r = 0; r < 4; ++r) {
                int lrow = wv * 32 + mt * 16 + quad * 4 + r;
                wt[swz64(lrow, nt * 16 + lm)] = f2bf(acc[mt][nt][r]);
            }
        }
    }
    __syncthreads();
    {
        int lrow = tid >> 1;
        int cb = (tid & 1) * 32;
        int gr = r0 + lrow;
        if (gr < N_NODES) {
            unsigned short* dst = h2b + (size_t)gr * 64 + cb;
#pragma unroll
            for (int c = 0; c < 4; ++c)
                *(uint4*)(dst + c * 8) = *(uint4*)&wt[swz64(lrow, cb + c * 8)];
        }
    }
}

// -------- layer 1 aggregate: half-wave/edge, uint2 gather, 8 edges/iter --------
__global__ void agg1_kernel(const unsigned short* __restrict__ h1b,
                            const float* __restrict__ as1,
                            const float* __restrict__ ad1, const float* __restrict__ b1,
                            const int* __restrict__ offsets, const int* __restrict__ deg,
                            const int* __restrict__ csr_src,
                            unsigned short* __restrict__ out1b) {
    int wid = (blockIdx.x * blockDim.x + threadIdx.x) >> 6;
    if (wid >= N_NODES) return;
    int lane = threadIdx.x & 63;
    int cl = lane & 31;
    int half = lane >> 5;
    bool head1 = (cl >= 16);
    float da0 = ad1[wid * 2 + 0], da1 = ad1[wid * 2 + 1];
    int jb = offsets[wid], je = jb + deg[wid];
    float a0 = 0.f, a1 = 0.f, a2 = 0.f, a3 = 0.f;
    float psum0 = 0.f, psum1 = 0.f;

    for (int chunk = jb; chunk < je; chunk += 64) {
        int j = chunk + lane;
        int s = 0; float w0 = 0.f, w1 = 0.f;
        if (j < je) {
            s = csr_src[j];
            float2 av = *(const float2*)&as1[s * 2];
            w0 = __expf(lrelu(av.x + da0));
            w1 = __expf(lrelu(av.y + da1));
        }
        psum0 += w0; psum1 += w1;
        int cnt = je - chunk; if (cnt > 64) cnt = 64;
        for (int k = 0; k < cnt; k += 8) {
            int k0 = k + half, k1 = k + 2 + half, k2 = k + 4 + half, k3 = k + 6 + half;
            int ss0 = __shfl(s, k0, 64);
            int ss1 = __shfl(s, k1, 64);
            int ss2 = __shfl(s, k2, 64);
            int ss3 = __shfl(s, k3, 64);
            uint2 u0 = ((const uint2*)(h1b + (size_t)ss0 * 128))[cl];
            uint2 u1 = ((const uint2*)(h1b + (size_t)ss1 * 128))[cl];
            uint2 u2 = ((const uint2*)(h1b + (size_t)ss2 * 128))[cl];
            uint2 u3 = ((const uint2*)(h1b + (size_t)ss3 * 128))[cl];
            float p0 = __shfl(w0, k0, 64), q0 = __shfl(w1, k0, 64);
            float p1 = __shfl(w0, k1, 64), q1 = __shfl(w1, k1, 64);
            float p2 = __shfl(w0, k2, 64), q2 = __shfl(w1, k2, 64);
            float p3 = __shfl(w0, k3, 64), q3 = __shfl(w1, k3, 64);
            float bw0 = head1 ? q0 : p0;
            float bw1 = head1 ? q1 : p1;
            float bw2 = head1 ? q2 : p2;
            float bw3 = head1 ? q3 : p3;
            a0 += bw0 * bflo(u0.x); a1 += bw0 * bfhi(u0.x); a2 += bw0 * bflo(u0.y); a3 += bw0 * bfhi(u0.y);
            a0 += bw1 * bflo(u1.x); a1 += bw1 * bfhi(u1.x); a2 += bw1 * bflo(u1.y); a3 += bw1 * bfhi(u1.y);
            a0 += bw2 * bflo(u2.x); a1 += bw2 * bfhi(u2.x); a2 += bw2 * bflo(u2.y); a3 += bw2 * bfhi(u2.y);
            a0 += bw3 * bflo(u3.x); a1 += bw3 * bfhi(u3.x); a2 += bw3 * bflo(u3.y); a3 += bw3 * bfhi(u3.y);
        }
    }
#pragma unroll
    for (int m = 1; m < 64; m <<= 1) {
        psum0 += __shfl_xor(psum0, m, 64);
        psum1 += __shfl_xor(psum1, m, 64);
    }
    float o0 = __shfl(a0, cl + 32, 64);
    float o1 = __shfl(a1, cl + 32, 64);
    float o2 = __shfl(a2, cl + 32, 64);
    float o3 = __shfl(a3, cl + 32, 64);
    if (lane < 32) {
        float inv = 1.f / (head1 ? psum1 : psum0);
        float4 bv = *(const float4*)&b1[cl * 4];
        float v0 = (a0 + o0) * inv + bv.x;
        float v1 = (a1 + o1) * inv + bv.y;
        float v2 = (a2 + o2) * inv + bv.z;
        float v3 = (a3 + o3) * inv + bv.w;
        v0 = v0 > 0.f ? v0 : 0.f;
        v1 = v1 > 0.f ? v1 : 0.f;
        v2 = v2 > 0.f ? v2 : 0.f;
        v3 = v3 > 0.f ? v3 : 0.f;
        ushort4 p;
        p.x = f2bf(v0); p.y = f2bf(v1); p.z = f2bf(v2); p.w = f2bf(v3);
        *(ushort4*)&out1b[(size_t)wid * 128 + cl * 4] = p;
    }
}

// -------- layer 2 aggregate: half-wave/edge, 8 edges per iteration --------
__global__ void agg2_kernel(const unsigned short* __restrict__ h2b,
                            const float* __restrict__ as2,
                            const float* __restrict__ ad2, const float* __restrict__ b2,
                            const int* __restrict__ offsets, const int* __restrict__ deg,
                            const int* __restrict__ csr_src,
                            float* __restrict__ out) {
    int wid = (blockIdx.x * blockDim.x + threadIdx.x) >> 6;
    if (wid >= N_NODES) return;
    int lane = threadIdx.x & 63;
    int cl = lane & 31;
    int half = lane >> 5;
    float da = ad2[wid];
    int jb = offsets[wid], je = jb + deg[wid];
    float acc0 = 0.f, acc1 = 0.f, psum = 0.f;

    for (int chunk = jb; chunk < je; chunk += 64) {
        int j = chunk + lane;
        int s = 0; float w = 0.f;
        if (j < je) {
            s = csr_src[j];
            w = __expf(lrelu(as2[s] + da));
        }
        psum += w;
        int cnt = je - chunk; if (cnt > 64) cnt = 64;
        for (int k = 0; k < cnt; k += 8) {
            int k0 = k + half, k1 = k + 2 + half, k2 = k + 4 + half, k3 = k + 6 + half;
            int ss0 = __shfl(s, k0, 64);
            int ss1 = __shfl(s, k1, 64);
            int ss2 = __shfl(s, k2, 64);
            int ss3 = __shfl(s, k3, 64);
            unsigned u0 = ((const unsigned*)(h2b + (size_t)ss0 * 64))[cl];
            unsigned u1 = ((const unsigned*)(h2b + (size_t)ss1 * 64))[cl];
            unsigned u2 = ((const unsigned*)(h2b + (size_t)ss2 * 64))[cl];
            unsigned u3 = ((const unsigned*)(h2b + (size_t)ss3 * 64))[cl];
            float bw0 = __shfl(w, k0, 64);
            float bw1 = __shfl(w, k1, 64);
            float bw2 = __shfl(w, k2, 64);
            float bw3 = __shfl(w, k3, 64);
            acc0 += bw0 * bflo(u0); acc1 += bw0 * bfhi(u0);
            acc0 += bw1 * bflo(u1); acc1 += bw1 * bfhi(u1);
            acc0 += bw2 * bflo(u2); acc1 += bw2 * bfhi(u2);
            acc0 += bw3 * bflo(u3); acc1 += bw3 * bfhi(u3);
        }
    }
#pragma unroll
    for (int m = 1; m < 64; m <<= 1) psum += __shfl_xor(psum, m, 64);
    float o0 = __shfl(acc0, cl + 32, 64);
    float o1 = __shfl(acc1, cl + 32, 64);
    if (lane < 32) {
        float inv = 1.f / psum;
        float2 bv = *(const float2*)&b2[cl * 2];
        float v0 = (acc0 + o0) * inv + bv.x;
        float v1 = (acc1 + o1) * inv + bv.y;
        v0 = 1.f / (1.f + __expf(-v0));
        v1 = 1.f / (1.f + __expf(-v1));
        *(float2*)&out[(size_t)wid * 64 + cl * 2] = make_float2(v0, v1);
    }
}

extern "C" void kernel_launch(void* const* d_in, const int* in_sizes, int n_in,
                              void* d_out, int out_size, void* d_ws, size_t ws_size,
                              hipStream_t stream) {
    const float* x     = (const float*)d_in[0];
    const int*   ei    = (const int*)d_in[1];
    const float* W1    = (const float*)d_in[2];
    const float* asrc1 = (const float*)d_in[3];
    const float* adst1 = (const float*)d_in[4];
    const float* b1    = (const float*)d_in[5];
    const float* W2    = (const float*)d_in[6];
    const float* asrc2 = (const float*)d_in[7];
    const float* adst2 = (const float*)d_in[8];
    const float* b2    = (const float*)d_in[9];
    float* out = (float*)d_out;

    float* ws = (float*)d_ws;
    size_t off = 0;
    float* as1  = ws + off; off += (size_t)N_NODES * 2;
    float* ad1  = ws + off; off += (size_t)N_NODES * 2;
    float* as2  = ws + off; off += (size_t)N_NODES;
    float* ad2  = ws + off; off += (size_t)N_NODES;
    unsigned short* h1b   = (unsigned short*)(ws + off); off += (size_t)N_NODES * 64;  // 128 bf16
    unsigned short* out1b = (unsigned short*)(ws + off); off += (size_t)N_NODES * 64;  // 128 bf16
    unsigned short* h2b   = (unsigned short*)(ws + off); off += (size_t)N_NODES * 32;  // 64 bf16
    int* offsets = (int*)(ws + off);
    int* deg     = offsets + N_NODES;
    int* csr_src = deg + N_NODES;                         // padded: NB_BKT*BKT_CAP
    int* bktcnt  = csr_src + NB_BKT * BKT_CAP;
    uint2* pairs = (uint2*)((((size_t)(bktcnt + NB_BKT)) + 7) & ~(size_t)7);

    hipMemsetAsync(bktcnt, 0, NB_BKT * sizeof(int), stream);

    fusedA_kernel<<<NB_G1 + NB_P1, 256, 0, stream>>>(x, W1, asrc1, adst1, h1b, as1, ad1,
                                                     ei, bktcnt, pairs);
    scatterP2_kernel<<<NB_BKT, 256, 0, stream>>>(pairs, bktcnt, offsets, deg, csr_src);
    agg1_kernel<<<(N_NODES * 64 + 255) / 256, 256, 0, stream>>>(h1b, as1, ad1, b1, offsets, deg, csr_src, out1b);
    gemm2_kernel<<<NB_G1, 256, 0, stream>>>(out1b, W2, asrc2, adst2, h2b, as2, ad2);
    agg2_kernel<<<(N_NODES * 64 + 255) / 256, 256, 0, stream>>>(h2b, as2, ad2, b2, offsets, deg, csr_src, out);
}